// Round 1
// baseline (1450.817 us; speedup 1.0000x reference)
//
#include <hip/hip_runtime.h>
#include <math.h>

// GeoMamba: B=8, L=39, D=256, K=5, M=252
constexpr int cB   = 8;
constexpr int cL   = 39;
constexpr int cD   = 256;
constexpr int cDD  = 65536;   // D*D
constexpr int cM   = 252;
constexpr int cMM  = 63504;   // M*M
constexpr int PAIRS = cL * cL; // 1521

constexpr int KCHUNKS = 64;   // gram K-split (1024 each of 65536)
constexpr int GSPLIT  = 32;   // out-gemm K-split (1984 each, last 2000)

// ---- ws layout (float offsets) ----
constexpr size_t OFF_SP   = 0;                         // gram partials [B][KCHUNKS][1521]
constexpr size_t SZ_SP    = (size_t)cB * KCHUNKS * PAIRS;
constexpr size_t OFF_ATTN = OFF_SP + SZ_SP;            // attention    [B][1521]
constexpr size_t SZ_ATTN  = (size_t)cB * PAIRS;
constexpr size_t OFF_W2   = OFF_ATTN + SZ_ATTN;        // folded wts   [B][j=39][oc=39][25]
constexpr size_t SZ_W2    = (size_t)cB * cL * cL * 25;
constexpr size_t OFF_TS   = OFF_W2 + SZ_W2;            // tile sumsq   [B][256][39]
constexpr size_t SZ_TS    = (size_t)cB * 256 * cL;
constexpr size_t OFF_NORM = OFF_TS + SZ_TS;            // norms        [312]
constexpr size_t SZ_NORM  = (size_t)cB * cL;
constexpr size_t OFF_OP   = OFF_NORM + SZ_NORM;        // gemm partials[32][312][256]
constexpr size_t SZ_OP    = (size_t)GSPLIT * 312 * 256;
constexpr size_t OFF_CONV = OFF_OP + SZ_OP;            // exp(conv)    [B][39][252][252] (tril'd)
constexpr size_t SZ_CONV  = (size_t)cB * cL * cMM;
constexpr size_t WS_FLOATS = OFF_CONV + SZ_CONV;       // ~94.2 MB

// ---------------------------------------------------------------------------
// K1: partial gram. scores[b,i,j] = sum_f hs[b,i,f]*hs[b,j,f]  (scale later)
// grid (KCHUNKS, B), block 256. Each block: K-chunk of 1024, full 39x39 tile.
// ---------------------------------------------------------------------------
__global__ __launch_bounds__(256) void k_gram(const float* __restrict__ hs,
                                              float* __restrict__ sp) {
    const int b   = blockIdx.y;
    const int kc  = blockIdx.x;
    const int tid = threadIdx.x;
    __shared__ float lds[64][42];   // [k][row], pad 42 for 8B-aligned float2

    if (tid < 128) lds[tid >> 1][39 + (tid & 1)] = 0.f;  // zero pad cols once
    __syncthreads();

    float acc0[2][2] = {{0.f,0.f},{0.f,0.f}};
    float acc1[2][2] = {{0.f,0.f},{0.f,0.f}};
    const int t0  = tid;
    const int t1v = tid + 256;
    const int t1  = (t1v < 400) ? t1v : 0;   // 20x20 grid of 2x2 tiles
    const int ti0 = t0 / 20, tj0 = t0 % 20;
    const int ti1 = t1 / 20, tj1 = t1 % 20;
    const float* hb = hs + (size_t)b * (cL * cDD);
    const int kbase = kc * 1024;

    for (int s = 0; s < 16; ++s) {
        const int k0 = kbase + s * 64;
        for (int idx = tid; idx < cL * 64; idx += 256) {
            const int j = idx >> 6, kk = idx & 63;
            lds[kk][j] = hb[(size_t)j * cDD + k0 + kk];
        }
        __syncthreads();
        #pragma unroll 4
        for (int kk = 0; kk < 64; ++kk) {
            const float2 ai = *(const float2*)&lds[kk][2*ti0];
            const float2 aj = *(const float2*)&lds[kk][2*tj0];
            acc0[0][0] = fmaf(ai.x, aj.x, acc0[0][0]);
            acc0[0][1] = fmaf(ai.x, aj.y, acc0[0][1]);
            acc0[1][0] = fmaf(ai.y, aj.x, acc0[1][0]);
            acc0[1][1] = fmaf(ai.y, aj.y, acc0[1][1]);
            const float2 bi = *(const float2*)&lds[kk][2*ti1];
            const float2 bj = *(const float2*)&lds[kk][2*tj1];
            acc1[0][0] = fmaf(bi.x, bj.x, acc1[0][0]);
            acc1[0][1] = fmaf(bi.x, bj.y, acc1[0][1]);
            acc1[1][0] = fmaf(bi.y, bj.x, acc1[1][0]);
            acc1[1][1] = fmaf(bi.y, bj.y, acc1[1][1]);
        }
        __syncthreads();
    }

    float* outp = sp + ((size_t)b * KCHUNKS + kc) * PAIRS;
    {
        const int r = 2*ti0, c = 2*tj0;
        if (r   < cL && c   < cL) outp[r*cL + c]       = acc0[0][0];
        if (r   < cL && c+1 < cL) outp[r*cL + c+1]     = acc0[0][1];
        if (r+1 < cL && c   < cL) outp[(r+1)*cL + c]   = acc0[1][0];
        if (r+1 < cL && c+1 < cL) outp[(r+1)*cL + c+1] = acc0[1][1];
    }
    if (t1v < 400) {
        const int r = 2*ti1, c = 2*tj1;
        if (r   < cL && c   < cL) outp[r*cL + c]       = acc1[0][0];
        if (r   < cL && c+1 < cL) outp[r*cL + c+1]     = acc1[0][1];
        if (r+1 < cL && c   < cL) outp[(r+1)*cL + c]   = acc1[1][0];
        if (r+1 < cL && c+1 < cL) outp[(r+1)*cL + c+1] = acc1[1][1];
    }
}

// ---------------------------------------------------------------------------
// K2: reduce gram partials, scale 1/256, row softmax. Writes attention to ws
// and to d_out (output 1). grid B, block 256.
// ---------------------------------------------------------------------------
__global__ __launch_bounds__(256) void k_softmax(const float* __restrict__ sp,
                                                 float* __restrict__ attnWs,
                                                 float* __restrict__ outAttn) {
    const int b = blockIdx.x;
    const int tid = threadIdx.x;
    __shared__ float sc[PAIRS];
    for (int idx = tid; idx < PAIRS; idx += 256) {
        float s = 0.f;
        for (int c = 0; c < KCHUNKS; ++c)
            s += sp[((size_t)b * KCHUNKS + c) * PAIRS + idx];
        sc[idx] = s * (1.0f / 256.0f);
    }
    __syncthreads();
    if (tid < cL) {
        const int i = tid;
        float m = -1e30f;
        #pragma unroll
        for (int j = 0; j < cL; ++j) m = fmaxf(m, sc[i*cL + j]);
        float e[cL];
        float sum = 0.f;
        #pragma unroll
        for (int j = 0; j < cL; ++j) { e[j] = expf(sc[i*cL + j] - m); sum += e[j]; }
        const float inv = 1.0f / sum;
        #pragma unroll
        for (int j = 0; j < cL; ++j) {
            const float a = e[j] * inv;
            attnWs [(size_t)b*PAIRS + i*cL + j] = a;
            outAttn[(size_t)b*PAIRS + i*cL + j] = a;
        }
    }
}

// ---------------------------------------------------------------------------
// K3: fold attention into conv weights.
// w2[b,j,oc,tap] = sum_i conv_w[oc,i,tap] * attn[b,i,j]
// grid B, block 1024 (975 active: one (oc,tap) each).
// ---------------------------------------------------------------------------
__global__ __launch_bounds__(1024) void k_wtrans(const float* __restrict__ cw,
                                                 const float* __restrict__ attn,
                                                 float* __restrict__ w2) {
    const int b = blockIdx.x;
    const int t = threadIdx.x;
    __shared__ float at[PAIRS];
    for (int idx = t; idx < PAIRS; idx += 1024)
        at[idx] = attn[(size_t)b*PAIRS + idx];
    __syncthreads();
    if (t < cL * 25) {
        const int oc = t / 25, tap = t % 25;
        float c[cL];
        #pragma unroll
        for (int i = 0; i < cL; ++i)
            c[i] = cw[(size_t)oc * (cL*25) + i*25 + tap];   // conv_w is (512,39,5,5); oc<39
        for (int j = 0; j < cL; ++j) {
            float a = 0.f;
            #pragma unroll
            for (int i = 0; i < cL; ++i) a = fmaf(c[i], at[i*cL + j], a);
            w2[(((size_t)b*cL + j)*cL + oc)*25 + tap] = a;
        }
    }
}

// ---------------------------------------------------------------------------
// K4: 5x5 VALID conv on hs with folded weights + bias + exp; store tril'd
// values; per-tile per-channel sum of exp^2 (full plane, pre-tril).
// grid (16,16,B), block (16,16). Weights read via uniform addr -> s_load.
// ---------------------------------------------------------------------------
__global__ __launch_bounds__(256) void k_conv(const float* __restrict__ hs,
                                              const float* __restrict__ w2,
                                              const float* __restrict__ cb,
                                              float* __restrict__ convout,
                                              float* __restrict__ tileSumsq) {
    const int b   = blockIdx.z;
    const int gh0 = blockIdx.y * 16, gw0 = blockIdx.x * 16;
    const int tx = threadIdx.x, ty = threadIdx.y;
    const int tid = ty * 16 + tx;
    __shared__ float tile[400];      // 20x20 input patch
    __shared__ float red[4][cL];

    float acc[cL];
    #pragma unroll
    for (int oc = 0; oc < cL; ++oc) acc[oc] = 0.f;

    const float* hbase = hs + (size_t)b * cL * cDD;
    const float* wbase = w2 + (size_t)b * (cL * cL * 25);

    for (int ic = 0; ic < cL; ++ic) {
        {
            int idx = tid;
            int r = idx / 20, c = idx % 20;
            int ih = gh0 + r, iw = gw0 + c;
            tile[idx] = (ih < cD && iw < cD) ? hbase[(size_t)ic*cDD + ih*cD + iw] : 0.f;
            idx = tid + 256;
            if (idx < 400) {
                r = idx / 20; c = idx % 20; ih = gh0 + r; iw = gw0 + c;
                tile[idx] = (ih < cD && iw < cD) ? hbase[(size_t)ic*cDD + ih*cD + iw] : 0.f;
            }
        }
        __syncthreads();
        float v[25];
        #pragma unroll
        for (int kh = 0; kh < 5; ++kh)
            #pragma unroll
            for (int kw = 0; kw < 5; ++kw)
                v[kh*5 + kw] = tile[(ty + kh)*20 + tx + kw];
        const float* wp = wbase + (size_t)ic * (cL * 25);   // [oc][tap], uniform addr
        #pragma unroll
        for (int oc = 0; oc < cL; ++oc) {
            float a = acc[oc];
            #pragma unroll
            for (int tap = 0; tap < 25; ++tap)
                a = fmaf(v[tap], wp[oc*25 + tap], a);
            acc[oc] = a;
        }
        __syncthreads();
    }

    const int oh = gh0 + ty, ow = gw0 + tx;
    const bool valid = (oh < cM) && (ow < cM);
    const size_t cbase = (size_t)b * cL * cMM + (size_t)oh * cM + ow;
    #pragma unroll
    for (int oc = 0; oc < cL; ++oc) {
        const float e = __expf(acc[oc] + cb[oc]);
        acc[oc] = valid ? e : 0.f;                       // for sumsq (full plane)
        if (valid) convout[cbase + (size_t)oc * cMM] = (ow <= oh) ? e : 0.f; // tril
    }
    const int lane = tid & 63, wid = tid >> 6;
    #pragma unroll
    for (int oc = 0; oc < cL; ++oc) {
        float v2 = acc[oc] * acc[oc];
        for (int off = 32; off; off >>= 1) v2 += __shfl_down(v2, off, 64);
        if (lane == 0) red[wid][oc] = v2;
    }
    __syncthreads();
    if (tid < cL) {
        const float s = red[0][tid] + red[1][tid] + red[2][tid] + red[3][tid];
        tileSumsq[((size_t)b*256 + blockIdx.y*16 + blockIdx.x)*cL + tid] = s;
    }
}

// ---------------------------------------------------------------------------
// K4b: norms[row] = sqrt(sum over 256 tiles). grid 312, block 256.
// ---------------------------------------------------------------------------
__global__ __launch_bounds__(256) void k_norm(const float* __restrict__ ts,
                                              float* __restrict__ norms) {
    const int row = blockIdx.x;           // b*39 + l
    const int b = row / cL, l = row % cL;
    const int tid = threadIdx.x;
    float v = ts[((size_t)b*256 + tid)*cL + l];
    for (int off = 32; off; off >>= 1) v += __shfl_down(v, off, 64);
    __shared__ float r[4];
    if ((tid & 63) == 0) r[tid >> 6] = v;
    __syncthreads();
    if (tid == 0) norms[row] = sqrtf(r[0] + r[1] + r[2] + r[3]);
}

// ---------------------------------------------------------------------------
// K5: out partials. C[row, o] = sum_f convout[row,f]*out_w[o,f]
// grid (4 ntiles, 5 mtiles, 32 kchunks), block 256, 64x64 tile, 4x4/thread.
// ---------------------------------------------------------------------------
__global__ __launch_bounds__(256) void k_gemm(const float* __restrict__ A,
                                              const float* __restrict__ Bw,
                                              float* __restrict__ op) {
    const int nt = blockIdx.x, mt = blockIdx.y, z = blockIdx.z;
    const int tid = threadIdx.x;
    const int tm = tid >> 4, tn = tid & 15;
    __shared__ float As[16][68];
    __shared__ float Bs[16][68];
    float c[4][4] = {};
    const int kbeg = z * 1984;
    const int kend = (z == GSPLIT - 1) ? cMM : kbeg + 1984;
    const int mbase = mt * 64, nbase = nt * 64;

    for (int k0 = kbeg; k0 < kend; k0 += 16) {
        #pragma unroll
        for (int i = 0; i < 4; ++i) {
            const int idx = tid + i * 256;
            const int kk = idx & 15, m = idx >> 4;
            const int k = k0 + kk;
            const int row = mbase + m;
            As[kk][m] = (row < 312 && k < kend) ? A[(size_t)row*cMM + k] : 0.f;
            Bs[kk][m] = (k < kend) ? Bw[(size_t)(nbase + m)*cMM + k] : 0.f;
        }
        __syncthreads();
        #pragma unroll
        for (int kk = 0; kk < 16; ++kk) {
            const float4 av = *(const float4*)&As[kk][tm*4];
            const float4 bv = *(const float4*)&Bs[kk][tn*4];
            c[0][0] = fmaf(av.x, bv.x, c[0][0]);
            c[0][1] = fmaf(av.x, bv.y, c[0][1]);
            c[0][2] = fmaf(av.x, bv.z, c[0][2]);
            c[0][3] = fmaf(av.x, bv.w, c[0][3]);
            c[1][0] = fmaf(av.y, bv.x, c[1][0]);
            c[1][1] = fmaf(av.y, bv.y, c[1][1]);
            c[1][2] = fmaf(av.y, bv.z, c[1][2]);
            c[1][3] = fmaf(av.y, bv.w, c[1][3]);
            c[2][0] = fmaf(av.z, bv.x, c[2][0]);
            c[2][1] = fmaf(av.z, bv.y, c[2][1]);
            c[2][2] = fmaf(av.z, bv.z, c[2][2]);
            c[2][3] = fmaf(av.z, bv.w, c[2][3]);
            c[3][0] = fmaf(av.w, bv.x, c[3][0]);
            c[3][1] = fmaf(av.w, bv.y, c[3][1]);
            c[3][2] = fmaf(av.w, bv.z, c[3][2]);
            c[3][3] = fmaf(av.w, bv.w, c[3][3]);
        }
        __syncthreads();
    }
    #pragma unroll
    for (int i = 0; i < 4; ++i) {
        const int row = mbase + tm*4 + i;
        if (row < 312) {
            #pragma unroll
            for (int j = 0; j < 4; ++j)
                op[((size_t)z*312 + row)*256 + nbase + tn*4 + j] = c[i][j];
        }
    }
}

// ---------------------------------------------------------------------------
// K5b: reduce K-split partials, divide by norm, write out. grid 312, block 256.
// ---------------------------------------------------------------------------
__global__ __launch_bounds__(256) void k_finish(const float* __restrict__ op,
                                                const float* __restrict__ norms,
                                                float* __restrict__ out) {
    const int idx = blockIdx.x * 256 + threadIdx.x;   // < 312*256
    float s = 0.f;
    for (int z = 0; z < GSPLIT; ++z) s += op[(size_t)z * (312*256) + idx];
    out[idx] = s / norms[idx >> 8];
}

// ---------------------------------------------------------------------------
extern "C" void kernel_launch(void* const* d_in, const int* in_sizes, int n_in,
                              void* d_out, int out_size, void* d_ws, size_t ws_size,
                              hipStream_t stream) {
    const float* hs = (const float*)d_in[0];   // (8,39,256,256)
    const float* cw = (const float*)d_in[1];   // (512,39,5,5)
    const float* cb = (const float*)d_in[2];   // (512,)
    const float* ow = (const float*)d_in[3];   // (256,63504)
    float* out = (float*)d_out;                // [79872 out][12168 attention]
    float* ws  = (float*)d_ws;

    if (ws_size < WS_FLOATS * sizeof(float)) return;   // insufficient scratch: fail loudly

    float* sp   = ws + OFF_SP;
    float* attn = ws + OFF_ATTN;
    float* w2   = ws + OFF_W2;
    float* ts   = ws + OFF_TS;
    float* nrm  = ws + OFF_NORM;
    float* op   = ws + OFF_OP;
    float* cv   = ws + OFF_CONV;

    k_gram   <<<dim3(KCHUNKS, cB), 256, 0, stream>>>(hs, sp);
    k_softmax<<<cB, 256, 0, stream>>>(sp, attn, out + (size_t)cB*cL*cD);
    k_wtrans <<<cB, 1024, 0, stream>>>(cw, attn, w2);
    k_conv   <<<dim3(16, 16, cB), dim3(16, 16), 0, stream>>>(hs, w2, cb, cv, ts);
    k_norm   <<<cB*cL, 256, 0, stream>>>(ts, nrm);
    k_gemm   <<<dim3(4, 5, GSPLIT), 256, 0, stream>>>(cv, ow, op);
    k_finish <<<312, 256, 0, stream>>>(op, nrm, out);
}

// Round 2
// 811.912 us; speedup vs baseline: 1.7869x; 1.7869x over previous
//
#include <hip/hip_runtime.h>
#include <math.h>

typedef unsigned short u16;
typedef __attribute__((ext_vector_type(8))) short short8;
typedef __attribute__((ext_vector_type(4))) float f32x4;

// GeoMamba: B=8, L=39, D=256, K=5, M=252
constexpr int cB   = 8;
constexpr int cL   = 39;
constexpr int cD   = 256;
constexpr int cDD  = 65536;   // D*D
constexpr int cM   = 252;
constexpr int cMM  = 63504;   // M*M
constexpr int PAIRS = cL * cL; // 1521

constexpr int KCHUNKS = 64;   // gram K-split (1024 each of 65536)
constexpr int GSPLIT  = 32;   // out-gemm K-split

// ---- ws layout (float offsets) ----
constexpr size_t OFF_SP   = 0;                         // gram partials [B][KCHUNKS][1521]
constexpr size_t SZ_SP    = (size_t)cB * KCHUNKS * PAIRS;
constexpr size_t OFF_ATTN = OFF_SP + SZ_SP;            // attention    [B][1521]
constexpr size_t SZ_ATTN  = (size_t)cB * PAIRS;
constexpr size_t OFF_W2   = OFF_ATTN + SZ_ATTN;        // folded wts bf16 [B][tap25][oc48][ic64]
constexpr size_t SZ_W2    = (size_t)cB * 25 * 48 * 64 / 2;   // ushorts -> floats
constexpr size_t OFF_TS   = OFF_W2 + SZ_W2;            // tile sumsq   [B][256][39]
constexpr size_t SZ_TS    = (size_t)cB * 256 * cL;
constexpr size_t OFF_NORM = OFF_TS + SZ_TS;            // norms        [312]
constexpr size_t SZ_NORM  = (size_t)cB * cL;
constexpr size_t OFF_OP   = OFF_NORM + SZ_NORM;        // gemm partials[32][312][256]
constexpr size_t SZ_OP    = (size_t)GSPLIT * 312 * 256;
constexpr size_t OFF_CONV = OFF_OP + SZ_OP;            // exp(conv)    [B][39][252][252] (tril'd)
constexpr size_t SZ_CONV  = (size_t)cB * cL * cMM;
constexpr size_t WS_FLOATS = OFF_CONV + SZ_CONV;       // ~94.2 MB

__device__ inline u16 f2bf(float x) {
    union { float f; unsigned u; } v; v.f = x;
    unsigned r = v.u + 0x7fffu + ((v.u >> 16) & 1u);   // RNE
    return (u16)(r >> 16);
}

// ---------------------------------------------------------------------------
// K1: partial gram. scores[b,i,j] = sum_f hs[b,i,f]*hs[b,j,f]  (scale later)
// ---------------------------------------------------------------------------
__global__ __launch_bounds__(256) void k_gram(const float* __restrict__ hs,
                                              float* __restrict__ sp) {
    const int b   = blockIdx.y;
    const int kc  = blockIdx.x;
    const int tid = threadIdx.x;
    __shared__ float lds[64][42];

    if (tid < 128) lds[tid >> 1][39 + (tid & 1)] = 0.f;
    __syncthreads();

    float acc0[2][2] = {{0.f,0.f},{0.f,0.f}};
    float acc1[2][2] = {{0.f,0.f},{0.f,0.f}};
    const int t0  = tid;
    const int t1v = tid + 256;
    const int t1  = (t1v < 400) ? t1v : 0;
    const int ti0 = t0 / 20, tj0 = t0 % 20;
    const int ti1 = t1 / 20, tj1 = t1 % 20;
    const float* hb = hs + (size_t)b * (cL * cDD);
    const int kbase = kc * 1024;

    for (int s = 0; s < 16; ++s) {
        const int k0 = kbase + s * 64;
        for (int idx = tid; idx < cL * 64; idx += 256) {
            const int j = idx >> 6, kk = idx & 63;
            lds[kk][j] = hb[(size_t)j * cDD + k0 + kk];
        }
        __syncthreads();
        #pragma unroll 4
        for (int kk = 0; kk < 64; ++kk) {
            const float2 ai = *(const float2*)&lds[kk][2*ti0];
            const float2 aj = *(const float2*)&lds[kk][2*tj0];
            acc0[0][0] = fmaf(ai.x, aj.x, acc0[0][0]);
            acc0[0][1] = fmaf(ai.x, aj.y, acc0[0][1]);
            acc0[1][0] = fmaf(ai.y, aj.x, acc0[1][0]);
            acc0[1][1] = fmaf(ai.y, aj.y, acc0[1][1]);
            const float2 bi = *(const float2*)&lds[kk][2*ti1];
            const float2 bj = *(const float2*)&lds[kk][2*tj1];
            acc1[0][0] = fmaf(bi.x, bj.x, acc1[0][0]);
            acc1[0][1] = fmaf(bi.x, bj.y, acc1[0][1]);
            acc1[1][0] = fmaf(bi.y, bj.x, acc1[1][0]);
            acc1[1][1] = fmaf(bi.y, bj.y, acc1[1][1]);
        }
        __syncthreads();
    }

    float* outp = sp + ((size_t)b * KCHUNKS + kc) * PAIRS;
    {
        const int r = 2*ti0, c = 2*tj0;
        if (r   < cL && c   < cL) outp[r*cL + c]       = acc0[0][0];
        if (r   < cL && c+1 < cL) outp[r*cL + c+1]     = acc0[0][1];
        if (r+1 < cL && c   < cL) outp[(r+1)*cL + c]   = acc0[1][0];
        if (r+1 < cL && c+1 < cL) outp[(r+1)*cL + c+1] = acc0[1][1];
    }
    if (t1v < 400) {
        const int r = 2*ti1, c = 2*tj1;
        if (r   < cL && c   < cL) outp[r*cL + c]       = acc1[0][0];
        if (r   < cL && c+1 < cL) outp[r*cL + c+1]     = acc1[0][1];
        if (r+1 < cL && c   < cL) outp[(r+1)*cL + c]   = acc1[1][0];
        if (r+1 < cL && c+1 < cL) outp[(r+1)*cL + c+1] = acc1[1][1];
    }
}

// ---------------------------------------------------------------------------
// K2: reduce gram partials, scale 1/256, row softmax.
// ---------------------------------------------------------------------------
__global__ __launch_bounds__(256) void k_softmax(const float* __restrict__ sp,
                                                 float* __restrict__ attnWs,
                                                 float* __restrict__ outAttn) {
    const int b = blockIdx.x;
    const int tid = threadIdx.x;
    __shared__ float sc[PAIRS];
    for (int idx = tid; idx < PAIRS; idx += 256) {
        float s = 0.f;
        for (int c = 0; c < KCHUNKS; ++c)
            s += sp[((size_t)b * KCHUNKS + c) * PAIRS + idx];
        sc[idx] = s * (1.0f / 256.0f);
    }
    __syncthreads();
    if (tid < cL) {
        const int i = tid;
        float m = -1e30f;
        #pragma unroll
        for (int j = 0; j < cL; ++j) m = fmaxf(m, sc[i*cL + j]);
        float e[cL];
        float sum = 0.f;
        #pragma unroll
        for (int j = 0; j < cL; ++j) { e[j] = expf(sc[i*cL + j] - m); sum += e[j]; }
        const float inv = 1.0f / sum;
        #pragma unroll
        for (int j = 0; j < cL; ++j) {
            const float a = e[j] * inv;
            attnWs [(size_t)b*PAIRS + i*cL + j] = a;
            outAttn[(size_t)b*PAIRS + i*cL + j] = a;
        }
    }
}

// ---------------------------------------------------------------------------
// K3: fold attention into conv weights -> bf16 MFMA A-layout.
// w2g[b][tap][oc(48 pad)][j=ic(64 pad)] = sum_i conv_w[oc,i,tap]*attn[b,i,j]
// ---------------------------------------------------------------------------
__global__ __launch_bounds__(1024) void k_wtrans(const float* __restrict__ cw,
                                                 const float* __restrict__ attn,
                                                 u16* __restrict__ w2g) {
    const int b = blockIdx.x;
    const int t = threadIdx.x;
    __shared__ float at[PAIRS];
    for (int idx = t; idx < PAIRS; idx += 1024)
        at[idx] = attn[(size_t)b*PAIRS + idx];
    __syncthreads();
    if (t < cL * 25) {
        const int oc = t / 25, tap = t % 25;
        float c[cL];
        #pragma unroll
        for (int i = 0; i < cL; ++i)
            c[i] = cw[(size_t)oc * (cL*25) + i*25 + tap];
        u16* dst = w2g + (((size_t)b*25 + tap)*48 + oc)*64;
        for (int j = 0; j < cL; ++j) {
            float a = 0.f;
            #pragma unroll
            for (int i = 0; i < cL; ++i) a = fmaf(c[i], at[i*cL + j], a);
            dst[j] = f2bf(a);
        }
        for (int j = cL; j < 64; ++j) dst[j] = 0;
    } else if (t < cL * 25 + 25) {
        const int tap = t - cL * 25;           // zero oc rows 39..47
        u16* dst = w2g + (((size_t)b*25 + tap)*48 + cL)*64;
        for (int k = 0; k < 9*64; ++k) dst[k] = 0;
    }
}

// ---------------------------------------------------------------------------
// K4: conv as 25 shifted MFMA-GEMMs. Block = 16x16 output pixels, all 39 oc.
// P[400 pix][64 ic] bf16 in LDS, XOR-swizzled 16B slots. 4 waves, each 4 rows.
// ---------------------------------------------------------------------------
__global__ __launch_bounds__(256) void k_conv(const float* __restrict__ hs,
                                              const u16* __restrict__ w2g,
                                              const float* __restrict__ cb,
                                              float* __restrict__ convout,
                                              float* __restrict__ tileSumsq) {
    const int b   = blockIdx.z;
    const int gh0 = blockIdx.y * 16, gw0 = blockIdx.x * 16;
    const int tid = threadIdx.x;
    const int wv  = tid >> 6;
    const int ln15 = tid & 15;
    const int kg4  = (tid & 63) >> 4;

    __shared__ u16 P[400 * 64];       // 51.2 KB
    __shared__ float red[4][48];

    // ---- stage 20x20 patch for all 39 channels (+ zero pad ic 39..63) ----
    const float* hb = hs + (size_t)b * (cL * cDD);
    for (int ic = 0; ic < cL; ++ic) {
        const float* hc = hb + (size_t)ic * cDD;
        for (int p = tid; p < 400; p += 256) {
            const int pr = p / 20, pc = p % 20;
            const int gh = gh0 + pr, gw = gw0 + pc;
            const float v = (gh < cD && gw < cD) ? hc[gh*cD + gw] : 0.f;
            const int slot = (ic >> 3) ^ (p & 7);
            P[p*64 + slot*8 + (ic & 7)] = f2bf(v);
        }
    }
    for (int s = cL; s < 64; ++s)
        for (int p = tid; p < 400; p += 256)
            P[p*64 + (((s >> 3) ^ (p & 7))*8) + (s & 7)] = 0;
    __syncthreads();

    // ---- main loop: 25 taps x 2 K-chunks, MFMA 16x16x32 bf16 ----
    f32x4 acc[3][4] = {};
    const u16* wb = w2g + ((size_t)b * 25) * 48 * 64;

    for (int kh = 0; kh < 5; ++kh) {
        for (int kw = 0; kw < 5; ++kw) {
            const int tap = kh*5 + kw;
            const u16* wt = wb + (size_t)tap * 48 * 64;
            short8 afr[3][2];
            #pragma unroll
            for (int o = 0; o < 3; ++o)
                #pragma unroll
                for (int kc = 0; kc < 2; ++kc)
                    afr[o][kc] = *(const short8*)(wt + (o*16 + ln15)*64 + kc*32 + kg4*8);
            #pragma unroll
            for (int pt = 0; pt < 4; ++pt) {
                const int p = (wv*4 + pt + kh)*20 + ln15 + kw;
                #pragma unroll
                for (int kc = 0; kc < 2; ++kc) {
                    const int slot = (kc*4 + kg4) ^ (p & 7);
                    const short8 bfr = *(const short8*)&P[p*64 + slot*8];
                    #pragma unroll
                    for (int o = 0; o < 3; ++o)
                        acc[o][pt] = __builtin_amdgcn_mfma_f32_16x16x32_bf16(
                            afr[o][kc], bfr, acc[o][pt], 0, 0, 0);
                }
            }
        }
    }

    // ---- epilogue: bias + exp, tril store, sum-of-squares ----
    float ss[3][4];
    #pragma unroll
    for (int o = 0; o < 3; ++o)
        #pragma unroll
        for (int r = 0; r < 4; ++r) ss[o][r] = 0.f;

    const int ow = gw0 + ln15;
    #pragma unroll
    for (int o = 0; o < 3; ++o) {
        #pragma unroll
        for (int r = 0; r < 4; ++r) {
            const int oc = o*16 + kg4*4 + r;
            const float bias = (oc < cL) ? cb[oc] : 0.f;
            #pragma unroll
            for (int pt = 0; pt < 4; ++pt) {
                const int oh = gh0 + wv*4 + pt;
                if (oc < cL && oh < cM && ow < cM) {
                    const float e = __expf(acc[o][pt][r] + bias);
                    convout[((size_t)(b*cL + oc))*cMM + oh*cM + ow] = (ow <= oh) ? e : 0.f;
                    ss[o][r] += e * e;
                }
            }
        }
    }

    #pragma unroll
    for (int o = 0; o < 3; ++o) {
        #pragma unroll
        for (int r = 0; r < 4; ++r) {
            float v = ss[o][r];
            v += __shfl_xor(v, 1);
            v += __shfl_xor(v, 2);
            v += __shfl_xor(v, 4);
            v += __shfl_xor(v, 8);
            if (ln15 == 0) red[wv][o*16 + kg4*4 + r] = v;
        }
    }
    __syncthreads();
    if (tid < 2*48 && tid >= 48) {} // no-op spacing
    if (tid < cL) {
        const int tileIdx = blockIdx.y * 16 + blockIdx.x;
        tileSumsq[((size_t)b*256 + tileIdx)*cL + tid] =
            red[0][tid] + red[1][tid] + red[2][tid] + red[3][tid];
    }
}

// ---------------------------------------------------------------------------
// K4b: norms[row] = sqrt(sum over 256 tiles).
// ---------------------------------------------------------------------------
__global__ __launch_bounds__(256) void k_norm(const float* __restrict__ ts,
                                              float* __restrict__ norms) {
    const int row = blockIdx.x;           // b*39 + l
    const int b = row / cL, l = row % cL;
    const int tid = threadIdx.x;
    float v = ts[((size_t)b*256 + tid)*cL + l];
    for (int off = 32; off; off >>= 1) v += __shfl_down(v, off, 64);
    __shared__ float r[4];
    if ((tid & 63) == 0) r[tid >> 6] = v;
    __syncthreads();
    if (tid == 0) norms[row] = sqrtf(r[0] + r[1] + r[2] + r[3]);
}

// ---------------------------------------------------------------------------
// K5: out partials. C[row, o] = sum_f convout[row,f]*out_w[o,f]
// ---------------------------------------------------------------------------
__global__ __launch_bounds__(256) void k_gemm(const float* __restrict__ A,
                                              const float* __restrict__ Bw,
                                              float* __restrict__ op) {
    const int nt = blockIdx.x, mt = blockIdx.y, z = blockIdx.z;
    const int tid = threadIdx.x;
    const int tm = tid >> 4, tn = tid & 15;
    __shared__ float As[16][68];
    __shared__ float Bs[16][68];
    float c[4][4] = {};
    const int kbeg = z * 1984;
    const int kend = (z == GSPLIT - 1) ? cMM : kbeg + 1984;
    const int mbase = mt * 64, nbase = nt * 64;

    for (int k0 = kbeg; k0 < kend; k0 += 16) {
        #pragma unroll
        for (int i = 0; i < 4; ++i) {
            const int idx = tid + i * 256;
            const int kk = idx & 15, m = idx >> 4;
            const int k = k0 + kk;
            const int row = mbase + m;
            As[kk][m] = (row < 312 && k < kend) ? A[(size_t)row*cMM + k] : 0.f;
            Bs[kk][m] = (k < kend) ? Bw[(size_t)(nbase + m)*cMM + k] : 0.f;
        }
        __syncthreads();
        #pragma unroll
        for (int kk = 0; kk < 16; ++kk) {
            const float4 av = *(const float4*)&As[kk][tm*4];
            const float4 bv = *(const float4*)&Bs[kk][tn*4];
            c[0][0] = fmaf(av.x, bv.x, c[0][0]);
            c[0][1] = fmaf(av.x, bv.y, c[0][1]);
            c[0][2] = fmaf(av.x, bv.z, c[0][2]);
            c[0][3] = fmaf(av.x, bv.w, c[0][3]);
            c[1][0] = fmaf(av.y, bv.x, c[1][0]);
            c[1][1] = fmaf(av.y, bv.y, c[1][1]);
            c[1][2] = fmaf(av.y, bv.z, c[1][2]);
            c[1][3] = fmaf(av.y, bv.w, c[1][3]);
            c[2][0] = fmaf(av.z, bv.x, c[2][0]);
            c[2][1] = fmaf(av.z, bv.y, c[2][1]);
            c[2][2] = fmaf(av.z, bv.z, c[2][2]);
            c[2][3] = fmaf(av.z, bv.w, c[2][3]);
            c[3][0] = fmaf(av.w, bv.x, c[3][0]);
            c[3][1] = fmaf(av.w, bv.y, c[3][1]);
            c[3][2] = fmaf(av.w, bv.z, c[3][2]);
            c[3][3] = fmaf(av.w, bv.w, c[3][3]);
        }
        __syncthreads();
    }
    #pragma unroll
    for (int i = 0; i < 4; ++i) {
        const int row = mbase + tm*4 + i;
        if (row < 312) {
            #pragma unroll
            for (int j = 0; j < 4; ++j)
                op[((size_t)z*312 + row)*256 + nbase + tn*4 + j] = c[i][j];
        }
    }
}

// ---------------------------------------------------------------------------
// K5b: reduce K-split partials, divide by norm, write out.
// ---------------------------------------------------------------------------
__global__ __launch_bounds__(256) void k_finish(const float* __restrict__ op,
                                                const float* __restrict__ norms,
                                                float* __restrict__ out) {
    const int idx = blockIdx.x * 256 + threadIdx.x;
    float s = 0.f;
    for (int z = 0; z < GSPLIT; ++z) s += op[(size_t)z * (312*256) + idx];
    out[idx] = s / norms[idx >> 8];
}

// ---------------------------------------------------------------------------
extern "C" void kernel_launch(void* const* d_in, const int* in_sizes, int n_in,
                              void* d_out, int out_size, void* d_ws, size_t ws_size,
                              hipStream_t stream) {
    const float* hs = (const float*)d_in[0];
    const float* cw = (const float*)d_in[1];
    const float* cb = (const float*)d_in[2];
    const float* ow = (const float*)d_in[3];
    float* out = (float*)d_out;
    float* ws  = (float*)d_ws;

    if (ws_size < WS_FLOATS * sizeof(float)) return;

    float* sp   = ws + OFF_SP;
    float* attn = ws + OFF_ATTN;
    u16*   w2g  = (u16*)(ws + OFF_W2);
    float* ts   = ws + OFF_TS;
    float* nrm  = ws + OFF_NORM;
    float* op   = ws + OFF_OP;
    float* cv   = ws + OFF_CONV;

    k_gram   <<<dim3(KCHUNKS, cB), 256, 0, stream>>>(hs, sp);
    k_softmax<<<cB, 256, 0, stream>>>(sp, attn, out + (size_t)cB*cL*cD);
    k_wtrans <<<cB, 1024, 0, stream>>>(cw, attn, w2g);
    k_conv   <<<dim3(16, 16, cB), 256, 0, stream>>>(hs, w2g, cb, cv, ts);
    k_norm   <<<cB*cL, 256, 0, stream>>>(ts, nrm);
    k_gemm   <<<dim3(4, 5, GSPLIT), 256, 0, stream>>>(cv, ow, op);
    k_finish <<<312, 256, 0, stream>>>(op, nrm, out);
}

// Round 3
// 513.974 us; speedup vs baseline: 2.8227x; 1.5797x over previous
//
#include <hip/hip_runtime.h>
#include <math.h>

typedef unsigned short u16;
typedef __attribute__((ext_vector_type(8))) short short8;
typedef __attribute__((ext_vector_type(4))) float f32x4;
typedef __attribute__((ext_vector_type(4))) unsigned short ushort4_t;

// GeoMamba: B=8, L=39, D=256, K=5, M=252
constexpr int cB   = 8;
constexpr int cL   = 39;
constexpr int cD   = 256;
constexpr int cDD  = 65536;   // D*D
constexpr int cM   = 252;
constexpr int cMM  = 63504;   // M*M
constexpr int PAIRS = cL * cL; // 1521

constexpr int KCHUNKS = 64;   // gram K-split (1024 each of 65536)
constexpr int GSPLIT  = 40;   // out-gemm K-split
constexpr int GK      = 65536; // padded K stride for bf16 A/B (u16 elems)
constexpr int CHUNK   = 1600;  // K per gemm block (25 steps of 64)
constexpr int NSTEPS  = CHUNK / 64;

// ---- ws layout (float offsets) ----
constexpr size_t OFF_SP   = 0;                         // gram partials [B][KCHUNKS][1521]
constexpr size_t SZ_SP    = (size_t)cB * KCHUNKS * PAIRS;
constexpr size_t OFF_ATTN = OFF_SP + SZ_SP;            // attention    [B][1521]
constexpr size_t SZ_ATTN  = (size_t)cB * PAIRS;
constexpr size_t OFF_W2   = OFF_ATTN + SZ_ATTN;        // folded wts bf16 [B][tap25][oc48][ic64]
constexpr size_t SZ_W2    = (size_t)cB * 25 * 48 * 64 / 2;
constexpr size_t OFF_TS   = OFF_W2 + SZ_W2;            // tile sumsq   [B][256][39]
constexpr size_t SZ_TS    = (size_t)cB * 256 * cL;
constexpr size_t OFF_NORM = OFF_TS + SZ_TS;            // norms        [312]
constexpr size_t SZ_NORM  = (size_t)cB * cL;
constexpr size_t OFF_OP   = OFF_NORM + SZ_NORM;        // gemm partials[40][312][256]
constexpr size_t SZ_OP    = (size_t)GSPLIT * 312 * 256;
constexpr size_t OFF_CONV = OFF_OP + SZ_OP;            // exp(conv) bf16 [312][GK]
constexpr size_t SZ_CONV  = (size_t)312 * GK / 2;
constexpr size_t OFF_OWB  = OFF_CONV + SZ_CONV;        // out_w bf16 [256][GK]
constexpr size_t SZ_OWB   = (size_t)256 * GK / 2;
constexpr size_t WS_FLOATS = OFF_OWB + SZ_OWB;         // ~92 MB

__device__ inline u16 f2bf(float x) {
    union { float f; unsigned u; } v; v.f = x;
    unsigned r = v.u + 0x7fffu + ((v.u >> 16) & 1u);   // RNE
    return (u16)(r >> 16);
}

// ---------------------------------------------------------------------------
// K0a: cast out_w to bf16 with zero-padded K stride GK.
// ---------------------------------------------------------------------------
__global__ __launch_bounds__(256) void k_bwcast(const float* __restrict__ ow,
                                                u16* __restrict__ owb) {
    const int o = blockIdx.x;
    const float* src = ow + (size_t)o * cMM;
    u16* dst = owb + (size_t)o * GK;
    for (int k4 = threadIdx.x; k4 < GK / 4; k4 += 256) {
        const int k = k4 * 4;
        ushort4_t v;
        if (k < cMM) {   // cMM % 4 == 0
            const float4 f = *(const float4*)(src + k);
            v.x = f2bf(f.x); v.y = f2bf(f.y); v.z = f2bf(f.z); v.w = f2bf(f.w);
        } else {
            v.x = 0; v.y = 0; v.z = 0; v.w = 0;
        }
        *(ushort4_t*)(dst + k) = v;
    }
}

// K0b: zero the K-pad of conv A matrix (cols cMM..GK of 312 rows).
__global__ __launch_bounds__(256) void k_zpad(u16* __restrict__ cv) {
    u16* p = cv + (size_t)blockIdx.x * GK + cMM;
    for (int i = threadIdx.x; i < GK - cMM; i += 256) p[i] = 0;
}

// ---------------------------------------------------------------------------
// K1: partial gram. scores[b,i,j] = sum_f hs[b,i,f]*hs[b,j,f]  (scale later)
// ---------------------------------------------------------------------------
__global__ __launch_bounds__(256) void k_gram(const float* __restrict__ hs,
                                              float* __restrict__ sp) {
    const int b   = blockIdx.y;
    const int kc  = blockIdx.x;
    const int tid = threadIdx.x;
    __shared__ float lds[64][42];

    if (tid < 128) lds[tid >> 1][39 + (tid & 1)] = 0.f;
    __syncthreads();

    float acc0[2][2] = {{0.f,0.f},{0.f,0.f}};
    float acc1[2][2] = {{0.f,0.f},{0.f,0.f}};
    const int t0  = tid;
    const int t1v = tid + 256;
    const int t1  = (t1v < 400) ? t1v : 0;
    const int ti0 = t0 / 20, tj0 = t0 % 20;
    const int ti1 = t1 / 20, tj1 = t1 % 20;
    const float* hb = hs + (size_t)b * (cL * cDD);
    const int kbase = kc * 1024;

    for (int s = 0; s < 16; ++s) {
        const int k0 = kbase + s * 64;
        for (int idx = tid; idx < cL * 64; idx += 256) {
            const int j = idx >> 6, kk = idx & 63;
            lds[kk][j] = hb[(size_t)j * cDD + k0 + kk];
        }
        __syncthreads();
        #pragma unroll 4
        for (int kk = 0; kk < 64; ++kk) {
            const float2 ai = *(const float2*)&lds[kk][2*ti0];
            const float2 aj = *(const float2*)&lds[kk][2*tj0];
            acc0[0][0] = fmaf(ai.x, aj.x, acc0[0][0]);
            acc0[0][1] = fmaf(ai.x, aj.y, acc0[0][1]);
            acc0[1][0] = fmaf(ai.y, aj.x, acc0[1][0]);
            acc0[1][1] = fmaf(ai.y, aj.y, acc0[1][1]);
            const float2 bi = *(const float2*)&lds[kk][2*ti1];
            const float2 bj = *(const float2*)&lds[kk][2*tj1];
            acc1[0][0] = fmaf(bi.x, bj.x, acc1[0][0]);
            acc1[0][1] = fmaf(bi.x, bj.y, acc1[0][1]);
            acc1[1][0] = fmaf(bi.y, bj.x, acc1[1][0]);
            acc1[1][1] = fmaf(bi.y, bj.y, acc1[1][1]);
        }
        __syncthreads();
    }

    float* outp = sp + ((size_t)b * KCHUNKS + kc) * PAIRS;
    {
        const int r = 2*ti0, c = 2*tj0;
        if (r   < cL && c   < cL) outp[r*cL + c]       = acc0[0][0];
        if (r   < cL && c+1 < cL) outp[r*cL + c+1]     = acc0[0][1];
        if (r+1 < cL && c   < cL) outp[(r+1)*cL + c]   = acc0[1][0];
        if (r+1 < cL && c+1 < cL) outp[(r+1)*cL + c+1] = acc0[1][1];
    }
    if (t1v < 400) {
        const int r = 2*ti1, c = 2*tj1;
        if (r   < cL && c   < cL) outp[r*cL + c]       = acc1[0][0];
        if (r   < cL && c+1 < cL) outp[r*cL + c+1]     = acc1[0][1];
        if (r+1 < cL && c   < cL) outp[(r+1)*cL + c]   = acc1[1][0];
        if (r+1 < cL && c+1 < cL) outp[(r+1)*cL + c+1] = acc1[1][1];
    }
}

// ---------------------------------------------------------------------------
// K2: reduce gram partials, scale 1/256, row softmax.
// ---------------------------------------------------------------------------
__global__ __launch_bounds__(256) void k_softmax(const float* __restrict__ sp,
                                                 float* __restrict__ attnWs,
                                                 float* __restrict__ outAttn) {
    const int b = blockIdx.x;
    const int tid = threadIdx.x;
    __shared__ float sc[PAIRS];
    for (int idx = tid; idx < PAIRS; idx += 256) {
        float s = 0.f;
        for (int c = 0; c < KCHUNKS; ++c)
            s += sp[((size_t)b * KCHUNKS + c) * PAIRS + idx];
        sc[idx] = s * (1.0f / 256.0f);
    }
    __syncthreads();
    if (tid < cL) {
        const int i = tid;
        float m = -1e30f;
        #pragma unroll
        for (int j = 0; j < cL; ++j) m = fmaxf(m, sc[i*cL + j]);
        float e[cL];
        float sum = 0.f;
        #pragma unroll
        for (int j = 0; j < cL; ++j) { e[j] = expf(sc[i*cL + j] - m); sum += e[j]; }
        const float inv = 1.0f / sum;
        #pragma unroll
        for (int j = 0; j < cL; ++j) {
            const float a = e[j] * inv;
            attnWs [(size_t)b*PAIRS + i*cL + j] = a;
            outAttn[(size_t)b*PAIRS + i*cL + j] = a;
        }
    }
}

// ---------------------------------------------------------------------------
// K3: fold attention into conv weights -> bf16 MFMA A-layout.
// ---------------------------------------------------------------------------
__global__ __launch_bounds__(1024) void k_wtrans(const float* __restrict__ cw,
                                                 const float* __restrict__ attn,
                                                 u16* __restrict__ w2g) {
    const int b = blockIdx.x;
    const int t = threadIdx.x;
    __shared__ float at[PAIRS];
    for (int idx = t; idx < PAIRS; idx += 1024)
        at[idx] = attn[(size_t)b*PAIRS + idx];
    __syncthreads();
    if (t < cL * 25) {
        const int oc = t / 25, tap = t % 25;
        float c[cL];
        #pragma unroll
        for (int i = 0; i < cL; ++i)
            c[i] = cw[(size_t)oc * (cL*25) + i*25 + tap];
        u16* dst = w2g + (((size_t)b*25 + tap)*48 + oc)*64;
        for (int j = 0; j < cL; ++j) {
            float a = 0.f;
            #pragma unroll
            for (int i = 0; i < cL; ++i) a = fmaf(c[i], at[i*cL + j], a);
            dst[j] = f2bf(a);
        }
        for (int j = cL; j < 64; ++j) dst[j] = 0;
    } else if (t < cL * 25 + 25) {
        const int tap = t - cL * 25;
        u16* dst = w2g + (((size_t)b*25 + tap)*48 + cL)*64;
        for (int k = 0; k < 9*64; ++k) dst[k] = 0;
    }
}

// ---------------------------------------------------------------------------
// K4: conv as 25 shifted MFMA-GEMMs; outputs exp(conv) as bf16 (tril'd).
// ---------------------------------------------------------------------------
__global__ __launch_bounds__(256) void k_conv(const float* __restrict__ hs,
                                              const u16* __restrict__ w2g,
                                              const float* __restrict__ cb,
                                              u16* __restrict__ convout,
                                              float* __restrict__ tileSumsq) {
    const int b   = blockIdx.z;
    const int gh0 = blockIdx.y * 16, gw0 = blockIdx.x * 16;
    const int tid = threadIdx.x;
    const int wv  = tid >> 6;
    const int ln15 = tid & 15;
    const int kg4  = (tid & 63) >> 4;

    __shared__ u16 P[400 * 64];       // 51.2 KB
    __shared__ float red[4][48];

    const float* hb = hs + (size_t)b * (cL * cDD);
    for (int ic = 0; ic < cL; ++ic) {
        const float* hc = hb + (size_t)ic * cDD;
        for (int p = tid; p < 400; p += 256) {
            const int pr = p / 20, pc = p % 20;
            const int gh = gh0 + pr, gw = gw0 + pc;
            const float v = (gh < cD && gw < cD) ? hc[gh*cD + gw] : 0.f;
            const int slot = (ic >> 3) ^ (p & 7);
            P[p*64 + slot*8 + (ic & 7)] = f2bf(v);
        }
    }
    for (int s = cL; s < 64; ++s)
        for (int p = tid; p < 400; p += 256)
            P[p*64 + (((s >> 3) ^ (p & 7))*8) + (s & 7)] = 0;
    __syncthreads();

    f32x4 acc[3][4] = {};
    const u16* wb = w2g + ((size_t)b * 25) * 48 * 64;

    for (int kh = 0; kh < 5; ++kh) {
        for (int kw = 0; kw < 5; ++kw) {
            const int tap = kh*5 + kw;
            const u16* wt = wb + (size_t)tap * 48 * 64;
            short8 afr[3][2];
            #pragma unroll
            for (int o = 0; o < 3; ++o)
                #pragma unroll
                for (int kc = 0; kc < 2; ++kc)
                    afr[o][kc] = *(const short8*)(wt + (o*16 + ln15)*64 + kc*32 + kg4*8);
            #pragma unroll
            for (int pt = 0; pt < 4; ++pt) {
                const int p = (wv*4 + pt + kh)*20 + ln15 + kw;
                #pragma unroll
                for (int kc = 0; kc < 2; ++kc) {
                    const int slot = (kc*4 + kg4) ^ (p & 7);
                    const short8 bfr = *(const short8*)&P[p*64 + slot*8];
                    #pragma unroll
                    for (int o = 0; o < 3; ++o)
                        acc[o][pt] = __builtin_amdgcn_mfma_f32_16x16x32_bf16(
                            afr[o][kc], bfr, acc[o][pt], 0, 0, 0);
                }
            }
        }
    }

    float ss[3][4];
    #pragma unroll
    for (int o = 0; o < 3; ++o)
        #pragma unroll
        for (int r = 0; r < 4; ++r) ss[o][r] = 0.f;

    const int ow = gw0 + ln15;
    #pragma unroll
    for (int o = 0; o < 3; ++o) {
        #pragma unroll
        for (int r = 0; r < 4; ++r) {
            const int oc = o*16 + kg4*4 + r;
            const float bias = (oc < cL) ? cb[oc] : 0.f;
            #pragma unroll
            for (int pt = 0; pt < 4; ++pt) {
                const int oh = gh0 + wv*4 + pt;
                if (oc < cL && oh < cM && ow < cM) {
                    const float e = __expf(acc[o][pt][r] + bias);
                    convout[((size_t)(b*cL + oc))*GK + oh*cM + ow] = f2bf((ow <= oh) ? e : 0.f);
                    ss[o][r] += e * e;
                }
            }
        }
    }

    #pragma unroll
    for (int o = 0; o < 3; ++o) {
        #pragma unroll
        for (int r = 0; r < 4; ++r) {
            float v = ss[o][r];
            v += __shfl_xor(v, 1);
            v += __shfl_xor(v, 2);
            v += __shfl_xor(v, 4);
            v += __shfl_xor(v, 8);
            if (ln15 == 0) red[wv][o*16 + kg4*4 + r] = v;
        }
    }
    __syncthreads();
    if (tid < cL) {
        const int tileIdx = blockIdx.y * 16 + blockIdx.x;
        tileSumsq[((size_t)b*256 + tileIdx)*cL + tid] =
            red[0][tid] + red[1][tid] + red[2][tid] + red[3][tid];
    }
}

// ---------------------------------------------------------------------------
// K4b: norms[row] = sqrt(sum over 256 tiles).
// ---------------------------------------------------------------------------
__global__ __launch_bounds__(256) void k_norm(const float* __restrict__ ts,
                                              float* __restrict__ norms) {
    const int row = blockIdx.x;
    const int b = row / cL, l = row % cL;
    const int tid = threadIdx.x;
    float v = ts[((size_t)b*256 + tid)*cL + l];
    for (int off = 32; off; off >>= 1) v += __shfl_down(v, off, 64);
    __shared__ float r[4];
    if ((tid & 63) == 0) r[tid >> 6] = v;
    __syncthreads();
    if (tid == 0) norms[row] = sqrtf(r[0] + r[1] + r[2] + r[3]);
}

// ---------------------------------------------------------------------------
// K5: bf16 MFMA out-GEMM. C[row,o] partials over K-split.
// grid (Nt=2, Mt=5, Z=40), 512 thr, block tile 64x128, wave tile 32x32.
// Reg-staged double-buffered LDS pipeline; LDS row stride 72 u16.
// ---------------------------------------------------------------------------
__global__ __launch_bounds__(512) void k_gemm(const u16* __restrict__ A,
                                              const u16* __restrict__ Bw,
                                              float* __restrict__ op) {
    const int nt = blockIdx.x;
    const int mt = blockIdx.y;
    const int z  = blockIdx.z;
    const int tid = threadIdx.x;
    const int wid = tid >> 6, lane = tid & 63;
    const int ln15 = lane & 15, kg4 = lane >> 4;
    const int wm = wid >> 2, wn = wid & 3;

    __shared__ u16 As[2][64*72];
    __shared__ u16 Bs[2][128*72];

    const int mbase = mt * 64, nbase = nt * 128;
    const int ar = tid >> 3, asl = tid & 7;

    const int arow = mbase + ar;
    const bool aval = (arow < 312);
    const u16* Ap  = A  + (size_t)(aval ? arow : 0) * GK + z*CHUNK + asl*8;
    const u16* Bp0 = Bw + (size_t)(nbase + ar)      * GK + z*CHUNK + asl*8;
    const u16* Bp1 = Bw + (size_t)(nbase + 64 + ar) * GK + z*CHUNK + asl*8;

    short8 zz = {};
    short8 ra = aval ? *(const short8*)Ap : zz;
    short8 rb0 = *(const short8*)Bp0;
    short8 rb1 = *(const short8*)Bp1;

    f32x4 acc[2][2] = {};

    for (int s = 0; s < NSTEPS; ++s) {
        const int cur = s & 1;
        __syncthreads();
        *(short8*)&As[cur][ar*72 + asl*8]      = ra;
        *(short8*)&Bs[cur][ar*72 + asl*8]      = rb0;
        *(short8*)&Bs[cur][(64+ar)*72 + asl*8] = rb1;
        __syncthreads();
        if (s + 1 < NSTEPS) {
            const int off = (s + 1) * 64;
            ra  = aval ? *(const short8*)(Ap + off) : zz;
            rb0 = *(const short8*)(Bp0 + off);
            rb1 = *(const short8*)(Bp1 + off);
        }
        #pragma unroll
        for (int kc = 0; kc < 2; ++kc) {
            short8 af[2], bf[2];
            #pragma unroll
            for (int fm = 0; fm < 2; ++fm)
                af[fm] = *(const short8*)&As[cur][(wm*32 + fm*16 + ln15)*72 + kc*32 + kg4*8];
            #pragma unroll
            for (int fn = 0; fn < 2; ++fn)
                bf[fn] = *(const short8*)&Bs[cur][(wn*32 + fn*16 + ln15)*72 + kc*32 + kg4*8];
            #pragma unroll
            for (int fm = 0; fm < 2; ++fm)
                #pragma unroll
                for (int fn = 0; fn < 2; ++fn)
                    acc[fm][fn] = __builtin_amdgcn_mfma_f32_16x16x32_bf16(
                        af[fm], bf[fn], acc[fm][fn], 0, 0, 0);
        }
    }

    #pragma unroll
    for (int fm = 0; fm < 2; ++fm) {
        #pragma unroll
        for (int r = 0; r < 4; ++r) {
            const int row = mbase + wm*32 + fm*16 + kg4*4 + r;
            if (row < 312) {
                #pragma unroll
                for (int fn = 0; fn < 2; ++fn) {
                    const int col = nbase + wn*32 + fn*16 + ln15;
                    op[((size_t)z*312 + row)*256 + col] = acc[fm][fn][r];
                }
            }
        }
    }
}

// ---------------------------------------------------------------------------
// K5b: reduce K-split partials, divide by norm, write out.
// ---------------------------------------------------------------------------
__global__ __launch_bounds__(256) void k_finish(const float* __restrict__ op,
                                                const float* __restrict__ norms,
                                                float* __restrict__ out) {
    const int idx = blockIdx.x * 256 + threadIdx.x;
    float s = 0.f;
    for (int z = 0; z < GSPLIT; ++z) s += op[(size_t)z * (312*256) + idx];
    out[idx] = s / norms[idx >> 8];
}

// ---------------------------------------------------------------------------
extern "C" void kernel_launch(void* const* d_in, const int* in_sizes, int n_in,
                              void* d_out, int out_size, void* d_ws, size_t ws_size,
                              hipStream_t stream) {
    const float* hs = (const float*)d_in[0];
    const float* cw = (const float*)d_in[1];
    const float* cb = (const float*)d_in[2];
    const float* ow = (const float*)d_in[3];
    float* out = (float*)d_out;
    float* ws  = (float*)d_ws;

    if (ws_size < WS_FLOATS * sizeof(float)) return;

    float* sp   = ws + OFF_SP;
    float* attn = ws + OFF_ATTN;
    u16*   w2g  = (u16*)(ws + OFF_W2);
    float* ts   = ws + OFF_TS;
    float* nrm  = ws + OFF_NORM;
    float* op   = ws + OFF_OP;
    u16*   cv   = (u16*)(ws + OFF_CONV);
    u16*   owb  = (u16*)(ws + OFF_OWB);

    k_bwcast <<<256, 256, 0, stream>>>(ow, owb);
    k_zpad   <<<312, 256, 0, stream>>>(cv);
    k_gram   <<<dim3(KCHUNKS, cB), 256, 0, stream>>>(hs, sp);
    k_softmax<<<cB, 256, 0, stream>>>(sp, attn, out + (size_t)cB*cL*cD);
    k_wtrans <<<cB, 1024, 0, stream>>>(cw, attn, w2g);
    k_conv   <<<dim3(16, 16, cB), 256, 0, stream>>>(hs, w2g, cb, cv, ts);
    k_norm   <<<cB*cL, 256, 0, stream>>>(ts, nrm);
    k_gemm   <<<dim3(2, 5, GSPLIT), 512, 0, stream>>>(cv, owb, op);
    k_finish <<<312, 256, 0, stream>>>(op, nrm, out);
}

// Round 4
// 445.808 us; speedup vs baseline: 3.2544x; 1.1529x over previous
//
#include <hip/hip_runtime.h>
#include <math.h>

typedef unsigned short u16;
typedef unsigned char  u8;
typedef __attribute__((ext_vector_type(8))) short short8;
typedef __attribute__((ext_vector_type(4))) float f32x4;
typedef __attribute__((ext_vector_type(4))) unsigned short ushort4_t;

// GeoMamba: B=8, L=39, D=256, K=5, M=252
constexpr int cB   = 8;
constexpr int cL   = 39;
constexpr int cD   = 256;
constexpr int cDD  = 65536;   // D*D
constexpr int cM   = 252;
constexpr int cMM  = 63504;   // M*M
constexpr int PAIRS = cL * cL; // 1521

constexpr int KCHUNKS = 64;    // gram K-split
constexpr int GKP     = 64000; // padded K for out-gemm (fp8 bytes per row)
constexpr int CSTEP   = 512;   // K per gemm block
constexpr int GSPLIT  = 125;   // 125*512 = 64000

// ---- ws layout (float offsets) ----
constexpr size_t OFF_SP   = 0;                          // gram partials [B][KCHUNKS][1521]
constexpr size_t SZ_SP    = (size_t)cB * KCHUNKS * PAIRS;   // 778752
constexpr size_t OFF_TS   = 0;                          // overlaps SP (dead after softmax)
constexpr size_t OFF_NORM = OFF_TS + (size_t)cB * 256 * cL; // 79872
constexpr size_t OFF_ATTN = OFF_SP + SZ_SP;
constexpr size_t SZ_ATTN  = (size_t)cB * PAIRS;
constexpr size_t OFF_W2   = OFF_ATTN + SZ_ATTN;         // folded wts bf16 [B][tap][oc48][ic64]
constexpr size_t SZ_W2    = (size_t)cB * 25 * 48 * 64 / 2;
constexpr size_t OFF_HSTOP = OFF_W2 + SZ_W2;            // hst bf16 [B][65536][40] (+slack) / gemm partials
constexpr size_t SZ_HST   = ((size_t)cB * 65536 * 40 + 4096) / 2;      // floats
constexpr size_t SZ_OP    = (size_t)GSPLIT * 312 * 256;                // floats
constexpr size_t SZ_HSTOP = SZ_HST > SZ_OP ? SZ_HST : SZ_OP;
constexpr size_t OFF_CONV = OFF_HSTOP + SZ_HSTOP;       // exp(conv) fp8 [312][GKP]
constexpr size_t SZ_CONV  = (size_t)312 * GKP / 4;      // floats
constexpr size_t OFF_OWB  = OFF_CONV + SZ_CONV;         // out_w fp8*256 [256][GKP]
constexpr size_t SZ_OWB   = (size_t)256 * GKP / 4;
constexpr size_t WS_FLOATS = OFF_OWB + SZ_OWB;          // ~82.7 MB

__device__ inline u16 f2bf(float x) {
    union { float f; unsigned u; } v; v.f = x;
    unsigned r = v.u + 0x7fffu + ((v.u >> 16) & 1u);   // RNE
    return (u16)(r >> 16);
}
__device__ inline u8 f2fp8(float x) {
    return (u8)(__builtin_amdgcn_cvt_pk_fp8_f32(x, x, 0, false) & 0xff);
}

// ---------------------------------------------------------------------------
// K0a: cast out_w*256 -> fp8 e4m3, zero-padded K stride GKP.
// ---------------------------------------------------------------------------
__global__ __launch_bounds__(256) void k_bwcast(const float* __restrict__ ow,
                                                u8* __restrict__ owb) {
    const int o = blockIdx.x;
    const float* src = ow + (size_t)o * cMM;
    u8* dst = owb + (size_t)o * GKP;
    for (int k4 = threadIdx.x; k4 < GKP / 4; k4 += 256) {
        const int k = k4 * 4;
        unsigned r = 0;
        if (k < cMM) {   // cMM % 4 == 0
            const float4 f = *(const float4*)(src + k);
            unsigned lo = (unsigned)__builtin_amdgcn_cvt_pk_fp8_f32(f.x*256.f, f.y*256.f, 0, false);
            unsigned hi = (unsigned)__builtin_amdgcn_cvt_pk_fp8_f32(f.z*256.f, f.w*256.f, 0, false);
            r = (lo & 0xffffu) | (hi << 16);
        }
        *(unsigned*)(dst + k) = r;
    }
}

// K0b: zero the K-pad of conv A matrix (cols cMM..GKP of 312 rows).
__global__ __launch_bounds__(256) void k_zpad(u8* __restrict__ cv) {
    u8* p = cv + (size_t)blockIdx.x * GKP + cMM;
    for (int i = threadIdx.x; i < GKP - cMM; i += 256) p[i] = 0;
}

// ---------------------------------------------------------------------------
// K0c: transpose hs -> hst[b][pix][40] bf16 (ic 0..38 + one zero pad).
// ---------------------------------------------------------------------------
__global__ __launch_bounds__(256) void k_hst(const float* __restrict__ hs,
                                             u16* __restrict__ hst) {
    const int b = blockIdx.y;
    const int t = threadIdx.x;
    const int pix0 = blockIdx.x * 256;
    __shared__ u16 T[256 * 44];
    const float* hb = hs + (size_t)b * cL * cDD + pix0 + t;
    for (int ic = 0; ic < cL; ++ic)
        T[t*44 + ic] = f2bf(hb[(size_t)ic * cDD]);
    T[t*44 + cL] = 0;
    __syncthreads();
    u16* ob = hst + (size_t)b * (65536*40) + (size_t)pix0 * 40;
    for (int c = t; c < 1280; c += 256) {     // 5 iters: chunk c = pix*5+g
        const int pix = c / 5, g = c - pix*5;
        const ushort4_t lo = *(const ushort4_t*)&T[pix*44 + g*8];
        const ushort4_t hi = *(const ushort4_t*)&T[pix*44 + g*8 + 4];
        *(ushort4_t*)(ob + (size_t)c*8)     = lo;
        *(ushort4_t*)(ob + (size_t)c*8 + 4) = hi;
    }
}

// ---------------------------------------------------------------------------
// K1: partial gram. scores[b,i,j] = sum_f hs[b,i,f]*hs[b,j,f]  (scale later)
// ---------------------------------------------------------------------------
__global__ __launch_bounds__(256) void k_gram(const float* __restrict__ hs,
                                              float* __restrict__ sp) {
    const int b   = blockIdx.y;
    const int kc  = blockIdx.x;
    const int tid = threadIdx.x;
    __shared__ float lds[64][42];

    if (tid < 128) lds[tid >> 1][39 + (tid & 1)] = 0.f;
    __syncthreads();

    float acc0[2][2] = {{0.f,0.f},{0.f,0.f}};
    float acc1[2][2] = {{0.f,0.f},{0.f,0.f}};
    const int t0  = tid;
    const int t1v = tid + 256;
    const int t1  = (t1v < 400) ? t1v : 0;
    const int ti0 = t0 / 20, tj0 = t0 % 20;
    const int ti1 = t1 / 20, tj1 = t1 % 20;
    const float* hb = hs + (size_t)b * (cL * cDD);
    const int kbase = kc * 1024;

    for (int s = 0; s < 16; ++s) {
        const int k0 = kbase + s * 64;
        for (int idx = tid; idx < cL * 64; idx += 256) {
            const int j = idx >> 6, kk = idx & 63;
            lds[kk][j] = hb[(size_t)j * cDD + k0 + kk];
        }
        __syncthreads();
        #pragma unroll 4
        for (int kk = 0; kk < 64; ++kk) {
            const float2 ai = *(const float2*)&lds[kk][2*ti0];
            const float2 aj = *(const float2*)&lds[kk][2*tj0];
            acc0[0][0] = fmaf(ai.x, aj.x, acc0[0][0]);
            acc0[0][1] = fmaf(ai.x, aj.y, acc0[0][1]);
            acc0[1][0] = fmaf(ai.y, aj.x, acc0[1][0]);
            acc0[1][1] = fmaf(ai.y, aj.y, acc0[1][1]);
            const float2 bi = *(const float2*)&lds[kk][2*ti1];
            const float2 bj = *(const float2*)&lds[kk][2*tj1];
            acc1[0][0] = fmaf(bi.x, bj.x, acc1[0][0]);
            acc1[0][1] = fmaf(bi.x, bj.y, acc1[0][1]);
            acc1[1][0] = fmaf(bi.y, bj.x, acc1[1][0]);
            acc1[1][1] = fmaf(bi.y, bj.y, acc1[1][1]);
        }
        __syncthreads();
    }

    float* outp = sp + ((size_t)b * KCHUNKS + kc) * PAIRS;
    {
        const int r = 2*ti0, c = 2*tj0;
        if (r   < cL && c   < cL) outp[r*cL + c]       = acc0[0][0];
        if (r   < cL && c+1 < cL) outp[r*cL + c+1]     = acc0[0][1];
        if (r+1 < cL && c   < cL) outp[(r+1)*cL + c]   = acc0[1][0];
        if (r+1 < cL && c+1 < cL) outp[(r+1)*cL + c+1] = acc0[1][1];
    }
    if (t1v < 400) {
        const int r = 2*ti1, c = 2*tj1;
        if (r   < cL && c   < cL) outp[r*cL + c]       = acc1[0][0];
        if (r   < cL && c+1 < cL) outp[r*cL + c+1]     = acc1[0][1];
        if (r+1 < cL && c   < cL) outp[(r+1)*cL + c]   = acc1[1][0];
        if (r+1 < cL && c+1 < cL) outp[(r+1)*cL + c+1] = acc1[1][1];
    }
}

// ---------------------------------------------------------------------------
// K2: reduce gram partials, scale 1/256, row softmax.
// ---------------------------------------------------------------------------
__global__ __launch_bounds__(256) void k_softmax(const float* __restrict__ sp,
                                                 float* __restrict__ attnWs,
                                                 float* __restrict__ outAttn) {
    const int b = blockIdx.x;
    const int tid = threadIdx.x;
    __shared__ float sc[PAIRS];
    for (int idx = tid; idx < PAIRS; idx += 256) {
        float s = 0.f;
        for (int c = 0; c < KCHUNKS; ++c)
            s += sp[((size_t)b * KCHUNKS + c) * PAIRS + idx];
        sc[idx] = s * (1.0f / 256.0f);
    }
    __syncthreads();
    if (tid < cL) {
        const int i = tid;
        float m = -1e30f;
        #pragma unroll
        for (int j = 0; j < cL; ++j) m = fmaxf(m, sc[i*cL + j]);
        float e[cL];
        float sum = 0.f;
        #pragma unroll
        for (int j = 0; j < cL; ++j) { e[j] = expf(sc[i*cL + j] - m); sum += e[j]; }
        const float inv = 1.0f / sum;
        #pragma unroll
        for (int j = 0; j < cL; ++j) {
            const float a = e[j] * inv;
            attnWs [(size_t)b*PAIRS + i*cL + j] = a;
            outAttn[(size_t)b*PAIRS + i*cL + j] = a;
        }
    }
}

// ---------------------------------------------------------------------------
// K3: fold attention into conv weights -> bf16 MFMA A-layout.
// ---------------------------------------------------------------------------
__global__ __launch_bounds__(1024) void k_wtrans(const float* __restrict__ cw,
                                                 const float* __restrict__ attn,
                                                 u16* __restrict__ w2g) {
    const int b = blockIdx.x;
    const int t = threadIdx.x;
    __shared__ float at[PAIRS];
    for (int idx = t; idx < PAIRS; idx += 1024)
        at[idx] = attn[(size_t)b*PAIRS + idx];
    __syncthreads();
    if (t < cL * 25) {
        const int oc = t / 25, tap = t % 25;
        float c[cL];
        #pragma unroll
        for (int i = 0; i < cL; ++i)
            c[i] = cw[(size_t)oc * (cL*25) + i*25 + tap];
        u16* dst = w2g + (((size_t)b*25 + tap)*48 + oc)*64;
        for (int j = 0; j < cL; ++j) {
            float a = 0.f;
            #pragma unroll
            for (int i = 0; i < cL; ++i) a = fmaf(c[i], at[i*cL + j], a);
            dst[j] = f2bf(a);
        }
        for (int j = cL; j < 64; ++j) dst[j] = 0;
    } else if (t < cL * 25 + 25) {
        const int tap = t - cL * 25;
        u16* dst = w2g + (((size_t)b*25 + tap)*48 + cL)*64;
        for (int k = 0; k < 9*64; ++k) dst[k] = 0;
    }
}

// ---------------------------------------------------------------------------
// K4: conv as 25 shifted MFMA-GEMMs; stages from pre-transposed hst;
// outputs exp(conv) as fp8 (tril'd) + per-tile sumsq.
// ---------------------------------------------------------------------------
constexpr int ZOFF = 400 * 64;   // 16B zero block at end of P

__global__ __launch_bounds__(256) void k_conv(const u16* __restrict__ hst,
                                              const u16* __restrict__ w2g,
                                              const float* __restrict__ cb,
                                              u8* __restrict__ convout,
                                              float* __restrict__ tileSumsq) {
    const int b   = blockIdx.z;
    const int gh0 = blockIdx.y * 16, gw0 = blockIdx.x * 16;
    const int tid = threadIdx.x;
    const int wv  = tid >> 6;
    const int ln15 = tid & 15;
    const int kg4  = (tid & 63) >> 4;

    __shared__ u16 P[400 * 64 + 16];
    __shared__ float red[4][48];

    // ---- stage 20x20 patch (all 39+1 ic, XOR-swizzled 16B slots) ----
    const u16* hb = hst + (size_t)b * (65536 * 40);
    for (int c = tid; c < 2000; c += 256) {            // chunk = (pixel, group)
        const int p = c / 5, g = c - p*5;
        const int pr = p / 20, pc = p - pr*20;
        const int gh = min(gh0 + pr, 255);
        const int pix = gh * 256 + gw0 + pc;           // may spill; slack covers
        const short8 v = *(const short8*)(hb + (size_t)pix*40 + g*8);
        *(short8*)&P[p*64 + ((g ^ (p & 7)) * 8)] = v;
    }
    if (tid < 8) P[ZOFF + tid] = 0;
    __syncthreads();

    // ---- main loop: 25 taps x 2 K-chunks, MFMA 16x16x32 bf16 ----
    f32x4 acc[3][4] = {};
    const u16* wb = w2g + ((size_t)b * 25) * 48 * 64;

    for (int kh = 0; kh < 5; ++kh) {
        for (int kw = 0; kw < 5; ++kw) {
            const int tap = kh*5 + kw;
            const u16* wt = wb + (size_t)tap * 48 * 64;
            short8 afr[3][2];
            #pragma unroll
            for (int o = 0; o < 3; ++o)
                #pragma unroll
                for (int kc = 0; kc < 2; ++kc)
                    afr[o][kc] = *(const short8*)(wt + (o*16 + ln15)*64 + kc*32 + kg4*8);
            #pragma unroll
            for (int pt = 0; pt < 4; ++pt) {
                const int p = (wv*4 + pt + kh)*20 + ln15 + kw;
                const int px7 = p & 7;
                {   // kc = 0: groups 0..3, all real
                    const short8 bfr = *(const short8*)&P[p*64 + ((kg4 ^ px7) * 8)];
                    #pragma unroll
                    for (int o = 0; o < 3; ++o)
                        acc[o][pt] = __builtin_amdgcn_mfma_f32_16x16x32_bf16(
                            afr[o][0], bfr, acc[o][pt], 0, 0, 0);
                }
                {   // kc = 1: group 4 real (kg4==0), rest zero block
                    const int off = (kg4 == 0) ? (p*64 + ((4 ^ px7) * 8)) : ZOFF;
                    const short8 bfr = *(const short8*)&P[off];
                    #pragma unroll
                    for (int o = 0; o < 3; ++o)
                        acc[o][pt] = __builtin_amdgcn_mfma_f32_16x16x32_bf16(
                            afr[o][1], bfr, acc[o][pt], 0, 0, 0);
                }
            }
        }
    }

    // ---- epilogue: bias + exp, tril fp8 store, sum-of-squares ----
    float ss[3][4];
    #pragma unroll
    for (int o = 0; o < 3; ++o)
        #pragma unroll
        for (int r = 0; r < 4; ++r) ss[o][r] = 0.f;

    const int ow = gw0 + ln15;
    #pragma unroll
    for (int o = 0; o < 3; ++o) {
        #pragma unroll
        for (int r = 0; r < 4; ++r) {
            const int oc = o*16 + kg4*4 + r;
            const float bias = (oc < cL) ? cb[oc] : 0.f;
            #pragma unroll
            for (int pt = 0; pt < 4; ++pt) {
                const int oh = gh0 + wv*4 + pt;
                if (oc < cL && oh < cM && ow < cM) {
                    const float e = __expf(acc[o][pt][r] + bias);
                    convout[(size_t)(b*cL + oc)*GKP + oh*cM + ow] =
                        (ow <= oh) ? f2fp8(e) : (u8)0;
                    ss[o][r] += e * e;
                }
            }
        }
    }

    #pragma unroll
    for (int o = 0; o < 3; ++o) {
        #pragma unroll
        for (int r = 0; r < 4; ++r) {
            float v = ss[o][r];
            v += __shfl_xor(v, 1);
            v += __shfl_xor(v, 2);
            v += __shfl_xor(v, 4);
            v += __shfl_xor(v, 8);
            if (ln15 == 0) red[wv][o*16 + kg4*4 + r] = v;
        }
    }
    __syncthreads();
    if (tid < cL) {
        const int tileIdx = blockIdx.y * 16 + blockIdx.x;
        tileSumsq[((size_t)b*256 + tileIdx)*cL + tid] =
            red[0][tid] + red[1][tid] + red[2][tid] + red[3][tid];
    }
}

// ---------------------------------------------------------------------------
// K4b: norms[row] = sqrt(sum over 256 tiles).
// ---------------------------------------------------------------------------
__global__ __launch_bounds__(256) void k_norm(const float* __restrict__ ts,
                                              float* __restrict__ norms) {
    const int row = blockIdx.x;
    const int b = row / cL, l = row % cL;
    const int tid = threadIdx.x;
    float v = ts[((size_t)b*256 + tid)*cL + l];
    for (int off = 32; off; off >>= 1) v += __shfl_down(v, off, 64);
    __shared__ float r[4];
    if ((tid & 63) == 0) r[tid >> 6] = v;
    __syncthreads();
    if (tid == 0) norms[row] = sqrtf(r[0] + r[1] + r[2] + r[3]);
}

// ---------------------------------------------------------------------------
// K5: fp8 MFMA out-GEMM. grid (1, 3, 125), 512 thr; block tile 128x256,
// wave tile 64x64; double-buffered LDS, rows padded to 80 B.
// ---------------------------------------------------------------------------
__global__ __launch_bounds__(512) void k_gemm(const u8* __restrict__ A,
                                              const u8* __restrict__ Bw,
                                              float* __restrict__ op) {
    const int mt = blockIdx.y, z = blockIdx.z;
    const int tid = threadIdx.x;
    const int wid = tid >> 6, lane = tid & 63;
    const int ln15 = lane & 15, kg4 = lane >> 4;
    const int wm = wid >> 2, wn = wid & 3;

    __shared__ u8 As[2][128*80];
    __shared__ u8 Bs[2][256*80];

    const int mbase = mt * 128;
    const int ra = tid >> 2, sl = tid & 3;      // 4 chunks of 16B per 64B row-step
    const int arow = mbase + ra;
    const int aro = (arow < 312) ? arow : 0;
    const u8* Ap  = A  + (size_t)aro * GKP        + z*CSTEP + sl*16;
    const u8* Bp0 = Bw + (size_t)ra * GKP         + z*CSTEP + sl*16;
    const u8* Bp1 = Bw + (size_t)(128 + ra) * GKP + z*CSTEP + sl*16;

    uint4 pa  = *(const uint4*)Ap;
    uint4 pb0 = *(const uint4*)Bp0;
    uint4 pb1 = *(const uint4*)Bp1;

    f32x4 acc[4][4] = {};

    for (int s = 0; s < CSTEP/64; ++s) {
        const int cur = s & 1;
        __syncthreads();
        *(uint4*)&As[cur][ra*80 + sl*16]        = pa;
        *(uint4*)&Bs[cur][ra*80 + sl*16]        = pb0;
        *(uint4*)&Bs[cur][(128 + ra)*80 + sl*16] = pb1;
        __syncthreads();
        if (s + 1 < CSTEP/64) {
            const int off = (s + 1) * 64;
            pa  = *(const uint4*)(Ap + off);
            pb0 = *(const uint4*)(Bp0 + off);
            pb1 = *(const uint4*)(Bp1 + off);
        }
        #pragma unroll
        for (int kc = 0; kc < 2; ++kc) {
            long af[4], bf[4];
            #pragma unroll
            for (int fm = 0; fm < 4; ++fm)
                af[fm] = *(const long*)&As[cur][(wm*64 + fm*16 + ln15)*80 + kc*32 + kg4*8];
            #pragma unroll
            for (int fn = 0; fn < 4; ++fn)
                bf[fn] = *(const long*)&Bs[cur][(wn*64 + fn*16 + ln15)*80 + kc*32 + kg4*8];
            #pragma unroll
            for (int fm = 0; fm < 4; ++fm)
                #pragma unroll
                for (int fn = 0; fn < 4; ++fn)
                    acc[fm][fn] = __builtin_amdgcn_mfma_f32_16x16x32_fp8_fp8(
                        af[fm], bf[fn], acc[fm][fn], 0, 0, 0);
        }
    }

    #pragma unroll
    for (int fm = 0; fm < 4; ++fm) {
        #pragma unroll
        for (int r = 0; r < 4; ++r) {
            const int row = mbase + wm*64 + fm*16 + kg4*4 + r;
            if (row < 312) {
                #pragma unroll
                for (int fn = 0; fn < 4; ++fn) {
                    const int col = wn*64 + fn*16 + ln15;
                    op[((size_t)z*312 + row)*256 + col] = acc[fm][fn][r];
                }
            }
        }
    }
}

// ---------------------------------------------------------------------------
// K5b: reduce K-split partials, divide by (norm*256), write out.
// ---------------------------------------------------------------------------
__global__ __launch_bounds__(256) void k_finish(const float* __restrict__ op,
                                                const float* __restrict__ norms,
                                                float* __restrict__ out) {
    const int idx = blockIdx.x * 256 + threadIdx.x;
    float s = 0.f;
    for (int z = 0; z < GSPLIT; ++z) s += op[(size_t)z * (312*256) + idx];
    out[idx] = s / (norms[idx >> 8] * 256.0f);
}

// ---------------------------------------------------------------------------
extern "C" void kernel_launch(void* const* d_in, const int* in_sizes, int n_in,
                              void* d_out, int out_size, void* d_ws, size_t ws_size,
                              hipStream_t stream) {
    const float* hs = (const float*)d_in[0];
    const float* cw = (const float*)d_in[1];
    const float* cb = (const float*)d_in[2];
    const float* ow = (const float*)d_in[3];
    float* out = (float*)d_out;
    float* ws  = (float*)d_ws;

    if (ws_size < WS_FLOATS * sizeof(float)) return;

    float* sp   = ws + OFF_SP;
    float* ts   = ws + OFF_TS;
    float* nrm  = ws + OFF_NORM;
    float* attn = ws + OFF_ATTN;
    u16*   w2g  = (u16*)(ws + OFF_W2);
    u16*   hst  = (u16*)(ws + OFF_HSTOP);
    float* op   = ws + OFF_HSTOP;
    u8*    cv   = (u8*)(ws + OFF_CONV);
    u8*    owb  = (u8*)(ws + OFF_OWB);

    k_hst    <<<dim3(256, cB), 256, 0, stream>>>(hs, hst);
    k_bwcast <<<256, 256, 0, stream>>>(ow, owb);
    k_zpad   <<<312, 256, 0, stream>>>(cv);
    k_gram   <<<dim3(KCHUNKS, cB), 256, 0, stream>>>(hs, sp);
    k_softmax<<<cB, 256, 0, stream>>>(sp, attn, out + (size_t)cB*cL*cD);
    k_wtrans <<<cB, 1024, 0, stream>>>(cw, attn, w2g);
    k_conv   <<<dim3(16, 16, cB), 256, 0, stream>>>(hst, w2g, cb, cv, ts);
    k_norm   <<<cB*cL, 256, 0, stream>>>(ts, nrm);
    k_gemm   <<<dim3(1, 3, GSPLIT), 512, 0, stream>>>(cv, owb, op);
    k_finish <<<312, 256, 0, stream>>>(op, nrm, out);
}

// Round 5
// 385.624 us; speedup vs baseline: 3.7623x; 1.1561x over previous
//
#include <hip/hip_runtime.h>
#include <math.h>

typedef unsigned short u16;
typedef unsigned int   u32;
typedef unsigned char  u8;
typedef __attribute__((ext_vector_type(8))) short short8;
typedef __attribute__((ext_vector_type(4))) float f32x4;
typedef __attribute__((ext_vector_type(4))) unsigned short ushort4_t;

// GeoMamba: B=8, L=39, D=256, K=5, M=252
constexpr int cB   = 8;
constexpr int cL   = 39;
constexpr int cD   = 256;
constexpr int cDD  = 65536;   // D*D
constexpr int cM   = 252;
constexpr int cMM  = 63504;   // M*M
constexpr int PAIRS = cL * cL; // 1521

constexpr int KCHUNKS = 64;    // gram K-split
constexpr int GKP     = 64000; // padded K for out-gemm (fp8 bytes per row)
constexpr int CSTEP   = 512;   // K per gemm block
constexpr int GSPLIT  = 125;   // 125*512 = 64000
constexpr int PROW    = 40;    // u16 per pixel row in conv LDS

// ---- ws layout (float offsets) ----
constexpr size_t OFF_SP   = 0;                          // gram partials [B][KCHUNKS][1521]
constexpr size_t SZ_SP    = (size_t)cB * KCHUNKS * PAIRS;
constexpr size_t OFF_TS   = 0;                          // overlaps SP (dead after softmax)
constexpr size_t OFF_NORM = OFF_TS + (size_t)cB * 256 * cL;
constexpr size_t OFF_ATTN = OFF_SP + SZ_SP;
constexpr size_t SZ_ATTN  = (size_t)cB * PAIRS;
constexpr size_t OFF_W2M  = OFF_ATTN + SZ_ATTN;         // main wts bf16 [B][tap25][oc48][32]
constexpr size_t SZ_W2M   = (size_t)cB * 25 * 48 * 32 / 2;
constexpr size_t OFF_W2T  = OFF_W2M + SZ_W2M;           // tail wts bf16 [B][kc7][oc48][32]
constexpr size_t SZ_W2T   = (size_t)cB * 7 * 48 * 32 / 2;
constexpr size_t OFF_HSTOP = OFF_W2T + SZ_W2T;          // hst bf16 [B][65536][40]+slack / gemm partials
constexpr size_t SZ_HST   = ((size_t)cB * 65536 * PROW + 4096) / 2;
constexpr size_t SZ_OP    = (size_t)GSPLIT * 312 * 256;
constexpr size_t SZ_HSTOP = SZ_HST > SZ_OP ? SZ_HST : SZ_OP;
constexpr size_t OFF_CONV = OFF_HSTOP + SZ_HSTOP;       // exp(conv) fp8 [312][GKP]
constexpr size_t SZ_CONV  = (size_t)312 * GKP / 4;
constexpr size_t OFF_OWB  = OFF_CONV + SZ_CONV;         // out_w fp8*256 [256][GKP]
constexpr size_t SZ_OWB   = (size_t)256 * GKP / 4;
constexpr size_t WS_FLOATS = OFF_OWB + SZ_OWB;          // ~82.3 MB

__device__ inline u16 f2bf(float x) {
    union { float f; unsigned u; } v; v.f = x;
    unsigned r = v.u + 0x7fffu + ((v.u >> 16) & 1u);   // RNE
    return (u16)(r >> 16);
}
__device__ inline u8 f2fp8(float x) {
    return (u8)(__builtin_amdgcn_cvt_pk_fp8_f32(x, x, 0, false) & 0xff);
}

// ---------------------------------------------------------------------------
// K0a: cast out_w*256 -> fp8 e4m3, zero-padded K stride GKP.
// ---------------------------------------------------------------------------
__global__ __launch_bounds__(256) void k_bwcast(const float* __restrict__ ow,
                                                u8* __restrict__ owb) {
    const int o = blockIdx.x;
    const float* src = ow + (size_t)o * cMM;
    u8* dst = owb + (size_t)o * GKP;
    for (int k4 = threadIdx.x; k4 < GKP / 4; k4 += 256) {
        const int k = k4 * 4;
        unsigned r = 0;
        if (k < cMM) {
            const float4 f = *(const float4*)(src + k);
            unsigned lo = (unsigned)__builtin_amdgcn_cvt_pk_fp8_f32(f.x*256.f, f.y*256.f, 0, false);
            unsigned hi = (unsigned)__builtin_amdgcn_cvt_pk_fp8_f32(f.z*256.f, f.w*256.f, 0, false);
            r = (lo & 0xffffu) | (hi << 16);
        }
        *(unsigned*)(dst + k) = r;
    }
}

// K0b: zero the K-pad of conv A matrix (cols cMM..GKP of 312 rows).
__global__ __launch_bounds__(256) void k_zpad(u8* __restrict__ cv) {
    u8* p = cv + (size_t)blockIdx.x * GKP + cMM;
    for (int i = threadIdx.x; i < GKP - cMM; i += 256) p[i] = 0;
}

// ---------------------------------------------------------------------------
// K1: partial gram + emit hst[b][pix][40] bf16 (fused transpose; each block
// owns a disjoint 1024-pixel chunk, already staged in LDS).
// ---------------------------------------------------------------------------
__global__ __launch_bounds__(256) void k_gram(const float* __restrict__ hs,
                                              float* __restrict__ sp,
                                              u16* __restrict__ hst) {
    const int b   = blockIdx.y;
    const int kc  = blockIdx.x;
    const int tid = threadIdx.x;
    __shared__ float lds[64][44];   // [pix_local][channel], 16B-aligned rows

    if (tid < 64) lds[tid][39] = 0.f;   // channel pad (read by gram + hst g=4)
    __syncthreads();

    float acc0[2][2] = {{0.f,0.f},{0.f,0.f}};
    float acc1[2][2] = {{0.f,0.f},{0.f,0.f}};
    const int t0  = tid;
    const int t1v = tid + 256;
    const int t1  = (t1v < 400) ? t1v : 0;
    const int ti0 = t0 / 20, tj0 = t0 % 20;
    const int ti1 = t1 / 20, tj1 = t1 % 20;
    const float* hb = hs + (size_t)b * (cL * cDD);
    u16* hstb = hst + (size_t)b * (65536 * PROW);
    const int kbase = kc * 1024;

    for (int s = 0; s < 16; ++s) {
        const int k0 = kbase + s * 64;
        for (int idx = tid; idx < cL * 64; idx += 256) {
            const int j = idx >> 6, kk = idx & 63;
            lds[kk][j] = hb[(size_t)j * cDD + k0 + kk];
        }
        __syncthreads();
        #pragma unroll 4
        for (int kk = 0; kk < 64; ++kk) {
            const float2 ai = *(const float2*)&lds[kk][2*ti0];
            const float2 aj = *(const float2*)&lds[kk][2*tj0];
            acc0[0][0] = fmaf(ai.x, aj.x, acc0[0][0]);
            acc0[0][1] = fmaf(ai.x, aj.y, acc0[0][1]);
            acc0[1][0] = fmaf(ai.y, aj.x, acc0[1][0]);
            acc0[1][1] = fmaf(ai.y, aj.y, acc0[1][1]);
            const float2 bi = *(const float2*)&lds[kk][2*ti1];
            const float2 bj = *(const float2*)&lds[kk][2*tj1];
            acc1[0][0] = fmaf(bi.x, bj.x, acc1[0][0]);
            acc1[0][1] = fmaf(bi.x, bj.y, acc1[0][1]);
            acc1[1][0] = fmaf(bi.y, bj.x, acc1[1][0]);
            acc1[1][1] = fmaf(bi.y, bj.y, acc1[1][1]);
        }
        // emit hst for this 64-pixel slice (reads lds, no hazard before sync)
        for (int c = tid; c < 320; c += 256) {
            const int pixl = c / 5, g = c - pixl*5;
            const float4 f0 = *(const float4*)&lds[pixl][g*8];
            const float4 f1 = *(const float4*)&lds[pixl][g*8 + 4];
            short8 w;
            w[0] = (short)f2bf(f0.x); w[1] = (short)f2bf(f0.y);
            w[2] = (short)f2bf(f0.z); w[3] = (short)f2bf(f0.w);
            w[4] = (short)f2bf(f1.x); w[5] = (short)f2bf(f1.y);
            w[6] = (short)f2bf(f1.z); w[7] = (short)f2bf(f1.w);
            *(short8*)(hstb + (size_t)(k0 + pixl) * PROW + g*8) = w;
        }
        __syncthreads();
    }

    float* outp = sp + ((size_t)b * KCHUNKS + kc) * PAIRS;
    {
        const int r = 2*ti0, c = 2*tj0;
        if (r   < cL && c   < cL) outp[r*cL + c]       = acc0[0][0];
        if (r   < cL && c+1 < cL) outp[r*cL + c+1]     = acc0[0][1];
        if (r+1 < cL && c   < cL) outp[(r+1)*cL + c]   = acc0[1][0];
        if (r+1 < cL && c+1 < cL) outp[(r+1)*cL + c+1] = acc0[1][1];
    }
    if (t1v < 400) {
        const int r = 2*ti1, c = 2*tj1;
        if (r   < cL && c   < cL) outp[r*cL + c]       = acc1[0][0];
        if (r   < cL && c+1 < cL) outp[r*cL + c+1]     = acc1[0][1];
        if (r+1 < cL && c   < cL) outp[(r+1)*cL + c]   = acc1[1][0];
        if (r+1 < cL && c+1 < cL) outp[(r+1)*cL + c+1] = acc1[1][1];
    }
}

// ---------------------------------------------------------------------------
// K2: reduce gram partials, scale 1/256, row softmax.
// ---------------------------------------------------------------------------
__global__ __launch_bounds__(256) void k_softmax(const float* __restrict__ sp,
                                                 float* __restrict__ attnWs,
                                                 float* __restrict__ outAttn) {
    const int b = blockIdx.x;
    const int tid = threadIdx.x;
    __shared__ float sc[PAIRS];
    for (int idx = tid; idx < PAIRS; idx += 256) {
        float s = 0.f;
        for (int c = 0; c < KCHUNKS; ++c)
            s += sp[((size_t)b * KCHUNKS + c) * PAIRS + idx];
        sc[idx] = s * (1.0f / 256.0f);
    }
    __syncthreads();
    if (tid < cL) {
        const int i = tid;
        float m = -1e30f;
        #pragma unroll
        for (int j = 0; j < cL; ++j) m = fmaxf(m, sc[i*cL + j]);
        float e[cL];
        float sum = 0.f;
        #pragma unroll
        for (int j = 0; j < cL; ++j) { e[j] = expf(sc[i*cL + j] - m); sum += e[j]; }
        const float inv = 1.0f / sum;
        #pragma unroll
        for (int j = 0; j < cL; ++j) {
            const float a = e[j] * inv;
            attnWs [(size_t)b*PAIRS + i*cL + j] = a;
            outAttn[(size_t)b*PAIRS + i*cL + j] = a;
        }
    }
}

// ---------------------------------------------------------------------------
// K3: fold attention into conv weights -> dense-K bf16 MFMA A-layout.
// main: w2m[b][tap][oc48][ic 0..31]; tail: w2t[b][kc7][oc48][(tap&3)*8+ic']
// where tail K-index = tap*8 + (ic-32), kc = tap>>2.
// ---------------------------------------------------------------------------
__global__ __launch_bounds__(1024) void k_wtrans(const float* __restrict__ cw,
                                                 const float* __restrict__ attn,
                                                 u16* __restrict__ w2m,
                                                 u16* __restrict__ w2t) {
    const int b = blockIdx.x;
    const int t = threadIdx.x;
    __shared__ float at[PAIRS];
    for (int idx = t; idx < PAIRS; idx += 1024)
        at[idx] = attn[(size_t)b*PAIRS + idx];
    // zero both weight regions for this batch
    u32* zm = (u32*)(w2m + (size_t)b * 25*48*32);
    u32* zt = (u32*)(w2t + (size_t)b * 7*48*32);
    for (int i = t; i < 25*48*16; i += 1024) zm[i] = 0;
    for (int i = t; i < 7*48*16;  i += 1024) zt[i] = 0;
    __syncthreads();
    if (t < cL * 25) {
        const int oc = t / 25, tap = t % 25;
        float c[cL];
        #pragma unroll
        for (int i = 0; i < cL; ++i)
            c[i] = cw[(size_t)oc * (cL*25) + i*25 + tap];
        u16* dm = w2m + ((size_t)(b*25 + tap)*48 + oc)*32;
        u16* dt = w2t + ((size_t)(b*7 + (tap>>2))*48 + oc)*32 + (tap&3)*8;
        for (int j = 0; j < cL; ++j) {
            float a = 0.f;
            #pragma unroll
            for (int i = 0; i < cL; ++i) a = fmaf(c[i], at[i*cL + j], a);
            if (j < 32) dm[j] = f2bf(a);
            else        dt[j - 32] = f2bf(a);
        }
    }
}

// ---------------------------------------------------------------------------
// K4: conv as dense-K MFMA. Main: 25 taps x K=32 (ic 0..31). Tail: 7 chunks
// packing ic 32..39 of 4 taps each (per-lane tap = kc*4+kg4).
// P = [400 pix][40 ic] bf16, 32 KB -> 4 blocks/CU.
// ---------------------------------------------------------------------------
__global__ __launch_bounds__(256, 4) void k_conv(const u16* __restrict__ hst,
                                                 const u16* __restrict__ w2m,
                                                 const u16* __restrict__ w2t,
                                                 const float* __restrict__ cb,
                                                 u8* __restrict__ convout,
                                                 float* __restrict__ tileSumsq) {
    const int b   = blockIdx.z;
    const int gh0 = blockIdx.y * 16, gw0 = blockIdx.x * 16;
    const int tid = threadIdx.x;
    const int wv  = tid >> 6;
    const int ln15 = tid & 15;
    const int kg4  = (tid & 63) >> 4;

    __shared__ u16 P[400 * PROW];     // 32 KB
    __shared__ float red[4][48];

    // ---- stage 20x20 patch, [pix][40ic], linear 16B chunks ----
    const u16* hb = hst + (size_t)b * (65536 * PROW);
    for (int c = tid; c < 2000; c += 256) {
        const int p = c / 5, g = c - p*5;
        const int pr = p / 20, pc = p - pr*20;
        const int gh = min(gh0 + pr, 255);
        const size_t pix = (size_t)gh * 256 + gw0 + pc;   // may spill; slack covers
        const short8 v = *(const short8*)(hb + pix*PROW + g*8);
        *(short8*)&P[p*PROW + g*8] = v;
    }
    __syncthreads();

    f32x4 acc[3][4] = {};
    const u16* wbm = w2m + (size_t)b * 25*48*32;
    const u16* wbt = w2t + (size_t)b * 7*48*32;

    // ---- main: 25 taps, dense K = ic 0..31 ----
    #pragma unroll
    for (int tap = 0; tap < 25; ++tap) {
        const int kh = tap / 5, kw = tap % 5;
        const u16* wt = wbm + (size_t)tap * 48*32;
        short8 af[3];
        #pragma unroll
        for (int o = 0; o < 3; ++o)
            af[o] = *(const short8*)(wt + (o*16 + ln15)*32 + kg4*8);
        #pragma unroll
        for (int pt = 0; pt < 4; ++pt) {
            const int p = (wv*4 + pt + kh)*20 + ln15 + kw;
            const short8 bfr = *(const short8*)&P[p*PROW + kg4*8];
            #pragma unroll
            for (int o = 0; o < 3; ++o)
                acc[o][pt] = __builtin_amdgcn_mfma_f32_16x16x32_bf16(
                    af[o], bfr, acc[o][pt], 0, 0, 0);
        }
    }

    // ---- tail: ic 32..39, K-packed as tap*8+ic'; per-lane tap = kc*4+kg4 ----
    #pragma unroll
    for (int kc = 0; kc < 7; ++kc) {
        const u16* wt = wbt + (size_t)kc * 48*32;
        short8 af[3];
        #pragma unroll
        for (int o = 0; o < 3; ++o)
            af[o] = *(const short8*)(wt + (o*16 + ln15)*32 + kg4*8);
        int tap = kc*4 + kg4;
        if (tap > 24) tap = 24;          // pad taps: A rows are zero anyway
        const int kh = tap / 5, kw = tap - kh*5;
        #pragma unroll
        for (int pt = 0; pt < 4; ++pt) {
            const int p = (wv*4 + pt + kh)*20 + ln15 + kw;
            const short8 bfr = *(const short8*)&P[p*PROW + 32];
            #pragma unroll
            for (int o = 0; o < 3; ++o)
                acc[o][pt] = __builtin_amdgcn_mfma_f32_16x16x32_bf16(
                    af[o], bfr, acc[o][pt], 0, 0, 0);
        }
    }

    // ---- epilogue: bias + exp, tril fp8 store, sum-of-squares ----
    float ss[3][4];
    #pragma unroll
    for (int o = 0; o < 3; ++o)
        #pragma unroll
        for (int r = 0; r < 4; ++r) ss[o][r] = 0.f;

    const int ow = gw0 + ln15;
    #pragma unroll
    for (int o = 0; o < 3; ++o) {
        #pragma unroll
        for (int r = 0; r < 4; ++r) {
            const int oc = o*16 + kg4*4 + r;
            const float bias = (oc < cL) ? cb[oc] : 0.f;
            #pragma unroll
            for (int pt = 0; pt < 4; ++pt) {
                const int oh = gh0 + wv*4 + pt;
                if (oc < cL && oh < cM && ow < cM) {
                    const float e = __expf(acc[o][pt][r] + bias);
                    convout[(size_t)(b*cL + oc)*GKP + oh*cM + ow] =
                        (ow <= oh) ? f2fp8(e) : (u8)0;
                    ss[o][r] += e * e;
                }
            }
        }
    }

    #pragma unroll
    for (int o = 0; o < 3; ++o) {
        #pragma unroll
        for (int r = 0; r < 4; ++r) {
            float v = ss[o][r];
            v += __shfl_xor(v, 1);
            v += __shfl_xor(v, 2);
            v += __shfl_xor(v, 4);
            v += __shfl_xor(v, 8);
            if (ln15 == 0) red[wv][o*16 + kg4*4 + r] = v;
        }
    }
    __syncthreads();
    if (tid < cL) {
        const int tileIdx = blockIdx.y * 16 + blockIdx.x;
        tileSumsq[((size_t)b*256 + tileIdx)*cL + tid] =
            red[0][tid] + red[1][tid] + red[2][tid] + red[3][tid];
    }
}

// ---------------------------------------------------------------------------
// K4b: norms[row] = sqrt(sum over 256 tiles).
// ---------------------------------------------------------------------------
__global__ __launch_bounds__(256) void k_norm(const float* __restrict__ ts,
                                              float* __restrict__ norms) {
    const int row = blockIdx.x;
    const int b = row / cL, l = row % cL;
    const int tid = threadIdx.x;
    float v = ts[((size_t)b*256 + tid)*cL + l];
    for (int off = 32; off; off >>= 1) v += __shfl_down(v, off, 64);
    __shared__ float r[4];
    if ((tid & 63) == 0) r[tid >> 6] = v;
    __syncthreads();
    if (tid == 0) norms[row] = sqrtf(r[0] + r[1] + r[2] + r[3]);
}

// ---------------------------------------------------------------------------
// K5: fp8 MFMA out-GEMM. grid (1, 3, 125), 512 thr; block tile 128x256,
// wave tile 64x64; double-buffered LDS, rows padded to 80 B.
// ---------------------------------------------------------------------------
__global__ __launch_bounds__(512) void k_gemm(const u8* __restrict__ A,
                                              const u8* __restrict__ Bw,
                                              float* __restrict__ op) {
    const int mt = blockIdx.y, z = blockIdx.z;
    const int tid = threadIdx.x;
    const int wid = tid >> 6, lane = tid & 63;
    const int ln15 = lane & 15, kg4 = lane >> 4;
    const int wm = wid >> 2, wn = wid & 3;

    __shared__ u8 As[2][128*80];
    __shared__ u8 Bs[2][256*80];

    const int mbase = mt * 128;
    const int ra = tid >> 2, sl = tid & 3;
    const int arow = mbase + ra;
    const int aro = (arow < 312) ? arow : 0;
    const u8* Ap  = A  + (size_t)aro * GKP        + z*CSTEP + sl*16;
    const u8* Bp0 = Bw + (size_t)ra * GKP         + z*CSTEP + sl*16;
    const u8* Bp1 = Bw + (size_t)(128 + ra) * GKP + z*CSTEP + sl*16;

    uint4 pa  = *(const uint4*)Ap;
    uint4 pb0 = *(const uint4*)Bp0;
    uint4 pb1 = *(const uint4*)Bp1;

    f32x4 acc[4][4] = {};

    for (int s = 0; s < CSTEP/64; ++s) {
        const int cur = s & 1;
        __syncthreads();
        *(uint4*)&As[cur][ra*80 + sl*16]        = pa;
        *(uint4*)&Bs[cur][ra*80 + sl*16]        = pb0;
        *(uint4*)&Bs[cur][(128 + ra)*80 + sl*16] = pb1;
        __syncthreads();
        if (s + 1 < CSTEP/64) {
            const int off = (s + 1) * 64;
            pa  = *(const uint4*)(Ap + off);
            pb0 = *(const uint4*)(Bp0 + off);
            pb1 = *(const uint4*)(Bp1 + off);
        }
        #pragma unroll
        for (int kc = 0; kc < 2; ++kc) {
            long af[4], bf[4];
            #pragma unroll
            for (int fm = 0; fm < 4; ++fm)
                af[fm] = *(const long*)&As[cur][(wm*64 + fm*16 + ln15)*80 + kc*32 + kg4*8];
            #pragma unroll
            for (int fn = 0; fn < 4; ++fn)
                bf[fn] = *(const long*)&Bs[cur][(wn*64 + fn*16 + ln15)*80 + kc*32 + kg4*8];
            #pragma unroll
            for (int fm = 0; fm < 4; ++fm)
                #pragma unroll
                for (int fn = 0; fn < 4; ++fn)
                    acc[fm][fn] = __builtin_amdgcn_mfma_f32_16x16x32_fp8_fp8(
                        af[fm], bf[fn], acc[fm][fn], 0, 0, 0);
        }
    }

    #pragma unroll
    for (int fm = 0; fm < 4; ++fm) {
        #pragma unroll
        for (int r = 0; r < 4; ++r) {
            const int row = mbase + wm*64 + fm*16 + kg4*4 + r;
            if (row < 312) {
                #pragma unroll
                for (int fn = 0; fn < 4; ++fn) {
                    const int col = wn*64 + fn*16 + ln15;
                    op[((size_t)z*312 + row)*256 + col] = acc[fm][fn][r];
                }
            }
        }
    }
}

// ---------------------------------------------------------------------------
// K5b: reduce K-split partials, divide by (norm*256), write out.
// ---------------------------------------------------------------------------
__global__ __launch_bounds__(256) void k_finish(const float* __restrict__ op,
                                                const float* __restrict__ norms,
                                                float* __restrict__ out) {
    const int idx = blockIdx.x * 256 + threadIdx.x;
    float s = 0.f;
    for (int z = 0; z < GSPLIT; ++z) s += op[(size_t)z * (312*256) + idx];
    out[idx] = s / (norms[idx >> 8] * 256.0f);
}

// ---------------------------------------------------------------------------
extern "C" void kernel_launch(void* const* d_in, const int* in_sizes, int n_in,
                              void* d_out, int out_size, void* d_ws, size_t ws_size,
                              hipStream_t stream) {
    const float* hs = (const float*)d_in[0];
    const float* cw = (const float*)d_in[1];
    const float* cb = (const float*)d_in[2];
    const float* ow = (const float*)d_in[3];
    float* out = (float*)d_out;
    float* ws  = (float*)d_ws;

    if (ws_size < WS_FLOATS * sizeof(float)) return;

    float* sp   = ws + OFF_SP;
    float* ts   = ws + OFF_TS;
    float* nrm  = ws + OFF_NORM;
    float* attn = ws + OFF_ATTN;
    u16*   w2m  = (u16*)(ws + OFF_W2M);
    u16*   w2t  = (u16*)(ws + OFF_W2T);
    u16*   hst  = (u16*)(ws + OFF_HSTOP);
    float* op   = ws + OFF_HSTOP;
    u8*    cv   = (u8*)(ws + OFF_CONV);
    u8*    owb  = (u8*)(ws + OFF_OWB);

    k_bwcast <<<256, 256, 0, stream>>>(ow, owb);
    k_zpad   <<<312, 256, 0, stream>>>(cv);
    k_gram   <<<dim3(KCHUNKS, cB), 256, 0, stream>>>(hs, sp, hst);
    k_softmax<<<cB, 256, 0, stream>>>(sp, attn, out + (size_t)cB*cL*cD);
    k_wtrans <<<cB, 1024, 0, stream>>>(cw, attn, w2m, w2t);
    k_conv   <<<dim3(16, 16, cB), 256, 0, stream>>>(hst, w2m, w2t, cb, cv, ts);
    k_norm   <<<cB*cL, 256, 0, stream>>>(ts, nrm);
    k_gemm   <<<dim3(1, 3, GSPLIT), 512, 0, stream>>>(cv, owb, op);
    k_finish <<<312, 256, 0, stream>>>(op, nrm, out);
}

// Round 6
// 300.339 us; speedup vs baseline: 4.8306x; 1.2840x over previous
//
#include <hip/hip_runtime.h>
#include <math.h>

typedef unsigned short u16;
typedef unsigned int   u32;
typedef unsigned char  u8;
typedef __attribute__((ext_vector_type(8))) short short8;
typedef __attribute__((ext_vector_type(4))) float f32x4;
typedef __attribute__((ext_vector_type(4))) unsigned short ushort4_t;

// GeoMamba: B=8, L=39, D=256, K=5, M=252
constexpr int cB   = 8;
constexpr int cL   = 39;
constexpr int cD   = 256;
constexpr int cDD  = 65536;   // D*D
constexpr int cM   = 252;
constexpr int cMM  = 63504;   // M*M
constexpr int PAIRS = cL * cL; // 1521

constexpr int KCHUNKS = 64;    // gram K-split (1024 px per block)
constexpr int GKP     = 64000; // padded K for out-gemm (fp8 bytes per row)
constexpr int CSTEP   = 512;   // K per gemm block
constexpr int GSPLIT  = 125;   // 125*512 = 64000
constexpr int PROW    = 40;    // u16 per pixel row of hst

// ---- ws layout (float offsets) ----
constexpr size_t OFF_SP   = 0;                          // gram partials [B][64][1521]
constexpr size_t SZ_SP    = (size_t)cB * KCHUNKS * PAIRS;
constexpr size_t OFF_TS   = 0;                          // overlaps SP (dead after softmax)
constexpr size_t OFF_NORM = OFF_TS + (size_t)cB * 256 * cL;
constexpr size_t OFF_ATTN = OFF_SP + SZ_SP;
constexpr size_t SZ_ATTN  = (size_t)cB * PAIRS;
constexpr size_t OFF_W2M  = OFF_ATTN + SZ_ATTN;         // main wts bf16 [B][tap25][oc48][32]
constexpr size_t SZ_W2M   = (size_t)cB * 25 * 48 * 32 / 2;
constexpr size_t OFF_W2T  = OFF_W2M + SZ_W2M;           // tail wts bf16 [B][kc7][oc48][32]
constexpr size_t SZ_W2T   = (size_t)cB * 7 * 48 * 32 / 2;
constexpr size_t OFF_HST  = OFF_W2T + SZ_W2T;           // hst bf16 [B][65536][40]; op overlaps
constexpr size_t SZ_HST   = (size_t)cB * 65536 * PROW / 2;   // 10,485,760 floats
constexpr size_t SZ_OP    = (size_t)GSPLIT * 312 * 256;      //  9,984,000 floats (fits in HST)
static_assert(SZ_OP <= SZ_HST, "op must fit inside hst region");
constexpr size_t OFF_CONV = OFF_HST + SZ_HST;           // exp(conv) fp8 [312][GKP]
constexpr size_t SZ_CONV  = (size_t)312 * GKP / 4;
constexpr size_t OFF_OWB  = OFF_CONV + SZ_CONV;         // out_w fp8*256 [256][GKP]
constexpr size_t SZ_OWB   = (size_t)256 * GKP / 4;
constexpr size_t WS_FLOATS = OFF_OWB + SZ_OWB;          // ~82.2 MB

__device__ inline u16 f2bf(float x) {
    union { float f; unsigned u; } v; v.f = x;
    unsigned r = v.u + 0x7fffu + ((v.u >> 16) & 1u);   // RNE
    return (u16)(r >> 16);
}
__device__ inline u8 f2fp8(float x) {
    return (u8)(__builtin_amdgcn_cvt_pk_fp8_f32(x, x, 0, false) & 0xff);
}

// ---------------------------------------------------------------------------
// K0a: cast out_w*256 -> fp8 e4m3, zero-padded K stride GKP.
// ---------------------------------------------------------------------------
__global__ __launch_bounds__(256) void k_bwcast(const float* __restrict__ ow,
                                                u8* __restrict__ owb) {
    const int o = blockIdx.x;
    const float* src = ow + (size_t)o * cMM;
    u8* dst = owb + (size_t)o * GKP;
    for (int k4 = threadIdx.x; k4 < GKP / 4; k4 += 256) {
        const int k = k4 * 4;
        unsigned r = 0;
        if (k < cMM) {
            const float4 f = *(const float4*)(src + k);
            unsigned lo = (unsigned)__builtin_amdgcn_cvt_pk_fp8_f32(f.x*256.f, f.y*256.f, 0, false);
            unsigned hi = (unsigned)__builtin_amdgcn_cvt_pk_fp8_f32(f.z*256.f, f.w*256.f, 0, false);
            r = (lo & 0xffffu) | (hi << 16);
        }
        *(unsigned*)(dst + k) = r;
    }
}

// K0b: zero the K-pad of conv A matrix (cols cMM..GKP of 312 rows).
__global__ __launch_bounds__(256) void k_zpad(u8* __restrict__ cv) {
    u8* p = cv + (size_t)blockIdx.x * GKP + cMM;
    for (int i = threadIdx.x; i < GKP - cMM; i += 256) p[i] = 0;
}

// ---------------------------------------------------------------------------
// K0c: hst[b][pix][40] bf16 = transpose+cast of hs (ch 0..38, ch39 = 0).
// Thread <-> pixel; 39 coalesced scalar f32 loads -> 20 packed u32 -> 5x16B.
// ---------------------------------------------------------------------------
__global__ __launch_bounds__(256) void k_hst(const float* __restrict__ hs,
                                             u16* __restrict__ hst) {
    const int b  = blockIdx.y;
    const int px = blockIdx.x * 256 + threadIdx.x;
    const float* hb = hs + (size_t)b * (cL * cDD) + px;
    u32 w[20];
    #pragma unroll
    for (int c2 = 0; c2 < 20; ++c2) {
        const int c0 = 2*c2, c1 = 2*c2 + 1;
        const u32 lo = f2bf(hb[(size_t)c0 * cDD]);
        const u32 hi = (c1 < cL) ? (u32)f2bf(hb[(size_t)c1 * cDD]) : 0u;
        w[c2] = lo | (hi << 16);
    }
    u16* ob = hst + (size_t)b * (65536 * PROW) + (size_t)px * PROW;
    #pragma unroll
    for (int g = 0; g < 5; ++g) {
        uint4 v;
        v.x = w[g*4 + 0]; v.y = w[g*4 + 1]; v.z = w[g*4 + 2]; v.w = w[g*4 + 3];
        *(uint4*)(ob + g*8) = v;
    }
}

// ---------------------------------------------------------------------------
// K1: MFMA gram. gram[i][j] = sum_px H[i][px]*H[j][px]; A-frag == B-frag
// (lane: ch = o*16+ln15, px = kg4*8+j), read straight from hst (strided u16).
// grid (64, B), 256 thr; per wave 256 px = 8 K32 steps, 9 MFMAs each.
// Cross-wave reduce via LDS, masked write to sp[b][kc][1521].
// ---------------------------------------------------------------------------
__global__ __launch_bounds__(256) void k_gram(const u16* __restrict__ hst,
                                              float* __restrict__ sp) {
    const int b  = blockIdx.y;
    const int kc = blockIdx.x;
    const int tid = threadIdx.x;
    const int wv = tid >> 6, ln15 = tid & 15, kg4 = (tid & 63) >> 4;
    const u16* hb = hst + (size_t)b * (65536 * PROW);
    const int px0 = kc * 1024 + wv * 256;

    f32x4 acc[3][3] = {};
    #pragma unroll
    for (int s = 0; s < 8; ++s) {
        const int px = px0 + s * 32 + kg4 * 8;
        short8 f[3];
        #pragma unroll
        for (int o = 0; o < 3; ++o) {
            const int ch = o * 16 + ln15;
            short8 v = {};
            if (ch < PROW) {                       // ch 39 is stored zeros; 40+ absent
                const u16* p = hb + (size_t)px * PROW + ch;
                #pragma unroll
                for (int j = 0; j < 8; ++j) v[j] = (short)p[j * PROW];
            }
            f[o] = v;
        }
        #pragma unroll
        for (int oi = 0; oi < 3; ++oi)
            #pragma unroll
            for (int oj = 0; oj < 3; ++oj)
                acc[oi][oj] = __builtin_amdgcn_mfma_f32_16x16x32_bf16(
                    f[oi], f[oj], acc[oi][oj], 0, 0, 0);
    }

    __shared__ float R[4][48 * 50];               // stride 50: <=2-way on write
    #pragma unroll
    for (int oi = 0; oi < 3; ++oi)
        #pragma unroll
        for (int oj = 0; oj < 3; ++oj)
            #pragma unroll
            for (int r = 0; r < 4; ++r)
                R[wv][(oi*16 + kg4*4 + r)*50 + oj*16 + ln15] = acc[oi][oj][r];
    __syncthreads();

    float* outp = sp + ((size_t)b * KCHUNKS + kc) * PAIRS;
    for (int idx = tid; idx < PAIRS; idx += 256) {
        const int i = idx / 39, j = idx - i * 39;
        const int a = i * 50 + j;
        outp[idx] = R[0][a] + R[1][a] + R[2][a] + R[3][a];
    }
}

// ---------------------------------------------------------------------------
// K2: reduce gram partials, scale 1/256, row softmax.
// ---------------------------------------------------------------------------
__global__ __launch_bounds__(256) void k_softmax(const float* __restrict__ sp,
                                                 float* __restrict__ attnWs,
                                                 float* __restrict__ outAttn) {
    const int b = blockIdx.x;
    const int tid = threadIdx.x;
    __shared__ float sc[PAIRS];
    for (int idx = tid; idx < PAIRS; idx += 256) {
        float s = 0.f;
        for (int c = 0; c < KCHUNKS; ++c)
            s += sp[((size_t)b * KCHUNKS + c) * PAIRS + idx];
        sc[idx] = s * (1.0f / 256.0f);
    }
    __syncthreads();
    if (tid < cL) {
        const int i = tid;
        float m = -1e30f;
        #pragma unroll
        for (int j = 0; j < cL; ++j) m = fmaxf(m, sc[i*cL + j]);
        float e[cL];
        float sum = 0.f;
        #pragma unroll
        for (int j = 0; j < cL; ++j) { e[j] = expf(sc[i*cL + j] - m); sum += e[j]; }
        const float inv = 1.0f / sum;
        #pragma unroll
        for (int j = 0; j < cL; ++j) {
            const float a = e[j] * inv;
            attnWs [(size_t)b*PAIRS + i*cL + j] = a;
            outAttn[(size_t)b*PAIRS + i*cL + j] = a;
        }
    }
}

// ---------------------------------------------------------------------------
// K3: fold attention into conv weights -> dense-K bf16 MFMA A-layout.
// main: w2m[b][tap][oc48][ic 0..31]; tail: w2t[b][kc7][oc48][(tap&3)*8+ic']
// ---------------------------------------------------------------------------
__global__ __launch_bounds__(1024) void k_wtrans(const float* __restrict__ cw,
                                                 const float* __restrict__ attn,
                                                 u16* __restrict__ w2m,
                                                 u16* __restrict__ w2t) {
    const int b = blockIdx.x;
    const int t = threadIdx.x;
    __shared__ float at[PAIRS];
    for (int idx = t; idx < PAIRS; idx += 1024)
        at[idx] = attn[(size_t)b*PAIRS + idx];
    u32* zm = (u32*)(w2m + (size_t)b * 25*48*32);
    u32* zt = (u32*)(w2t + (size_t)b * 7*48*32);
    for (int i = t; i < 25*48*16; i += 1024) zm[i] = 0;
    for (int i = t; i < 7*48*16;  i += 1024) zt[i] = 0;
    __syncthreads();
    if (t < cL * 25) {
        const int oc = t / 25, tap = t % 25;
        float c[cL];
        #pragma unroll
        for (int i = 0; i < cL; ++i)
            c[i] = cw[(size_t)oc * (cL*25) + i*25 + tap];
        u16* dm = w2m + ((size_t)(b*25 + tap)*48 + oc)*32;
        u16* dt = w2t + ((size_t)(b*7 + (tap>>2))*48 + oc)*32 + (tap&3)*8;
        for (int j = 0; j < cL; ++j) {
            float a = 0.f;
            #pragma unroll
            for (int i = 0; i < cL; ++i) a = fmaf(c[i], at[i*cL + j], a);
            if (j < 32) dm[j] = f2bf(a);
            else        dt[j - 32] = f2bf(a);
        }
    }
}

// ---------------------------------------------------------------------------
// K4: conv as dense-K MFMA. Main: 25 taps x K=32 (ic 0..31). Tail: 7 chunks
// packing ic 32..39 of 4 taps each (per-lane tap = kc*4+kg4).
// P = [400 pix][40 ic] bf16, 32 KB -> 4 blocks/CU.
// ---------------------------------------------------------------------------
__global__ __launch_bounds__(256, 4) void k_conv(const u16* __restrict__ hst,
                                                 const u16* __restrict__ w2m,
                                                 const u16* __restrict__ w2t,
                                                 const float* __restrict__ cb,
                                                 u8* __restrict__ convout,
                                                 float* __restrict__ tileSumsq) {
    const int b   = blockIdx.z;
    const int gh0 = blockIdx.y * 16, gw0 = blockIdx.x * 16;
    const int tid = threadIdx.x;
    const int wv  = tid >> 6;
    const int ln15 = tid & 15;
    const int kg4  = (tid & 63) >> 4;

    __shared__ u16 P[400 * PROW];     // 32 KB
    __shared__ float red[4][48];

    const u16* hb = hst + (size_t)b * (65536 * PROW);
    for (int c = tid; c < 2000; c += 256) {
        const int p = c / 5, g = c - p*5;
        const int pr = p / 20, pc = p - pr*20;
        const int gh = min(gh0 + pr, 255);
        const size_t pix = (size_t)gh * 256 + gw0 + pc;   // may spill; masked later
        const short8 v = *(const short8*)(hb + pix*PROW + g*8);
        *(short8*)&P[p*PROW + g*8] = v;
    }
    __syncthreads();

    f32x4 acc[3][4] = {};
    const u16* wbm = w2m + (size_t)b * 25*48*32;
    const u16* wbt = w2t + (size_t)b * 7*48*32;

    #pragma unroll
    for (int tap = 0; tap < 25; ++tap) {
        const int kh = tap / 5, kw = tap % 5;
        const u16* wt = wbm + (size_t)tap * 48*32;
        short8 af[3];
        #pragma unroll
        for (int o = 0; o < 3; ++o)
            af[o] = *(const short8*)(wt + (o*16 + ln15)*32 + kg4*8);
        #pragma unroll
        for (int pt = 0; pt < 4; ++pt) {
            const int p = (wv*4 + pt + kh)*20 + ln15 + kw;
            const short8 bfr = *(const short8*)&P[p*PROW + kg4*8];
            #pragma unroll
            for (int o = 0; o < 3; ++o)
                acc[o][pt] = __builtin_amdgcn_mfma_f32_16x16x32_bf16(
                    af[o], bfr, acc[o][pt], 0, 0, 0);
        }
    }

    #pragma unroll
    for (int kc = 0; kc < 7; ++kc) {
        const u16* wt = wbt + (size_t)kc * 48*32;
        short8 af[3];
        #pragma unroll
        for (int o = 0; o < 3; ++o)
            af[o] = *(const short8*)(wt + (o*16 + ln15)*32 + kg4*8);
        int tap = kc*4 + kg4;
        if (tap > 24) tap = 24;
        const int kh = tap / 5, kw = tap - kh*5;
        #pragma unroll
        for (int pt = 0; pt < 4; ++pt) {
            const int p = (wv*4 + pt + kh)*20 + ln15 + kw;
            const short8 bfr = *(const short8*)&P[p*PROW + 32];
            #pragma unroll
            for (int o = 0; o < 3; ++o)
                acc[o][pt] = __builtin_amdgcn_mfma_f32_16x16x32_bf16(
                    af[o], bfr, acc[o][pt], 0, 0, 0);
        }
    }

    float ss[3][4];
    #pragma unroll
    for (int o = 0; o < 3; ++o)
        #pragma unroll
        for (int r = 0; r < 4; ++r) ss[o][r] = 0.f;

    const int ow = gw0 + ln15;
    #pragma unroll
    for (int o = 0; o < 3; ++o) {
        #pragma unroll
        for (int r = 0; r < 4; ++r) {
            const int oc = o*16 + kg4*4 + r;
            const float bias = (oc < cL) ? cb[oc] : 0.f;
            #pragma unroll
            for (int pt = 0; pt < 4; ++pt) {
                const int oh = gh0 + wv*4 + pt;
                if (oc < cL && oh < cM && ow < cM) {
                    const float e = __expf(acc[o][pt][r] + bias);
                    convout[(size_t)(b*cL + oc)*GKP + oh*cM + ow] =
                        (ow <= oh) ? f2fp8(e) : (u8)0;
                    ss[o][r] += e * e;
                }
            }
        }
    }

    #pragma unroll
    for (int o = 0; o < 3; ++o) {
        #pragma unroll
        for (int r = 0; r < 4; ++r) {
            float v = ss[o][r];
            v += __shfl_xor(v, 1);
            v += __shfl_xor(v, 2);
            v += __shfl_xor(v, 4);
            v += __shfl_xor(v, 8);
            if (ln15 == 0) red[wv][o*16 + kg4*4 + r] = v;
        }
    }
    __syncthreads();
    if (tid < cL) {
        const int tileIdx = blockIdx.y * 16 + blockIdx.x;
        tileSumsq[((size_t)b*256 + tileIdx)*cL + tid] =
            red[0][tid] + red[1][tid] + red[2][tid] + red[3][tid];
    }
}

// ---------------------------------------------------------------------------
// K4b: norms[row] = sqrt(sum over 256 tiles).
// ---------------------------------------------------------------------------
__global__ __launch_bounds__(256) void k_norm(const float* __restrict__ ts,
                                              float* __restrict__ norms) {
    const int row = blockIdx.x;
    const int b = row / cL, l = row % cL;
    const int tid = threadIdx.x;
    float v = ts[((size_t)b*256 + tid)*cL + l];
    for (int off = 32; off; off >>= 1) v += __shfl_down(v, off, 64);
    __shared__ float r[4];
    if ((tid & 63) == 0) r[tid >> 6] = v;
    __syncthreads();
    if (tid == 0) norms[row] = sqrtf(r[0] + r[1] + r[2] + r[3]);
}

// ---------------------------------------------------------------------------
// K5: fp8 MFMA out-GEMM. grid (1, 3, 125), 512 thr; block tile 128x256,
// wave tile 64x64; double-buffered LDS, rows padded to 80 B.
// ---------------------------------------------------------------------------
__global__ __launch_bounds__(512) void k_gemm(const u8* __restrict__ A,
                                              const u8* __restrict__ Bw,
                                              float* __restrict__ op) {
    const int mt = blockIdx.y, z = blockIdx.z;
    const int tid = threadIdx.x;
    const int wid = tid >> 6, lane = tid & 63;
    const int ln15 = lane & 15, kg4 = lane >> 4;
    const int wm = wid >> 2, wn = wid & 3;

    __shared__ u8 As[2][128*80];
    __shared__ u8 Bs[2][256*80];

    const int mbase = mt * 128;
    const int ra = tid >> 2, sl = tid & 3;
    const int arow = mbase + ra;
    const int aro = (arow < 312) ? arow : 0;
    const u8* Ap  = A  + (size_t)aro * GKP        + z*CSTEP + sl*16;
    const u8* Bp0 = Bw + (size_t)ra * GKP         + z*CSTEP + sl*16;
    const u8* Bp1 = Bw + (size_t)(128 + ra) * GKP + z*CSTEP + sl*16;

    uint4 pa  = *(const uint4*)Ap;
    uint4 pb0 = *(const uint4*)Bp0;
    uint4 pb1 = *(const uint4*)Bp1;

    f32x4 acc[4][4] = {};

    for (int s = 0; s < CSTEP/64; ++s) {
        const int cur = s & 1;
        __syncthreads();
        *(uint4*)&As[cur][ra*80 + sl*16]        = pa;
        *(uint4*)&Bs[cur][ra*80 + sl*16]        = pb0;
        *(uint4*)&Bs[cur][(128 + ra)*80 + sl*16] = pb1;
        __syncthreads();
        if (s + 1 < CSTEP/64) {
            const int off = (s + 1) * 64;
            pa  = *(const uint4*)(Ap + off);
            pb0 = *(const uint4*)(Bp0 + off);
            pb1 = *(const uint4*)(Bp1 + off);
        }
        #pragma unroll
        for (int kc = 0; kc < 2; ++kc) {
            long af[4], bf[4];
            #pragma unroll
            for (int fm = 0; fm < 4; ++fm)
                af[fm] = *(const long*)&As[cur][(wm*64 + fm*16 + ln15)*80 + kc*32 + kg4*8];
            #pragma unroll
            for (int fn = 0; fn < 4; ++fn)
                bf[fn] = *(const long*)&Bs[cur][(wn*64 + fn*16 + ln15)*80 + kc*32 + kg4*8];
            #pragma unroll
            for (int fm = 0; fm < 4; ++fm)
                #pragma unroll
                for (int fn = 0; fn < 4; ++fn)
                    acc[fm][fn] = __builtin_amdgcn_mfma_f32_16x16x32_fp8_fp8(
                        af[fm], bf[fn], acc[fm][fn], 0, 0, 0);
        }
    }

    #pragma unroll
    for (int fm = 0; fm < 4; ++fm) {
        #pragma unroll
        for (int r = 0; r < 4; ++r) {
            const int row = mbase + wm*64 + fm*16 + kg4*4 + r;
            if (row < 312) {
                #pragma unroll
                for (int fn = 0; fn < 4; ++fn) {
                    const int col = wn*64 + fn*16 + ln15;
                    op[((size_t)z*312 + row)*256 + col] = acc[fm][fn][r];
                }
            }
        }
    }
}

// ---------------------------------------------------------------------------
// K5b: reduce K-split partials, divide by (norm*256), write out.
// ---------------------------------------------------------------------------
__global__ __launch_bounds__(256) void k_finish(const float* __restrict__ op,
                                                const float* __restrict__ norms,
                                                float* __restrict__ out) {
    const int idx = blockIdx.x * 256 + threadIdx.x;
    float s = 0.f;
    for (int z = 0; z < GSPLIT; ++z) s += op[(size_t)z * (312*256) + idx];
    out[idx] = s / (norms[idx >> 8] * 256.0f);
}

// ---------------------------------------------------------------------------
extern "C" void kernel_launch(void* const* d_in, const int* in_sizes, int n_in,
                              void* d_out, int out_size, void* d_ws, size_t ws_size,
                              hipStream_t stream) {
    const float* hs = (const float*)d_in[0];
    const float* cw = (const float*)d_in[1];
    const float* cb = (const float*)d_in[2];
    const float* ow = (const float*)d_in[3];
    float* out = (float*)d_out;
    float* ws  = (float*)d_ws;

    if (ws_size < WS_FLOATS * sizeof(float)) return;

    float* sp   = ws + OFF_SP;
    float* ts   = ws + OFF_TS;
    float* nrm  = ws + OFF_NORM;
    float* attn = ws + OFF_ATTN;
    u16*   w2m  = (u16*)(ws + OFF_W2M);
    u16*   w2t  = (u16*)(ws + OFF_W2T);
    u16*   hst  = (u16*)(ws + OFF_HST);
    float* op   = ws + OFF_HST;            // overlaps hst (dead by k_gemm)
    u8*    cv   = (u8*)(ws + OFF_CONV);
    u8*    owb  = (u8*)(ws + OFF_OWB);

    k_hst    <<<dim3(256, cB), 256, 0, stream>>>(hs, hst);
    k_bwcast <<<256, 256, 0, stream>>>(ow, owb);
    k_zpad   <<<312, 256, 0, stream>>>(cv);
    k_gram   <<<dim3(KCHUNKS, cB), 256, 0, stream>>>(hst, sp);
    k_softmax<<<cB, 256, 0, stream>>>(sp, attn, out + (size_t)cB*cL*cD);
    k_wtrans <<<cB, 1024, 0, stream>>>(cw, attn, w2m, w2t);
    k_conv   <<<dim3(16, 16, cB), 256, 0, stream>>>(hst, w2m, w2t, cb, cv, ts);
    k_norm   <<<cB*cL, 256, 0, stream>>>(ts, nrm);
    k_gemm   <<<dim3(1, 3, GSPLIT), 512, 0, stream>>>(cv, owb, op);
    k_finish <<<312, 256, 0, stream>>>(op, nrm, out);
}

// Round 7
// 298.555 us; speedup vs baseline: 4.8595x; 1.0060x over previous
//
#include <hip/hip_runtime.h>
#include <math.h>

typedef unsigned short u16;
typedef unsigned int   u32;
typedef unsigned char  u8;
typedef __attribute__((ext_vector_type(8))) short short8;
typedef __attribute__((ext_vector_type(4))) float f32x4;
typedef __attribute__((ext_vector_type(4))) unsigned short ushort4_t;

// GeoMamba: B=8, L=39, D=256, K=5, M=252
constexpr int cB   = 8;
constexpr int cL   = 39;
constexpr int cD   = 256;
constexpr int cDD  = 65536;   // D*D
constexpr int cM   = 252;
constexpr int cMM  = 63504;   // M*M
constexpr int PAIRS = cL * cL; // 1521

constexpr int KCHUNKS = 64;    // gram K-split (1024 px per block)
constexpr int GKP     = 65536; // tile-major K for out-gemm (fp8 bytes per row)
constexpr int CSTEP   = 512;   // K per gemm block
constexpr int GSPLIT  = 128;   // 128*512 = 65536
constexpr int PROW    = 40;    // u16 per pixel row of hst

// ---- ws layout (float offsets) ----
constexpr size_t OFF_SP   = 0;                          // gram partials [B][64][1521]
constexpr size_t SZ_SP    = (size_t)cB * KCHUNKS * PAIRS;
constexpr size_t OFF_TS   = 0;                          // overlaps SP (dead after softmax)
constexpr size_t OFF_NORM = OFF_TS + (size_t)cB * 256 * cL;
constexpr size_t OFF_ATTN = OFF_SP + SZ_SP;
constexpr size_t SZ_ATTN  = (size_t)cB * PAIRS;
constexpr size_t OFF_W2M  = OFF_ATTN + SZ_ATTN;         // main wts bf16 [B][tap25][oc48][32]
constexpr size_t SZ_W2M   = (size_t)cB * 25 * 48 * 32 / 2;
constexpr size_t OFF_W2T  = OFF_W2M + SZ_W2M;           // tail wts bf16 [B][kc7][oc48][32]
constexpr size_t SZ_W2T   = (size_t)cB * 7 * 48 * 32 / 2;
constexpr size_t OFF_HST  = OFF_W2T + SZ_W2T;           // hst bf16 [B][65536][40]; op overlaps
constexpr size_t SZ_HST   = (size_t)cB * 65536 * PROW / 2;   // 10,485,760 floats
constexpr size_t SZ_OP    = (size_t)GSPLIT * 312 * 256;      // 10,223,616 floats
static_assert(SZ_OP <= SZ_HST, "op must fit inside hst region");
constexpr size_t OFF_CONV = OFF_HST + SZ_HST;           // exp(conv) fp8 [312][GKP] tile-major
constexpr size_t SZ_CONV  = (size_t)312 * GKP / 4;
constexpr size_t OFF_OWB  = OFF_CONV + SZ_CONV;         // out_w fp8*256 [256][GKP] tile-major
constexpr size_t SZ_OWB   = (size_t)256 * GKP / 4;
constexpr size_t WS_FLOATS = OFF_OWB + SZ_OWB;          // ~83 MB

__device__ inline u16 f2bf(float x) {
    union { float f; unsigned u; } v; v.f = x;
    unsigned r = v.u + 0x7fffu + ((v.u >> 16) & 1u);   // RNE
    return (u16)(r >> 16);
}
__device__ inline u8 f2fp8(float x) {
    return (u8)(__builtin_amdgcn_cvt_pk_fp8_f32(x, x, 0, false) & 0xff);
}

// ---------------------------------------------------------------------------
// K0a: cast out_w*256 -> fp8 e4m3, gathered into tile-major K layout.
// k' = tile*256 + ph*16 + pw; tile = th*16+tw; (oh,ow) = (th*16+ph, tw*16+pw).
// Invalid (oh>=252 || ow>=252) -> 0.
// ---------------------------------------------------------------------------
__global__ __launch_bounds__(256) void k_bwcast(const float* __restrict__ ow,
                                                u8* __restrict__ owb) {
    const int o = blockIdx.x;
    const float* src = ow + (size_t)o * cMM;
    u8* dst = owb + (size_t)o * GKP;
    for (int k4 = threadIdx.x; k4 < GKP / 4; k4 += 256) {
        const int k = k4 * 4;                 // pw%4 == 0
        const int tile = k >> 8, loc = k & 255;
        const int th = tile >> 4, tw = tile & 15;
        const int ph = loc >> 4, pw = loc & 15;
        const int oh = th*16 + ph, owc = tw*16 + pw;
        unsigned r = 0;
        if (oh < cM && owc + 3 < cM) {
            const float4 f = *(const float4*)(src + oh*cM + owc);
            unsigned lo = (unsigned)__builtin_amdgcn_cvt_pk_fp8_f32(f.x*256.f, f.y*256.f, 0, false);
            unsigned hi = (unsigned)__builtin_amdgcn_cvt_pk_fp8_f32(f.z*256.f, f.w*256.f, 0, false);
            r = (lo & 0xffffu) | (hi << 16);
        }
        *(unsigned*)(dst + k) = r;
    }
}

// ---------------------------------------------------------------------------
// K0c: hst[b][pix][40] bf16 = transpose+cast of hs (ch 0..38, ch39 = 0).
// ---------------------------------------------------------------------------
__global__ __launch_bounds__(256) void k_hst(const float* __restrict__ hs,
                                             u16* __restrict__ hst) {
    const int b  = blockIdx.y;
    const int px = blockIdx.x * 256 + threadIdx.x;
    const float* hb = hs + (size_t)b * (cL * cDD) + px;
    u32 w[20];
    #pragma unroll
    for (int c2 = 0; c2 < 20; ++c2) {
        const int c0 = 2*c2, c1 = 2*c2 + 1;
        const u32 lo = f2bf(hb[(size_t)c0 * cDD]);
        const u32 hi = (c1 < cL) ? (u32)f2bf(hb[(size_t)c1 * cDD]) : 0u;
        w[c2] = lo | (hi << 16);
    }
    u16* ob = hst + (size_t)b * (65536 * PROW) + (size_t)px * PROW;
    #pragma unroll
    for (int g = 0; g < 5; ++g) {
        uint4 v;
        v.x = w[g*4 + 0]; v.y = w[g*4 + 1]; v.z = w[g*4 + 2]; v.w = w[g*4 + 3];
        *(uint4*)(ob + g*8) = v;
    }
}

// ---------------------------------------------------------------------------
// K1: MFMA gram. A-frag == B-frag, read straight from hst (strided u16).
// ---------------------------------------------------------------------------
__global__ __launch_bounds__(256) void k_gram(const u16* __restrict__ hst,
                                              float* __restrict__ sp) {
    const int b  = blockIdx.y;
    const int kc = blockIdx.x;
    const int tid = threadIdx.x;
    const int wv = tid >> 6, ln15 = tid & 15, kg4 = (tid & 63) >> 4;
    const u16* hb = hst + (size_t)b * (65536 * PROW);
    const int px0 = kc * 1024 + wv * 256;

    f32x4 acc[3][3] = {};
    #pragma unroll
    for (int s = 0; s < 8; ++s) {
        const int px = px0 + s * 32 + kg4 * 8;
        short8 f[3];
        #pragma unroll
        for (int o = 0; o < 3; ++o) {
            const int ch = o * 16 + ln15;
            short8 v = {};
            if (ch < PROW) {
                const u16* p = hb + (size_t)px * PROW + ch;
                #pragma unroll
                for (int j = 0; j < 8; ++j) v[j] = (short)p[j * PROW];
            }
            f[o] = v;
        }
        #pragma unroll
        for (int oi = 0; oi < 3; ++oi)
            #pragma unroll
            for (int oj = 0; oj < 3; ++oj)
                acc[oi][oj] = __builtin_amdgcn_mfma_f32_16x16x32_bf16(
                    f[oi], f[oj], acc[oi][oj], 0, 0, 0);
    }

    __shared__ float R[4][48 * 50];
    #pragma unroll
    for (int oi = 0; oi < 3; ++oi)
        #pragma unroll
        for (int oj = 0; oj < 3; ++oj)
            #pragma unroll
            for (int r = 0; r < 4; ++r)
                R[wv][(oi*16 + kg4*4 + r)*50 + oj*16 + ln15] = acc[oi][oj][r];
    __syncthreads();

    float* outp = sp + ((size_t)b * KCHUNKS + kc) * PAIRS;
    for (int idx = tid; idx < PAIRS; idx += 256) {
        const int i = idx / 39, j = idx - i * 39;
        const int a = i * 50 + j;
        outp[idx] = R[0][a] + R[1][a] + R[2][a] + R[3][a];
    }
}

// ---------------------------------------------------------------------------
// K2: reduce gram partials, scale 1/256, row softmax.
// ---------------------------------------------------------------------------
__global__ __launch_bounds__(256) void k_softmax(const float* __restrict__ sp,
                                                 float* __restrict__ attnWs,
                                                 float* __restrict__ outAttn) {
    const int b = blockIdx.x;
    const int tid = threadIdx.x;
    __shared__ float sc[PAIRS];
    for (int idx = tid; idx < PAIRS; idx += 256) {
        float s = 0.f;
        for (int c = 0; c < KCHUNKS; ++c)
            s += sp[((size_t)b * KCHUNKS + c) * PAIRS + idx];
        sc[idx] = s * (1.0f / 256.0f);
    }
    __syncthreads();
    if (tid < cL) {
        const int i = tid;
        float m = -1e30f;
        #pragma unroll
        for (int j = 0; j < cL; ++j) m = fmaxf(m, sc[i*cL + j]);
        float e[cL];
        float sum = 0.f;
        #pragma unroll
        for (int j = 0; j < cL; ++j) { e[j] = expf(sc[i*cL + j] - m); sum += e[j]; }
        const float inv = 1.0f / sum;
        #pragma unroll
        for (int j = 0; j < cL; ++j) {
            const float a = e[j] * inv;
            attnWs [(size_t)b*PAIRS + i*cL + j] = a;
            outAttn[(size_t)b*PAIRS + i*cL + j] = a;
        }
    }
}

// ---------------------------------------------------------------------------
// K3: fold attention into conv weights -> dense-K bf16 MFMA A-layout.
// ---------------------------------------------------------------------------
__global__ __launch_bounds__(1024) void k_wtrans(const float* __restrict__ cw,
                                                 const float* __restrict__ attn,
                                                 u16* __restrict__ w2m,
                                                 u16* __restrict__ w2t) {
    const int b = blockIdx.x;
    const int t = threadIdx.x;
    __shared__ float at[PAIRS];
    for (int idx = t; idx < PAIRS; idx += 1024)
        at[idx] = attn[(size_t)b*PAIRS + idx];
    u32* zm = (u32*)(w2m + (size_t)b * 25*48*32);
    u32* zt = (u32*)(w2t + (size_t)b * 7*48*32);
    for (int i = t; i < 25*48*16; i += 1024) zm[i] = 0;
    for (int i = t; i < 7*48*16;  i += 1024) zt[i] = 0;
    __syncthreads();
    if (t < cL * 25) {
        const int oc = t / 25, tap = t % 25;
        float c[cL];
        #pragma unroll
        for (int i = 0; i < cL; ++i)
            c[i] = cw[(size_t)oc * (cL*25) + i*25 + tap];
        u16* dm = w2m + ((size_t)(b*25 + tap)*48 + oc)*32;
        u16* dt = w2t + ((size_t)(b*7 + (tap>>2))*48 + oc)*32 + (tap&3)*8;
        for (int j = 0; j < cL; ++j) {
            float a = 0.f;
            #pragma unroll
            for (int i = 0; i < cL; ++i) a = fmaf(c[i], at[i*cL + j], a);
            if (j < 32) dm[j] = f2bf(a);
            else        dt[j - 32] = f2bf(a);
        }
    }
}

// ---------------------------------------------------------------------------
// K4: conv as dense-K MFMA; epilogue writes tile-major fp8 (full lines per
// block -> no RFO/write-amp). Invalid/tril pixels written as 0.
// ---------------------------------------------------------------------------
__global__ __launch_bounds__(256, 4) void k_conv(const u16* __restrict__ hst,
                                                 const u16* __restrict__ w2m,
                                                 const u16* __restrict__ w2t,
                                                 const float* __restrict__ cb,
                                                 u8* __restrict__ convout,
                                                 float* __restrict__ tileSumsq) {
    const int b   = blockIdx.z;
    const int gh0 = blockIdx.y * 16, gw0 = blockIdx.x * 16;
    const int tid = threadIdx.x;
    const int wv  = tid >> 6;
    const int ln15 = tid & 15;
    const int kg4  = (tid & 63) >> 4;

    __shared__ u16 P[400 * PROW];     // 32 KB
    __shared__ float red[4][48];

    const u16* hb = hst + (size_t)b * (65536 * PROW);
    for (int c = tid; c < 2000; c += 256) {
        const int p = c / 5, g = c - p*5;
        const int pr = p / 20, pc = p - pr*20;
        const int gh = min(gh0 + pr, 255);
        const size_t pix = (size_t)gh * 256 + gw0 + pc;   // may spill; masked later
        const short8 v = *(const short8*)(hb + pix*PROW + g*8);
        *(short8*)&P[p*PROW + g*8] = v;
    }
    __syncthreads();

    f32x4 acc[3][4] = {};
    const u16* wbm = w2m + (size_t)b * 25*48*32;
    const u16* wbt = w2t + (size_t)b * 7*48*32;

    #pragma unroll
    for (int tap = 0; tap < 25; ++tap) {
        const int kh = tap / 5, kw = tap % 5;
        const u16* wt = wbm + (size_t)tap * 48*32;
        short8 af[3];
        #pragma unroll
        for (int o = 0; o < 3; ++o)
            af[o] = *(const short8*)(wt + (o*16 + ln15)*32 + kg4*8);
        #pragma unroll
        for (int pt = 0; pt < 4; ++pt) {
            const int p = (wv*4 + pt + kh)*20 + ln15 + kw;
            const short8 bfr = *(const short8*)&P[p*PROW + kg4*8];
            #pragma unroll
            for (int o = 0; o < 3; ++o)
                acc[o][pt] = __builtin_amdgcn_mfma_f32_16x16x32_bf16(
                    af[o], bfr, acc[o][pt], 0, 0, 0);
        }
    }

    #pragma unroll
    for (int kc = 0; kc < 7; ++kc) {
        const u16* wt = wbt + (size_t)kc * 48*32;
        short8 af[3];
        #pragma unroll
        for (int o = 0; o < 3; ++o)
            af[o] = *(const short8*)(wt + (o*16 + ln15)*32 + kg4*8);
        int tap = kc*4 + kg4;
        if (tap > 24) tap = 24;
        const int kh = tap / 5, kw = tap - kh*5;
        #pragma unroll
        for (int pt = 0; pt < 4; ++pt) {
            const int p = (wv*4 + pt + kh)*20 + ln15 + kw;
            const short8 bfr = *(const short8*)&P[p*PROW + 32];
            #pragma unroll
            for (int o = 0; o < 3; ++o)
                acc[o][pt] = __builtin_amdgcn_mfma_f32_16x16x32_bf16(
                    af[o], bfr, acc[o][pt], 0, 0, 0);
        }
    }

    float ss[3][4];
    #pragma unroll
    for (int o = 0; o < 3; ++o)
        #pragma unroll
        for (int r = 0; r < 4; ++r) ss[o][r] = 0.f;

    const int tile = blockIdx.y * 16 + blockIdx.x;
    const int ow = gw0 + ln15;
    #pragma unroll
    for (int o = 0; o < 3; ++o) {
        #pragma unroll
        for (int r = 0; r < 4; ++r) {
            const int oc = o*16 + kg4*4 + r;
            const float bias = (oc < cL) ? cb[oc] : 0.f;
            #pragma unroll
            for (int pt = 0; pt < 4; ++pt) {
                const int oh = gh0 + wv*4 + pt;
                const int loc = (wv*4 + pt)*16 + ln15;
                u8 val = 0;
                if (oc < cL && oh < cM && ow < cM) {
                    const float e = __expf(acc[o][pt][r] + bias);
                    if (ow <= oh) val = f2fp8(e);
                    ss[o][r] += e * e;
                }
                if (oc < cL)
                    convout[(size_t)(b*cL + oc)*GKP + tile*256 + loc] = val;
            }
        }
    }

    #pragma unroll
    for (int o = 0; o < 3; ++o) {
        #pragma unroll
        for (int r = 0; r < 4; ++r) {
            float v = ss[o][r];
            v += __shfl_xor(v, 1);
            v += __shfl_xor(v, 2);
            v += __shfl_xor(v, 4);
            v += __shfl_xor(v, 8);
            if (ln15 == 0) red[wv][o*16 + kg4*4 + r] = v;
        }
    }
    __syncthreads();
    if (tid < cL) {
        tileSumsq[((size_t)b*256 + tile)*cL + tid] =
            red[0][tid] + red[1][tid] + red[2][tid] + red[3][tid];
    }
}

// ---------------------------------------------------------------------------
// K4b: norms[row] = sqrt(sum over 256 tiles).
// ---------------------------------------------------------------------------
__global__ __launch_bounds__(256) void k_norm(const float* __restrict__ ts,
                                              float* __restrict__ norms) {
    const int row = blockIdx.x;
    const int b = row / cL, l = row % cL;
    const int tid = threadIdx.x;
    float v = ts[((size_t)b*256 + tid)*cL + l];
    for (int off = 32; off; off >>= 1) v += __shfl_down(v, off, 64);
    __shared__ float r[4];
    if ((tid & 63) == 0) r[tid >> 6] = v;
    __syncthreads();
    if (tid == 0) norms[row] = sqrtf(r[0] + r[1] + r[2] + r[3]);
}

// ---------------------------------------------------------------------------
// K5: fp8 MFMA out-GEMM. grid (1, 3, 128), 512 thr; block tile 128x256,
// wave tile 64x64; double-buffered LDS, rows padded to 80 B.
// ---------------------------------------------------------------------------
__global__ __launch_bounds__(512) void k_gemm(const u8* __restrict__ A,
                                              const u8* __restrict__ Bw,
                                              float* __restrict__ op) {
    const int mt = blockIdx.y, z = blockIdx.z;
    const int tid = threadIdx.x;
    const int wid = tid >> 6, lane = tid & 63;
    const int ln15 = lane & 15, kg4 = lane >> 4;
    const int wm = wid >> 2, wn = wid & 3;

    __shared__ u8 As[2][128*80];
    __shared__ u8 Bs[2][256*80];

    const int mbase = mt * 128;
    const int ra = tid >> 2, sl = tid & 3;
    const int arow = mbase + ra;
    const int aro = (arow < 312) ? arow : 0;
    const u8* Ap  = A  + (size_t)aro * GKP        + z*CSTEP + sl*16;
    const u8* Bp0 = Bw + (size_t)ra * GKP         + z*CSTEP + sl*16;
    const u8* Bp1 = Bw + (size_t)(128 + ra) * GKP + z*CSTEP + sl*16;

    uint4 pa  = *(const uint4*)Ap;
    uint4 pb0 = *(const uint4*)Bp0;
    uint4 pb1 = *(const uint4*)Bp1;

    f32x4 acc[4][4] = {};

    for (int s = 0; s < CSTEP/64; ++s) {
        const int cur = s & 1;
        __syncthreads();
        *(uint4*)&As[cur][ra*80 + sl*16]        = pa;
        *(uint4*)&Bs[cur][ra*80 + sl*16]        = pb0;
        *(uint4*)&Bs[cur][(128 + ra)*80 + sl*16] = pb1;
        __syncthreads();
        if (s + 1 < CSTEP/64) {
            const int off = (s + 1) * 64;
            pa  = *(const uint4*)(Ap + off);
            pb0 = *(const uint4*)(Bp0 + off);
            pb1 = *(const uint4*)(Bp1 + off);
        }
        #pragma unroll
        for (int kc = 0; kc < 2; ++kc) {
            long af[4], bf[4];
            #pragma unroll
            for (int fm = 0; fm < 4; ++fm)
                af[fm] = *(const long*)&As[cur][(wm*64 + fm*16 + ln15)*80 + kc*32 + kg4*8];
            #pragma unroll
            for (int fn = 0; fn < 4; ++fn)
                bf[fn] = *(const long*)&Bs[cur][(wn*64 + fn*16 + ln15)*80 + kc*32 + kg4*8];
            #pragma unroll
            for (int fm = 0; fm < 4; ++fm)
                #pragma unroll
                for (int fn = 0; fn < 4; ++fn)
                    acc[fm][fn] = __builtin_amdgcn_mfma_f32_16x16x32_fp8_fp8(
                        af[fm], bf[fn], acc[fm][fn], 0, 0, 0);
        }
    }

    #pragma unroll
    for (int fm = 0; fm < 4; ++fm) {
        #pragma unroll
        for (int r = 0; r < 4; ++r) {
            const int row = mbase + wm*64 + fm*16 + kg4*4 + r;
            if (row < 312) {
                #pragma unroll
                for (int fn = 0; fn < 4; ++fn) {
                    const int col = wn*64 + fn*16 + ln15;
                    op[((size_t)z*312 + row)*256 + col] = acc[fm][fn][r];
                }
            }
        }
    }
}

// ---------------------------------------------------------------------------
// K5b: reduce K-split partials, divide by (norm*256), write out.
// ---------------------------------------------------------------------------
__global__ __launch_bounds__(256) void k_finish(const float* __restrict__ op,
                                                const float* __restrict__ norms,
                                                float* __restrict__ out) {
    const int idx = blockIdx.x * 256 + threadIdx.x;
    float s = 0.f;
    for (int z = 0; z < GSPLIT; ++z) s += op[(size_t)z * (312*256) + idx];
    out[idx] = s / (norms[idx >> 8] * 256.0f);
}

// ---------------------------------------------------------------------------
extern "C" void kernel_launch(void* const* d_in, const int* in_sizes, int n_in,
                              void* d_out, int out_size, void* d_ws, size_t ws_size,
                              hipStream_t stream) {
    const float* hs = (const float*)d_in[0];
    const float* cw = (const float*)d_in[1];
    const float* cb = (const float*)d_in[2];
    const float* ow = (const float*)d_in[3];
    float* out = (float*)d_out;
    float* ws  = (float*)d_ws;

    if (ws_size < WS_FLOATS * sizeof(float)) return;

    float* sp   = ws + OFF_SP;
    float* ts   = ws + OFF_TS;
    float* nrm  = ws + OFF_NORM;
    float* attn = ws + OFF_ATTN;
    u16*   w2m  = (u16*)(ws + OFF_W2M);
    u16*   w2t  = (u16*)(ws + OFF_W2T);
    u16*   hst  = (u16*)(ws + OFF_HST);
    float* op   = ws + OFF_HST;            // overlaps hst (dead by k_gemm)
    u8*    cv   = (u8*)(ws + OFF_CONV);
    u8*    owb  = (u8*)(ws + OFF_OWB);

    k_hst    <<<dim3(256, cB), 256, 0, stream>>>(hs, hst);
    k_bwcast <<<256, 256, 0, stream>>>(ow, owb);
    k_gram   <<<dim3(KCHUNKS, cB), 256, 0, stream>>>(hst, sp);
    k_softmax<<<cB, 256, 0, stream>>>(sp, attn, out + (size_t)cB*cL*cD);
    k_wtrans <<<cB, 1024, 0, stream>>>(cw, attn, w2m, w2t);
    k_conv   <<<dim3(16, 16, cB), 256, 0, stream>>>(hst, w2m, w2t, cb, cv, ts);
    k_norm   <<<cB*cL, 256, 0, stream>>>(ts, nrm);
    k_gemm   <<<dim3(1, 3, GSPLIT), 512, 0, stream>>>(cv, owb, op);
    k_finish <<<312, 256, 0, stream>>>(op, nrm, out);
}

// Round 8
// 293.275 us; speedup vs baseline: 4.9469x; 1.0180x over previous
//
#include <hip/hip_runtime.h>
#include <math.h>

typedef unsigned short u16;
typedef unsigned int   u32;
typedef unsigned char  u8;
typedef __attribute__((ext_vector_type(8))) short short8;
typedef __attribute__((ext_vector_type(4))) float f32x4;
typedef __attribute__((ext_vector_type(4))) unsigned short ushort4_t;

// GeoMamba: B=8, L=39, D=256, K=5, M=252
constexpr int cB   = 8;
constexpr int cL   = 39;
constexpr int cD   = 256;
constexpr int cDD  = 65536;   // D*D
constexpr int cM   = 252;
constexpr int cMM  = 63504;   // M*M
constexpr int PAIRS = cL * cL; // 1521

constexpr int KCHUNKS = 64;    // gram K-split (1024 px per block)
constexpr int GKP     = 65536; // tile-major K for out-gemm (fp8 bytes per row)
constexpr int CSTEP   = 512;   // K per gemm block
constexpr int GSPLIT  = 128;   // 128*512 = 65536
constexpr int PROW    = 40;    // u16 per pixel row of hst

// ---- ws layout (float offsets) ----
constexpr size_t OFF_SP   = 0;                          // gram partials [B][64][1521]
constexpr size_t SZ_SP    = (size_t)cB * KCHUNKS * PAIRS;
constexpr size_t OFF_TS   = 0;                          // overlaps SP (dead after softmax)
constexpr size_t OFF_NORM = OFF_TS + (size_t)cB * 256 * cL;
constexpr size_t OFF_ATTN = OFF_SP + SZ_SP;
constexpr size_t SZ_ATTN  = (size_t)cB * PAIRS;
constexpr size_t OFF_W2M  = OFF_ATTN + SZ_ATTN;         // main wts bf16 [B][tap25][oc48][32]
constexpr size_t SZ_W2M   = (size_t)cB * 25 * 48 * 32 / 2;
constexpr size_t OFF_W2T  = OFF_W2M + SZ_W2M;           // tail wts bf16 [B][kc7][oc48][32]
constexpr size_t SZ_W2T   = (size_t)cB * 7 * 48 * 32 / 2;
constexpr size_t OFF_HST  = OFF_W2T + SZ_W2T;           // hst bf16 [B][65536][40]; op overlaps
constexpr size_t SZ_HST   = (size_t)cB * 65536 * PROW / 2;   // 10,485,760 floats
constexpr size_t SZ_OP    = (size_t)GSPLIT * 312 * 256;      // 10,223,616 floats
static_assert(SZ_OP <= SZ_HST, "op must fit inside hst region");
constexpr size_t OFF_CONV = OFF_HST + SZ_HST;           // exp(conv) fp8 [312][GKP] tile-major
constexpr size_t SZ_CONV  = (size_t)312 * GKP / 4;
constexpr size_t OFF_OWB  = OFF_CONV + SZ_CONV;         // out_w fp8*256 [256][GKP] tile-major
constexpr size_t SZ_OWB   = (size_t)256 * GKP / 4;
constexpr size_t WS_FLOATS = OFF_OWB + SZ_OWB;          // ~83 MB

__device__ inline u16 f2bf(float x) {
    union { float f; unsigned u; } v; v.f = x;
    unsigned r = v.u + 0x7fffu + ((v.u >> 16) & 1u);   // RNE
    return (u16)(r >> 16);
}
__device__ inline u8 f2fp8(float x) {
    return (u8)(__builtin_amdgcn_cvt_pk_fp8_f32(x, x, 0, false) & 0xff);
}

// ---------------------------------------------------------------------------
// K0a: cast out_w*256 -> fp8 e4m3, gathered into tile-major K layout.
// ---------------------------------------------------------------------------
__global__ __launch_bounds__(256) void k_bwcast(const float* __restrict__ ow,
                                                u8* __restrict__ owb) {
    const int o = blockIdx.x;
    const float* src = ow + (size_t)o * cMM;
    u8* dst = owb + (size_t)o * GKP;
    for (int k4 = threadIdx.x; k4 < GKP / 4; k4 += 256) {
        const int k = k4 * 4;
        const int tile = k >> 8, loc = k & 255;
        const int th = tile >> 4, tw = tile & 15;
        const int ph = loc >> 4, pw = loc & 15;
        const int oh = th*16 + ph, owc = tw*16 + pw;
        unsigned r = 0;
        if (oh < cM && owc + 3 < cM) {
            const float4 f = *(const float4*)(src + oh*cM + owc);
            unsigned lo = (unsigned)__builtin_amdgcn_cvt_pk_fp8_f32(f.x*256.f, f.y*256.f, 0, false);
            unsigned hi = (unsigned)__builtin_amdgcn_cvt_pk_fp8_f32(f.z*256.f, f.w*256.f, 0, false);
            r = (lo & 0xffffu) | (hi << 16);
        }
        *(unsigned*)(dst + k) = r;
    }
}

// ---------------------------------------------------------------------------
// K0c: hst[b][pix][40] bf16 = transpose+cast of hs (ch 0..38, ch39 = 0).
// ---------------------------------------------------------------------------
__global__ __launch_bounds__(256) void k_hst(const float* __restrict__ hs,
                                             u16* __restrict__ hst) {
    const int b  = blockIdx.y;
    const int px = blockIdx.x * 256 + threadIdx.x;
    const float* hb = hs + (size_t)b * (cL * cDD) + px;
    u32 w[20];
    #pragma unroll
    for (int c2 = 0; c2 < 20; ++c2) {
        const int c0 = 2*c2, c1 = 2*c2 + 1;
        const u32 lo = f2bf(hb[(size_t)c0 * cDD]);
        const u32 hi = (c1 < cL) ? (u32)f2bf(hb[(size_t)c1 * cDD]) : 0u;
        w[c2] = lo | (hi << 16);
    }
    u16* ob = hst + (size_t)b * (65536 * PROW) + (size_t)px * PROW;
    #pragma unroll
    for (int g = 0; g < 5; ++g) {
        uint4 v;
        v.x = w[g*4 + 0]; v.y = w[g*4 + 1]; v.z = w[g*4 + 2]; v.w = w[g*4 + 3];
        *(uint4*)(ob + g*8) = v;
    }
}

// ---------------------------------------------------------------------------
// K1: MFMA gram. A-frag == B-frag, read straight from hst (strided u16).
// ---------------------------------------------------------------------------
__global__ __launch_bounds__(256) void k_gram(const u16* __restrict__ hst,
                                              float* __restrict__ sp) {
    const int b  = blockIdx.y;
    const int kc = blockIdx.x;
    const int tid = threadIdx.x;
    const int wv = tid >> 6, ln15 = tid & 15, kg4 = (tid & 63) >> 4;
    const u16* hb = hst + (size_t)b * (65536 * PROW);
    const int px0 = kc * 1024 + wv * 256;

    f32x4 acc[3][3] = {};
    #pragma unroll
    for (int s = 0; s < 8; ++s) {
        const int px = px0 + s * 32 + kg4 * 8;
        short8 f[3];
        #pragma unroll
        for (int o = 0; o < 3; ++o) {
            const int ch = o * 16 + ln15;
            short8 v = {};
            if (ch < PROW) {
                const u16* p = hb + (size_t)px * PROW + ch;
                #pragma unroll
                for (int j = 0; j < 8; ++j) v[j] = (short)p[j * PROW];
            }
            f[o] = v;
        }
        #pragma unroll
        for (int oi = 0; oi < 3; ++oi)
            #pragma unroll
            for (int oj = 0; oj < 3; ++oj)
                acc[oi][oj] = __builtin_amdgcn_mfma_f32_16x16x32_bf16(
                    f[oi], f[oj], acc[oi][oj], 0, 0, 0);
    }

    __shared__ float R[4][48 * 50];
    #pragma unroll
    for (int oi = 0; oi < 3; ++oi)
        #pragma unroll
        for (int oj = 0; oj < 3; ++oj)
            #pragma unroll
            for (int r = 0; r < 4; ++r)
                R[wv][(oi*16 + kg4*4 + r)*50 + oj*16 + ln15] = acc[oi][oj][r];
    __syncthreads();

    float* outp = sp + ((size_t)b * KCHUNKS + kc) * PAIRS;
    for (int idx = tid; idx < PAIRS; idx += 256) {
        const int i = idx / 39, j = idx - i * 39;
        const int a = i * 50 + j;
        outp[idx] = R[0][a] + R[1][a] + R[2][a] + R[3][a];
    }
}

// ---------------------------------------------------------------------------
// K2: reduce gram partials, scale 1/256, row softmax.
// ---------------------------------------------------------------------------
__global__ __launch_bounds__(256) void k_softmax(const float* __restrict__ sp,
                                                 float* __restrict__ attnWs,
                                                 float* __restrict__ outAttn) {
    const int b = blockIdx.x;
    const int tid = threadIdx.x;
    __shared__ float sc[PAIRS];
    for (int idx = tid; idx < PAIRS; idx += 256) {
        float s = 0.f;
        for (int c = 0; c < KCHUNKS; ++c)
            s += sp[((size_t)b * KCHUNKS + c) * PAIRS + idx];
        sc[idx] = s * (1.0f / 256.0f);
    }
    __syncthreads();
    if (tid < cL) {
        const int i = tid;
        float m = -1e30f;
        #pragma unroll
        for (int j = 0; j < cL; ++j) m = fmaxf(m, sc[i*cL + j]);
        float e[cL];
        float sum = 0.f;
        #pragma unroll
        for (int j = 0; j < cL; ++j) { e[j] = expf(sc[i*cL + j] - m); sum += e[j]; }
        const float inv = 1.0f / sum;
        #pragma unroll
        for (int j = 0; j < cL; ++j) {
            const float a = e[j] * inv;
            attnWs [(size_t)b*PAIRS + i*cL + j] = a;
            outAttn[(size_t)b*PAIRS + i*cL + j] = a;
        }
    }
}

// ---------------------------------------------------------------------------
// K3: fold attention into conv weights -> dense-K bf16 MFMA A-layout.
// ---------------------------------------------------------------------------
__global__ __launch_bounds__(1024) void k_wtrans(const float* __restrict__ cw,
                                                 const float* __restrict__ attn,
                                                 u16* __restrict__ w2m,
                                                 u16* __restrict__ w2t) {
    const int b = blockIdx.x;
    const int t = threadIdx.x;
    __shared__ float at[PAIRS];
    for (int idx = t; idx < PAIRS; idx += 1024)
        at[idx] = attn[(size_t)b*PAIRS + idx];
    u32* zm = (u32*)(w2m + (size_t)b * 25*48*32);
    u32* zt = (u32*)(w2t + (size_t)b * 7*48*32);
    for (int i = t; i < 25*48*16; i += 1024) zm[i] = 0;
    for (int i = t; i < 7*48*16;  i += 1024) zt[i] = 0;
    __syncthreads();
    if (t < cL * 25) {
        const int oc = t / 25, tap = t % 25;
        float c[cL];
        #pragma unroll
        for (int i = 0; i < cL; ++i)
            c[i] = cw[(size_t)oc * (cL*25) + i*25 + tap];
        u16* dm = w2m + ((size_t)(b*25 + tap)*48 + oc)*32;
        u16* dt = w2t + ((size_t)(b*7 + (tap>>2))*48 + oc)*32 + (tap&3)*8;
        for (int j = 0; j < cL; ++j) {
            float a = 0.f;
            #pragma unroll
            for (int i = 0; i < cL; ++i) a = fmaf(c[i], at[i*cL + j], a);
            if (j < 32) dm[j] = f2bf(a);
            else        dt[j - 32] = f2bf(a);
        }
    }
}

// ---------------------------------------------------------------------------
// K4: conv as dense-K MFMA; epilogue stages fp8 tile in LDS (reusing P) and
// writes 16B-vectorized full-line stores (624 dwordx4 per block).
// ---------------------------------------------------------------------------
__global__ __launch_bounds__(256, 4) void k_conv(const u16* __restrict__ hst,
                                                 const u16* __restrict__ w2m,
                                                 const u16* __restrict__ w2t,
                                                 const float* __restrict__ cb,
                                                 u8* __restrict__ convout,
                                                 float* __restrict__ tileSumsq) {
    const int b   = blockIdx.z;
    const int gh0 = blockIdx.y * 16, gw0 = blockIdx.x * 16;
    const int tid = threadIdx.x;
    const int wv  = tid >> 6;
    const int ln15 = tid & 15;
    const int kg4  = (tid & 63) >> 4;

    __shared__ u16 P[400 * PROW];     // 32 KB; reused as fp8 staging in epilogue
    __shared__ float red[4][48];

    const u16* hb = hst + (size_t)b * (65536 * PROW);
    for (int c = tid; c < 2000; c += 256) {
        const int p = c / 5, g = c - p*5;
        const int pr = p / 20, pc = p - pr*20;
        const int gh = min(gh0 + pr, 255);
        const size_t pix = (size_t)gh * 256 + gw0 + pc;   // may spill; masked later
        const short8 v = *(const short8*)(hb + pix*PROW + g*8);
        *(short8*)&P[p*PROW + g*8] = v;
    }
    __syncthreads();

    f32x4 acc[3][4] = {};
    const u16* wbm = w2m + (size_t)b * 25*48*32;
    const u16* wbt = w2t + (size_t)b * 7*48*32;

    #pragma unroll
    for (int tap = 0; tap < 25; ++tap) {
        const int kh = tap / 5, kw = tap % 5;
        const u16* wt = wbm + (size_t)tap * 48*32;
        short8 af[3];
        #pragma unroll
        for (int o = 0; o < 3; ++o)
            af[o] = *(const short8*)(wt + (o*16 + ln15)*32 + kg4*8);
        #pragma unroll
        for (int pt = 0; pt < 4; ++pt) {
            const int p = (wv*4 + pt + kh)*20 + ln15 + kw;
            const short8 bfr = *(const short8*)&P[p*PROW + kg4*8];
            #pragma unroll
            for (int o = 0; o < 3; ++o)
                acc[o][pt] = __builtin_amdgcn_mfma_f32_16x16x32_bf16(
                    af[o], bfr, acc[o][pt], 0, 0, 0);
        }
    }

    #pragma unroll
    for (int kc = 0; kc < 7; ++kc) {
        const u16* wt = wbt + (size_t)kc * 48*32;
        short8 af[3];
        #pragma unroll
        for (int o = 0; o < 3; ++o)
            af[o] = *(const short8*)(wt + (o*16 + ln15)*32 + kg4*8);
        int tap = kc*4 + kg4;
        if (tap > 24) tap = 24;
        const int kh = tap / 5, kw = tap - kh*5;
        #pragma unroll
        for (int pt = 0; pt < 4; ++pt) {
            const int p = (wv*4 + pt + kh)*20 + ln15 + kw;
            const short8 bfr = *(const short8*)&P[p*PROW + 32];
            #pragma unroll
            for (int o = 0; o < 3; ++o)
                acc[o][pt] = __builtin_amdgcn_mfma_f32_16x16x32_bf16(
                    af[o], bfr, acc[o][pt], 0, 0, 0);
        }
    }

    __syncthreads();                  // P reads done; reuse as E
    u8* E = (u8*)P;                   // E[oc][256] fp8 staging (9984 B)

    float ss[3][4];
    #pragma unroll
    for (int o = 0; o < 3; ++o)
        #pragma unroll
        for (int r = 0; r < 4; ++r) ss[o][r] = 0.f;

    const int tile = blockIdx.y * 16 + blockIdx.x;
    const int ow = gw0 + ln15;
    #pragma unroll
    for (int o = 0; o < 3; ++o) {
        #pragma unroll
        for (int r = 0; r < 4; ++r) {
            const int oc = o*16 + kg4*4 + r;
            const float bias = (oc < cL) ? cb[oc] : 0.f;
            #pragma unroll
            for (int pt = 0; pt < 4; ++pt) {
                const int oh = gh0 + wv*4 + pt;
                const int loc = (wv*4 + pt)*16 + ln15;
                u8 val = 0;
                if (oc < cL && oh < cM && ow < cM) {
                    const float e = __expf(acc[o][pt][r] + bias);
                    if (ow <= oh) val = f2fp8(e);
                    ss[o][r] += e * e;
                }
                if (oc < cL) E[oc*256 + loc] = val;
            }
        }
    }
    __syncthreads();

    // full-line vectorized stores: 39 oc x 16 segs of 16B
    for (int c = tid; c < cL*16; c += 256) {
        const int oc = c >> 4, seg = c & 15;
        const uint4 v = *(const uint4*)&E[oc*256 + seg*16];
        *(uint4*)&convout[(size_t)(b*cL + oc)*GKP + tile*256 + seg*16] = v;
    }

    #pragma unroll
    for (int o = 0; o < 3; ++o) {
        #pragma unroll
        for (int r = 0; r < 4; ++r) {
            float v = ss[o][r];
            v += __shfl_xor(v, 1);
            v += __shfl_xor(v, 2);
            v += __shfl_xor(v, 4);
            v += __shfl_xor(v, 8);
            if (ln15 == 0) red[wv][o*16 + kg4*4 + r] = v;
        }
    }
    __syncthreads();
    if (tid < cL) {
        tileSumsq[((size_t)b*256 + tile)*cL + tid] =
            red[0][tid] + red[1][tid] + red[2][tid] + red[3][tid];
    }
}

// ---------------------------------------------------------------------------
// K4b: norms[row] = sqrt(sum over 256 tiles).
// ---------------------------------------------------------------------------
__global__ __launch_bounds__(256) void k_norm(const float* __restrict__ ts,
                                              float* __restrict__ norms) {
    const int row = blockIdx.x;
    const int b = row / cL, l = row % cL;
    const int tid = threadIdx.x;
    float v = ts[((size_t)b*256 + tid)*cL + l];
    for (int off = 32; off; off >>= 1) v += __shfl_down(v, off, 64);
    __shared__ float r[4];
    if ((tid & 63) == 0) r[tid >> 6] = v;
    __syncthreads();
    if (tid == 0) norms[row] = sqrtf(r[0] + r[1] + r[2] + r[3]);
}

// ---------------------------------------------------------------------------
// K5: fp8 MFMA out-GEMM. grid (1, 3, 128), 512 thr; block tile 128x256,
// wave tile 64x64; double-buffered LDS, rows padded to 80 B.
// ---------------------------------------------------------------------------
__global__ __launch_bounds__(512) void k_gemm(const u8* __restrict__ A,
                                              const u8* __restrict__ Bw,
                                              float* __restrict__ op) {
    const int mt = blockIdx.y, z = blockIdx.z;
    const int tid = threadIdx.x;
    const int wid = tid >> 6, lane = tid & 63;
    const int ln15 = lane & 15, kg4 = lane >> 4;
    const int wm = wid >> 2, wn = wid & 3;

    __shared__ u8 As[2][128*80];
    __shared__ u8 Bs[2][256*80];

    const int mbase = mt * 128;
    const int ra = tid >> 2, sl = tid & 3;
    const int arow = mbase + ra;
    const int aro = (arow < 312) ? arow : 0;
    const u8* Ap  = A  + (size_t)aro * GKP        + z*CSTEP + sl*16;
    const u8* Bp0 = Bw + (size_t)ra * GKP         + z*CSTEP + sl*16;
    const u8* Bp1 = Bw + (size_t)(128 + ra) * GKP + z*CSTEP + sl*16;

    uint4 pa  = *(const uint4*)Ap;
    uint4 pb0 = *(const uint4*)Bp0;
    uint4 pb1 = *(const uint4*)Bp1;

    f32x4 acc[4][4] = {};

    for (int s = 0; s < CSTEP/64; ++s) {
        const int cur = s & 1;
        __syncthreads();
        *(uint4*)&As[cur][ra*80 + sl*16]        = pa;
        *(uint4*)&Bs[cur][ra*80 + sl*16]        = pb0;
        *(uint4*)&Bs[cur][(128 + ra)*80 + sl*16] = pb1;
        __syncthreads();
        if (s + 1 < CSTEP/64) {
            const int off = (s + 1) * 64;
            pa  = *(const uint4*)(Ap + off);
            pb0 = *(const uint4*)(Bp0 + off);
            pb1 = *(const uint4*)(Bp1 + off);
        }
        #pragma unroll
        for (int kc = 0; kc < 2; ++kc) {
            long af[4], bf[4];
            #pragma unroll
            for (int fm = 0; fm < 4; ++fm)
                af[fm] = *(const long*)&As[cur][(wm*64 + fm*16 + ln15)*80 + kc*32 + kg4*8];
            #pragma unroll
            for (int fn = 0; fn < 4; ++fn)
                bf[fn] = *(const long*)&Bs[cur][(wn*64 + fn*16 + ln15)*80 + kc*32 + kg4*8];
            #pragma unroll
            for (int fm = 0; fm < 4; ++fm)
                #pragma unroll
                for (int fn = 0; fn < 4; ++fn)
                    acc[fm][fn] = __builtin_amdgcn_mfma_f32_16x16x32_fp8_fp8(
                        af[fm], bf[fn], acc[fm][fn], 0, 0, 0);
        }
    }

    #pragma unroll
    for (int fm = 0; fm < 4; ++fm) {
        #pragma unroll
        for (int r = 0; r < 4; ++r) {
            const int row = mbase + wm*64 + fm*16 + kg4*4 + r;
            if (row < 312) {
                #pragma unroll
                for (int fn = 0; fn < 4; ++fn) {
                    const int col = wn*64 + fn*16 + ln15;
                    op[((size_t)z*312 + row)*256 + col] = acc[fm][fn][r];
                }
            }
        }
    }
}

// ---------------------------------------------------------------------------
// K5b: reduce K-split partials, divide by (norm*256), write out.
// ---------------------------------------------------------------------------
__global__ __launch_bounds__(256) void k_finish(const float* __restrict__ op,
                                                const float* __restrict__ norms,
                                                float* __restrict__ out) {
    const int idx = blockIdx.x * 256 + threadIdx.x;
    float s = 0.f;
    for (int z = 0; z < GSPLIT; ++z) s += op[(size_t)z * (312*256) + idx];
    out[idx] = s / (norms[idx >> 8] * 256.0f);
}

// ---------------------------------------------------------------------------
extern "C" void kernel_launch(void* const* d_in, const int* in_sizes, int n_in,
                              void* d_out, int out_size, void* d_ws, size_t ws_size,
                              hipStream_t stream) {
    const float* hs = (const float*)d_in[0];
    const float* cw = (const float*)d_in[1];
    const float* cb = (const float*)d_in[2];
    const float* ow = (const float*)d_in[3];
    float* out = (float*)d_out;
    float* ws  = (float*)d_ws;

    if (ws_size < WS_FLOATS * sizeof(float)) return;

    float* sp   = ws + OFF_SP;
    float* ts   = ws + OFF_TS;
    float* nrm  = ws + OFF_NORM;
    float* attn = ws + OFF_ATTN;
    u16*   w2m  = (u16*)(ws + OFF_W2M);
    u16*   w2t  = (u16*)(ws + OFF_W2T);
    u16*   hst  = (u16*)(ws + OFF_HST);
    float* op   = ws + OFF_HST;            // overlaps hst (dead by k_gemm)
    u8*    cv   = (u8*)(ws + OFF_CONV);
    u8*    owb  = (u8*)(ws + OFF_OWB);

    k_hst    <<<dim3(256, cB), 256, 0, stream>>>(hs, hst);
    k_bwcast <<<256, 256, 0, stream>>>(ow, owb);
    k_gram   <<<dim3(KCHUNKS, cB), 256, 0, stream>>>(hst, sp);
    k_softmax<<<cB, 256, 0, stream>>>(sp, attn, out + (size_t)cB*cL*cD);
    k_wtrans <<<cB, 1024, 0, stream>>>(cw, attn, w2m, w2t);
    k_conv   <<<dim3(16, 16, cB), 256, 0, stream>>>(hst, w2m, w2t, cb, cv, ts);
    k_norm   <<<cB*cL, 256, 0, stream>>>(ts, nrm);
    k_gemm   <<<dim3(1, 3, GSPLIT), 512, 0, stream>>>(cv, owb, op);
    k_finish <<<312, 256, 0, stream>>>(op, nrm, out);
}

// Round 9
// 289.873 us; speedup vs baseline: 5.0050x; 1.0117x over previous
//
#include <hip/hip_runtime.h>
#include <math.h>

typedef unsigned short u16;
typedef unsigned int   u32;
typedef unsigned char  u8;
typedef __attribute__((ext_vector_type(8))) short short8;
typedef __attribute__((ext_vector_type(4))) float f32x4;
typedef __attribute__((ext_vector_type(4))) unsigned short ushort4_t;

// GeoMamba: B=8, L=39, D=256, K=5, M=252
constexpr int cB   = 8;
constexpr int cL   = 39;
constexpr int cD   = 256;
constexpr int cDD  = 65536;   // D*D
constexpr int cM   = 252;
constexpr int cMM  = 63504;   // M*M
constexpr int PAIRS = cL * cL; // 1521

constexpr int KCHUNKS = 64;    // gram K-split (1024 px per block)
constexpr int GKP     = 65536; // tile-major K for out-gemm (fp8 bytes per row)
constexpr int CSTEP   = 512;   // K per gemm block
constexpr int GSPLIT  = 128;   // 128*512 = 65536
constexpr int PROW    = 40;    // u16 per pixel row of hst

// ---- ws layout (float offsets) ----
constexpr size_t OFF_SP   = 0;                          // gram partials [B][64][1521]
constexpr size_t SZ_SP    = (size_t)cB * KCHUNKS * PAIRS;
constexpr size_t OFF_TS   = 0;                          // overlaps SP (dead after softmax)
constexpr size_t OFF_NORM = OFF_TS + (size_t)cB * 256 * cL;
constexpr size_t OFF_ATTN = OFF_SP + SZ_SP;
constexpr size_t SZ_ATTN  = (size_t)cB * PAIRS;
constexpr size_t OFF_W2M  = OFF_ATTN + SZ_ATTN;         // main wts bf16 [B][tap25][oc48][32]
constexpr size_t SZ_W2M   = (size_t)cB * 25 * 48 * 32 / 2;
constexpr size_t OFF_W2T  = OFF_W2M + SZ_W2M;           // tail wts bf16 [B][kc7][oc48][32]
constexpr size_t SZ_W2T   = (size_t)cB * 7 * 48 * 32 / 2;
constexpr size_t OFF_HST  = OFF_W2T + SZ_W2T;           // hst bf16 [B][65536][40]; op overlaps
constexpr size_t SZ_HST   = (size_t)cB * 65536 * PROW / 2;   // 10,485,760 floats
constexpr size_t SZ_OP    = (size_t)GSPLIT * 312 * 256;      // 10,223,616 floats
static_assert(SZ_OP <= SZ_HST, "op must fit inside hst region");
constexpr size_t OFF_CONV = OFF_HST + SZ_HST;           // exp(conv) fp8 [312][GKP] tile-major
constexpr size_t SZ_CONV  = (size_t)312 * GKP / 4;
constexpr size_t OFF_OWB  = OFF_CONV + SZ_CONV;         // out_w fp8*256 [256][GKP] tile-major
constexpr size_t SZ_OWB   = (size_t)256 * GKP / 4;
constexpr size_t WS_FLOATS = OFF_OWB + SZ_OWB;          // ~83 MB

__device__ inline u16 f2bf(float x) {
    union { float f; unsigned u; } v; v.f = x;
    unsigned r = v.u + 0x7fffu + ((v.u >> 16) & 1u);   // RNE
    return (u16)(r >> 16);
}
__device__ inline u8 f2fp8(float x) {
    return (u8)(__builtin_amdgcn_cvt_pk_fp8_f32(x, x, 0, false) & 0xff);
}

// ---------------------------------------------------------------------------
// K0a: cast out_w*256 -> fp8 e4m3, gathered into tile-major K layout.
// ---------------------------------------------------------------------------
__global__ __launch_bounds__(256) void k_bwcast(const float* __restrict__ ow,
                                                u8* __restrict__ owb) {
    const int o = blockIdx.x;
    const float* src = ow + (size_t)o * cMM;
    u8* dst = owb + (size_t)o * GKP;
    for (int k4 = threadIdx.x; k4 < GKP / 4; k4 += 256) {
        const int k = k4 * 4;
        const int tile = k >> 8, loc = k & 255;
        const int th = tile >> 4, tw = tile & 15;
        const int ph = loc >> 4, pw = loc & 15;
        const int oh = th*16 + ph, owc = tw*16 + pw;
        unsigned r = 0;
        if (oh < cM && owc + 3 < cM) {
            const float4 f = *(const float4*)(src + oh*cM + owc);
            unsigned lo = (unsigned)__builtin_amdgcn_cvt_pk_fp8_f32(f.x*256.f, f.y*256.f, 0, false);
            unsigned hi = (unsigned)__builtin_amdgcn_cvt_pk_fp8_f32(f.z*256.f, f.w*256.f, 0, false);
            r = (lo & 0xffffu) | (hi << 16);
        }
        *(unsigned*)(dst + k) = r;
    }
}

// ---------------------------------------------------------------------------
// K0c: hst[b][pix][40] bf16 = transpose+cast of hs (ch 0..38, ch39 = 0).
// ---------------------------------------------------------------------------
__global__ __launch_bounds__(256) void k_hst(const float* __restrict__ hs,
                                             u16* __restrict__ hst) {
    const int b  = blockIdx.y;
    const int px = blockIdx.x * 256 + threadIdx.x;
    const float* hb = hs + (size_t)b * (cL * cDD) + px;
    u32 w[20];
    #pragma unroll
    for (int c2 = 0; c2 < 20; ++c2) {
        const int c0 = 2*c2, c1 = 2*c2 + 1;
        const u32 lo = f2bf(hb[(size_t)c0 * cDD]);
        const u32 hi = (c1 < cL) ? (u32)f2bf(hb[(size_t)c1 * cDD]) : 0u;
        w[c2] = lo | (hi << 16);
    }
    u16* ob = hst + (size_t)b * (65536 * PROW) + (size_t)px * PROW;
    #pragma unroll
    for (int g = 0; g < 5; ++g) {
        uint4 v;
        v.x = w[g*4 + 0]; v.y = w[g*4 + 1]; v.z = w[g*4 + 2]; v.w = w[g*4 + 3];
        *(uint4*)(ob + g*8) = v;
    }
}

// ---------------------------------------------------------------------------
// K1: MFMA gram. A-frag == B-frag, read straight from hst (strided u16).
// ---------------------------------------------------------------------------
__global__ __launch_bounds__(256) void k_gram(const u16* __restrict__ hst,
                                              float* __restrict__ sp) {
    const int b  = blockIdx.y;
    const int kc = blockIdx.x;
    const int tid = threadIdx.x;
    const int wv = tid >> 6, ln15 = tid & 15, kg4 = (tid & 63) >> 4;
    const u16* hb = hst + (size_t)b * (65536 * PROW);
    const int px0 = kc * 1024 + wv * 256;

    f32x4 acc[3][3] = {};
    #pragma unroll
    for (int s = 0; s < 8; ++s) {
        const int px = px0 + s * 32 + kg4 * 8;
        short8 f[3];
        #pragma unroll
        for (int o = 0; o < 3; ++o) {
            const int ch = o * 16 + ln15;
            short8 v = {};
            if (ch < PROW) {
                const u16* p = hb + (size_t)px * PROW + ch;
                #pragma unroll
                for (int j = 0; j < 8; ++j) v[j] = (short)p[j * PROW];
            }
            f[o] = v;
        }
        #pragma unroll
        for (int oi = 0; oi < 3; ++oi)
            #pragma unroll
            for (int oj = 0; oj < 3; ++oj)
                acc[oi][oj] = __builtin_amdgcn_mfma_f32_16x16x32_bf16(
                    f[oi], f[oj], acc[oi][oj], 0, 0, 0);
    }

    __shared__ float R[4][48 * 50];
    #pragma unroll
    for (int oi = 0; oi < 3; ++oi)
        #pragma unroll
        for (int oj = 0; oj < 3; ++oj)
            #pragma unroll
            for (int r = 0; r < 4; ++r)
                R[wv][(oi*16 + kg4*4 + r)*50 + oj*16 + ln15] = acc[oi][oj][r];
    __syncthreads();

    float* outp = sp + ((size_t)b * KCHUNKS + kc) * PAIRS;
    for (int idx = tid; idx < PAIRS; idx += 256) {
        const int i = idx / 39, j = idx - i * 39;
        const int a = i * 50 + j;
        outp[idx] = R[0][a] + R[1][a] + R[2][a] + R[3][a];
    }
}

// ---------------------------------------------------------------------------
// K2: reduce gram partials, scale 1/256, row softmax.
// ---------------------------------------------------------------------------
__global__ __launch_bounds__(256) void k_softmax(const float* __restrict__ sp,
                                                 float* __restrict__ attnWs,
                                                 float* __restrict__ outAttn) {
    const int b = blockIdx.x;
    const int tid = threadIdx.x;
    __shared__ float sc[PAIRS];
    for (int idx = tid; idx < PAIRS; idx += 256) {
        float s = 0.f;
        for (int c = 0; c < KCHUNKS; ++c)
            s += sp[((size_t)b * KCHUNKS + c) * PAIRS + idx];
        sc[idx] = s * (1.0f / 256.0f);
    }
    __syncthreads();
    if (tid < cL) {
        const int i = tid;
        float m = -1e30f;
        #pragma unroll
        for (int j = 0; j < cL; ++j) m = fmaxf(m, sc[i*cL + j]);
        float e[cL];
        float sum = 0.f;
        #pragma unroll
        for (int j = 0; j < cL; ++j) { e[j] = expf(sc[i*cL + j] - m); sum += e[j]; }
        const float inv = 1.0f / sum;
        #pragma unroll
        for (int j = 0; j < cL; ++j) {
            const float a = e[j] * inv;
            attnWs [(size_t)b*PAIRS + i*cL + j] = a;
            outAttn[(size_t)b*PAIRS + i*cL + j] = a;
        }
    }
}

// ---------------------------------------------------------------------------
// K3: fold attention into conv weights -> dense-K bf16 MFMA A-layout.
// ---------------------------------------------------------------------------
__global__ __launch_bounds__(1024) void k_wtrans(const float* __restrict__ cw,
                                                 const float* __restrict__ attn,
                                                 u16* __restrict__ w2m,
                                                 u16* __restrict__ w2t) {
    const int b = blockIdx.x;
    const int t = threadIdx.x;
    __shared__ float at[PAIRS];
    for (int idx = t; idx < PAIRS; idx += 1024)
        at[idx] = attn[(size_t)b*PAIRS + idx];
    u32* zm = (u32*)(w2m + (size_t)b * 25*48*32);
    u32* zt = (u32*)(w2t + (size_t)b * 7*48*32);
    for (int i = t; i < 25*48*16; i += 1024) zm[i] = 0;
    for (int i = t; i < 7*48*16;  i += 1024) zt[i] = 0;
    __syncthreads();
    if (t < cL * 25) {
        const int oc = t / 25, tap = t % 25;
        float c[cL];
        #pragma unroll
        for (int i = 0; i < cL; ++i)
            c[i] = cw[(size_t)oc * (cL*25) + i*25 + tap];
        u16* dm = w2m + ((size_t)(b*25 + tap)*48 + oc)*32;
        u16* dt = w2t + ((size_t)(b*7 + (tap>>2))*48 + oc)*32 + (tap&3)*8;
        for (int j = 0; j < cL; ++j) {
            float a = 0.f;
            #pragma unroll
            for (int i = 0; i < cL; ++i) a = fmaf(c[i], at[i*cL + j], a);
            if (j < 32) dm[j] = f2bf(a);
            else        dt[j - 32] = f2bf(a);
        }
    }
}

// ---------------------------------------------------------------------------
// K4: conv as dense-K MFMA with one-tap-ahead register prefetch of A-frags
// (af double-buffer carried across main->tail boundary). Epilogue stages fp8
// tile in LDS and writes full-line vectorized stores.
// ---------------------------------------------------------------------------
__global__ __launch_bounds__(256, 4) void k_conv(const u16* __restrict__ hst,
                                                 const u16* __restrict__ w2m,
                                                 const u16* __restrict__ w2t,
                                                 const float* __restrict__ cb,
                                                 u8* __restrict__ convout,
                                                 float* __restrict__ tileSumsq) {
    const int b   = blockIdx.z;
    const int gh0 = blockIdx.y * 16, gw0 = blockIdx.x * 16;
    const int tid = threadIdx.x;
    const int wv  = tid >> 6;
    const int ln15 = tid & 15;
    const int kg4  = (tid & 63) >> 4;

    __shared__ u16 P[400 * PROW];     // 32 KB; reused as fp8 staging in epilogue
    __shared__ float red[4][48];

    const u16* wbm = w2m + (size_t)b * 25*48*32;
    const u16* wbt = w2t + (size_t)b * 7*48*32;
    const int wlane = (ln15)*32 + kg4*8;   // per-lane offset within a 48x32 tile

    // issue first A-frag loads before staging (latency hides under staging)
    short8 afc0 = *(const short8*)(wbm + 0*16*32 + wlane);
    short8 afc1 = *(const short8*)(wbm + 1*16*32 + wlane);
    short8 afc2 = *(const short8*)(wbm + 2*16*32 + wlane);

    const u16* hb = hst + (size_t)b * (65536 * PROW);
    for (int c = tid; c < 2000; c += 256) {
        const int p = c / 5, g = c - p*5;
        const int pr = p / 20, pc = p - pr*20;
        const int gh = min(gh0 + pr, 255);
        const size_t pix = (size_t)gh * 256 + gw0 + pc;   // may spill; masked later
        const short8 v = *(const short8*)(hb + pix*PROW + g*8);
        *(short8*)&P[p*PROW + g*8] = v;
    }
    __syncthreads();

    f32x4 acc[3][4] = {};

    // ---- main: 25 taps, dense K = ic 0..31, one-tap-ahead af prefetch ----
    #pragma unroll
    for (int tap = 0; tap < 25; ++tap) {
        const int kh = tap / 5, kw = tap % 5;
        // prefetch next tap (or first tail chunk)
        const u16* wn = (tap < 24) ? (wbm + (size_t)(tap+1) * 48*32)
                                   : wbt;
        short8 afn0 = *(const short8*)(wn + 0*16*32 + wlane);
        short8 afn1 = *(const short8*)(wn + 1*16*32 + wlane);
        short8 afn2 = *(const short8*)(wn + 2*16*32 + wlane);
        #pragma unroll
        for (int pt = 0; pt < 4; ++pt) {
            const int p = (wv*4 + pt + kh)*20 + ln15 + kw;
            const short8 bfr = *(const short8*)&P[p*PROW + kg4*8];
            acc[0][pt] = __builtin_amdgcn_mfma_f32_16x16x32_bf16(afc0, bfr, acc[0][pt], 0, 0, 0);
            acc[1][pt] = __builtin_amdgcn_mfma_f32_16x16x32_bf16(afc1, bfr, acc[1][pt], 0, 0, 0);
            acc[2][pt] = __builtin_amdgcn_mfma_f32_16x16x32_bf16(afc2, bfr, acc[2][pt], 0, 0, 0);
        }
        afc0 = afn0; afc1 = afn1; afc2 = afn2;
    }

    // ---- tail: ic 32..39 packed as tap*8+ic'; per-lane tap = kc*4+kg4 ----
    #pragma unroll
    for (int kc = 0; kc < 7; ++kc) {
        short8 afn0, afn1, afn2;
        if (kc < 6) {
            const u16* wn = wbt + (size_t)(kc+1) * 48*32;
            afn0 = *(const short8*)(wn + 0*16*32 + wlane);
            afn1 = *(const short8*)(wn + 1*16*32 + wlane);
            afn2 = *(const short8*)(wn + 2*16*32 + wlane);
        }
        int tap = kc*4 + kg4;
        if (tap > 24) tap = 24;
        const int kh = tap / 5, kw = tap - kh*5;
        #pragma unroll
        for (int pt = 0; pt < 4; ++pt) {
            const int p = (wv*4 + pt + kh)*20 + ln15 + kw;
            const short8 bfr = *(const short8*)&P[p*PROW + 32];
            acc[0][pt] = __builtin_amdgcn_mfma_f32_16x16x32_bf16(afc0, bfr, acc[0][pt], 0, 0, 0);
            acc[1][pt] = __builtin_amdgcn_mfma_f32_16x16x32_bf16(afc1, bfr, acc[1][pt], 0, 0, 0);
            acc[2][pt] = __builtin_amdgcn_mfma_f32_16x16x32_bf16(afc2, bfr, acc[2][pt], 0, 0, 0);
        }
        if (kc < 6) { afc0 = afn0; afc1 = afn1; afc2 = afn2; }
    }

    __syncthreads();                  // P reads done; reuse as E
    u8* E = (u8*)P;                   // E[oc][256] fp8 staging (9984 B)

    float ss[3][4];
    #pragma unroll
    for (int o = 0; o < 3; ++o)
        #pragma unroll
        for (int r = 0; r < 4; ++r) ss[o][r] = 0.f;

    const int tile = blockIdx.y * 16 + blockIdx.x;
    const int ow = gw0 + ln15;
    #pragma unroll
    for (int o = 0; o < 3; ++o) {
        #pragma unroll
        for (int r = 0; r < 4; ++r) {
            const int oc = o*16 + kg4*4 + r;
            const float bias = (oc < cL) ? cb[oc] : 0.f;
            #pragma unroll
            for (int pt = 0; pt < 4; ++pt) {
                const int oh = gh0 + wv*4 + pt;
                const int loc = (wv*4 + pt)*16 + ln15;
                u8 val = 0;
                if (oc < cL && oh < cM && ow < cM) {
                    const float e = __expf(acc[o][pt][r] + bias);
                    if (ow <= oh) val = f2fp8(e);
                    ss[o][r] += e * e;
                }
                if (oc < cL) E[oc*256 + loc] = val;
            }
        }
    }
    __syncthreads();

    // full-line vectorized stores: 39 oc x 16 segs of 16B
    for (int c = tid; c < cL*16; c += 256) {
        const int oc = c >> 4, seg = c & 15;
        const uint4 v = *(const uint4*)&E[oc*256 + seg*16];
        *(uint4*)&convout[(size_t)(b*cL + oc)*GKP + tile*256 + seg*16] = v;
    }

    #pragma unroll
    for (int o = 0; o < 3; ++o) {
        #pragma unroll
        for (int r = 0; r < 4; ++r) {
            float v = ss[o][r];
            v += __shfl_xor(v, 1);
            v += __shfl_xor(v, 2);
            v += __shfl_xor(v, 4);
            v += __shfl_xor(v, 8);
            if (ln15 == 0) red[wv][o*16 + kg4*4 + r] = v;
        }
    }
    __syncthreads();
    if (tid < cL) {
        tileSumsq[((size_t)b*256 + tile)*cL + tid] =
            red[0][tid] + red[1][tid] + red[2][tid] + red[3][tid];
    }
}

// ---------------------------------------------------------------------------
// K4b: norms[row] = sqrt(sum over 256 tiles).
// ---------------------------------------------------------------------------
__global__ __launch_bounds__(256) void k_norm(const float* __restrict__ ts,
                                              float* __restrict__ norms) {
    const int row = blockIdx.x;
    const int b = row / cL, l = row % cL;
    const int tid = threadIdx.x;
    float v = ts[((size_t)b*256 + tid)*cL + l];
    for (int off = 32; off; off >>= 1) v += __shfl_down(v, off, 64);
    __shared__ float r[4];
    if ((tid & 63) == 0) r[tid >> 6] = v;
    __syncthreads();
    if (tid == 0) norms[row] = sqrtf(r[0] + r[1] + r[2] + r[3]);
}

// ---------------------------------------------------------------------------
// K5: fp8 MFMA out-GEMM. grid (1, 3, 128), 512 thr; block tile 128x256,
// wave tile 64x64; double-buffered LDS, rows padded to 80 B.
// ---------------------------------------------------------------------------
__global__ __launch_bounds__(512) void k_gemm(const u8* __restrict__ A,
                                              const u8* __restrict__ Bw,
                                              float* __restrict__ op) {
    const int mt = blockIdx.y, z = blockIdx.z;
    const int tid = threadIdx.x;
    const int wid = tid >> 6, lane = tid & 63;
    const int ln15 = lane & 15, kg4 = lane >> 4;
    const int wm = wid >> 2, wn = wid & 3;

    __shared__ u8 As[2][128*80];
    __shared__ u8 Bs[2][256*80];

    const int mbase = mt * 128;
    const int ra = tid >> 2, sl = tid & 3;
    const int arow = mbase + ra;
    const int aro = (arow < 312) ? arow : 0;
    const u8* Ap  = A  + (size_t)aro * GKP        + z*CSTEP + sl*16;
    const u8* Bp0 = Bw + (size_t)ra * GKP         + z*CSTEP + sl*16;
    const u8* Bp1 = Bw + (size_t)(128 + ra) * GKP + z*CSTEP + sl*16;

    uint4 pa  = *(const uint4*)Ap;
    uint4 pb0 = *(const uint4*)Bp0;
    uint4 pb1 = *(const uint4*)Bp1;

    f32x4 acc[4][4] = {};

    for (int s = 0; s < CSTEP/64; ++s) {
        const int cur = s & 1;
        __syncthreads();
        *(uint4*)&As[cur][ra*80 + sl*16]        = pa;
        *(uint4*)&Bs[cur][ra*80 + sl*16]        = pb0;
        *(uint4*)&Bs[cur][(128 + ra)*80 + sl*16] = pb1;
        __syncthreads();
        if (s + 1 < CSTEP/64) {
            const int off = (s + 1) * 64;
            pa  = *(const uint4*)(Ap + off);
            pb0 = *(const uint4*)(Bp0 + off);
            pb1 = *(const uint4*)(Bp1 + off);
        }
        #pragma unroll
        for (int kc = 0; kc < 2; ++kc) {
            long af[4], bf[4];
            #pragma unroll
            for (int fm = 0; fm < 4; ++fm)
                af[fm] = *(const long*)&As[cur][(wm*64 + fm*16 + ln15)*80 + kc*32 + kg4*8];
            #pragma unroll
            for (int fn = 0; fn < 4; ++fn)
                bf[fn] = *(const long*)&Bs[cur][(wn*64 + fn*16 + ln15)*80 + kc*32 + kg4*8];
            #pragma unroll
            for (int fm = 0; fm < 4; ++fm)
                #pragma unroll
                for (int fn = 0; fn < 4; ++fn)
                    acc[fm][fn] = __builtin_amdgcn_mfma_f32_16x16x32_fp8_fp8(
                        af[fm], bf[fn], acc[fm][fn], 0, 0, 0);
        }
    }

    #pragma unroll
    for (int fm = 0; fm < 4; ++fm) {
        #pragma unroll
        for (int r = 0; r < 4; ++r) {
            const int row = mbase + wm*64 + fm*16 + kg4*4 + r;
            if (row < 312) {
                #pragma unroll
                for (int fn = 0; fn < 4; ++fn) {
                    const int col = wn*64 + fn*16 + ln15;
                    op[((size_t)z*312 + row)*256 + col] = acc[fm][fn][r];
                }
            }
        }
    }
}

// ---------------------------------------------------------------------------
// K5b: reduce K-split partials, divide by (norm*256), write out.
// ---------------------------------------------------------------------------
__global__ __launch_bounds__(256) void k_finish(const float* __restrict__ op,
                                                const float* __restrict__ norms,
                                                float* __restrict__ out) {
    const int idx = blockIdx.x * 256 + threadIdx.x;
    float s = 0.f;
    for (int z = 0; z < GSPLIT; ++z) s += op[(size_t)z * (312*256) + idx];
    out[idx] = s / (norms[idx >> 8] * 256.0f);
}

// ---------------------------------------------------------------------------
extern "C" void kernel_launch(void* const* d_in, const int* in_sizes, int n_in,
                              void* d_out, int out_size, void* d_ws, size_t ws_size,
                              hipStream_t stream) {
    const float* hs = (const float*)d_in[0];
    const float* cw = (const float*)d_in[1];
    const float* cb = (const float*)d_in[2];
    const float* ow = (const float*)d_in[3];
    float* out = (float*)d_out;
    float* ws  = (float*)d_ws;

    if (ws_size < WS_FLOATS * sizeof(float)) return;

    float* sp   = ws + OFF_SP;
    float* ts   = ws + OFF_TS;
    float* nrm  = ws + OFF_NORM;
    float* attn = ws + OFF_ATTN;
    u16*   w2m  = (u16*)(ws + OFF_W2M);
    u16*   w2t  = (u16*)(ws + OFF_W2T);
    u16*   hst  = (u16*)(ws + OFF_HST);
    float* op   = ws + OFF_HST;            // overlaps hst (dead by k_gemm)
    u8*    cv   = (u8*)(ws + OFF_CONV);
    u8*    owb  = (u8*)(ws + OFF_OWB);

    k_hst    <<<dim3(256, cB), 256, 0, stream>>>(hs, hst);
    k_bwcast <<<256, 256, 0, stream>>>(ow, owb);
    k_gram   <<<dim3(KCHUNKS, cB), 256, 0, stream>>>(hst, sp);
    k_softmax<<<cB, 256, 0, stream>>>(sp, attn, out + (size_t)cB*cL*cD);
    k_wtrans <<<cB, 1024, 0, stream>>>(cw, attn, w2m, w2t);
    k_conv   <<<dim3(16, 16, cB), 256, 0, stream>>>(hst, w2m, w2t, cb, cv, ts);
    k_norm   <<<cB*cL, 256, 0, stream>>>(ts, nrm);
    k_gemm   <<<dim3(1, 3, GSPLIT), 512, 0, stream>>>(cv, owb, op);
    k_finish <<<312, 256, 0, stream>>>(op, nrm, out);
}

// Round 10
// 240.356 us; speedup vs baseline: 6.0361x; 1.2060x over previous
//
#include <hip/hip_runtime.h>
#include <math.h>

typedef unsigned short u16;
typedef unsigned int   u32;
typedef unsigned char  u8;
typedef __attribute__((ext_vector_type(8))) short short8;
typedef __attribute__((ext_vector_type(4))) float f32x4;
typedef __attribute__((ext_vector_type(4))) unsigned short ushort4_t;

// GeoMamba: B=8, L=39, D=256, K=5, M=252
constexpr int cB   = 8;
constexpr int cL   = 39;
constexpr int cD   = 256;
constexpr int cDD  = 65536;   // D*D
constexpr int cM   = 252;
constexpr int cMM  = 63504;   // M*M
constexpr int PAIRS = cL * cL; // 1521

constexpr int KCHUNKS = 64;    // gram K-split (1024 px per block)
constexpr int GKP     = 65536; // tile-major K for out-gemm (fp8 bytes per row)
constexpr int CSTEP   = 512;   // K per gemm block
constexpr int GSPLIT  = 128;   // 128*512 = 65536
constexpr int PROW    = 40;    // u16 per pixel row of hst
constexpr int WSTR    = 36;    // padded LDS row stride (u16) for weight tiles

// ---- ws layout (float offsets) ----
constexpr size_t OFF_SP   = 0;                          // gram partials [B][64][1521]
constexpr size_t SZ_SP    = (size_t)cB * KCHUNKS * PAIRS;
constexpr size_t OFF_TS   = 0;                          // overlaps SP (dead after softmax)
constexpr size_t OFF_NORM = OFF_TS + (size_t)cB * 256 * cL;
constexpr size_t OFF_ATTN = OFF_SP + SZ_SP;
constexpr size_t SZ_ATTN  = (size_t)cB * PAIRS;
constexpr size_t OFF_W2M  = OFF_ATTN + SZ_ATTN;         // main wts bf16 [B][tap25][oc48][32]
constexpr size_t SZ_W2M   = (size_t)cB * 25 * 48 * 32 / 2;
constexpr size_t OFF_W2T  = OFF_W2M + SZ_W2M;           // tail wts bf16 [B][kc7][oc48][32]
constexpr size_t SZ_W2T   = (size_t)cB * 7 * 48 * 32 / 2;
constexpr size_t OFF_HST  = OFF_W2T + SZ_W2T;           // hst bf16 [B][65536][40]; op overlaps
constexpr size_t SZ_HST   = (size_t)cB * 65536 * PROW / 2;   // 10,485,760 floats
constexpr size_t SZ_OP    = (size_t)GSPLIT * 312 * 256;      // 10,223,616 floats
static_assert(SZ_OP <= SZ_HST, "op must fit inside hst region");
constexpr size_t OFF_CONV = OFF_HST + SZ_HST;           // exp(conv) fp8 [312][GKP] tile-major
constexpr size_t SZ_CONV  = (size_t)312 * GKP / 4;
constexpr size_t OFF_OWB  = OFF_CONV + SZ_CONV;         // out_w fp8*256 [256][GKP] tile-major
constexpr size_t SZ_OWB   = (size_t)256 * GKP / 4;
constexpr size_t WS_FLOATS = OFF_OWB + SZ_OWB;          // ~83 MB

__device__ inline u16 f2bf(float x) {
    union { float f; unsigned u; } v; v.f = x;
    unsigned r = v.u + 0x7fffu + ((v.u >> 16) & 1u);   // RNE
    return (u16)(r >> 16);
}
__device__ inline u8 f2fp8(float x) {
    return (u8)(__builtin_amdgcn_cvt_pk_fp8_f32(x, x, 0, false) & 0xff);
}

// ---------------------------------------------------------------------------
// K0a: cast out_w*256 -> fp8 e4m3, gathered into tile-major K layout.
// ---------------------------------------------------------------------------
__global__ __launch_bounds__(256) void k_bwcast(const float* __restrict__ ow,
                                                u8* __restrict__ owb) {
    const int o = blockIdx.x;
    const float* src = ow + (size_t)o * cMM;
    u8* dst = owb + (size_t)o * GKP;
    for (int k4 = threadIdx.x; k4 < GKP / 4; k4 += 256) {
        const int k = k4 * 4;
        const int tile = k >> 8, loc = k & 255;
        const int th = tile >> 4, tw = tile & 15;
        const int ph = loc >> 4, pw = loc & 15;
        const int oh = th*16 + ph, owc = tw*16 + pw;
        unsigned r = 0;
        if (oh < cM && owc + 3 < cM) {
            const float4 f = *(const float4*)(src + oh*cM + owc);
            unsigned lo = (unsigned)__builtin_amdgcn_cvt_pk_fp8_f32(f.x*256.f, f.y*256.f, 0, false);
            unsigned hi = (unsigned)__builtin_amdgcn_cvt_pk_fp8_f32(f.z*256.f, f.w*256.f, 0, false);
            r = (lo & 0xffffu) | (hi << 16);
        }
        *(unsigned*)(dst + k) = r;
    }
}

// ---------------------------------------------------------------------------
// K0c: hst[b][pix][40] bf16 = transpose+cast of hs (ch 0..38, ch39 = 0).
// ---------------------------------------------------------------------------
__global__ __launch_bounds__(256) void k_hst(const float* __restrict__ hs,
                                             u16* __restrict__ hst) {
    const int b  = blockIdx.y;
    const int px = blockIdx.x * 256 + threadIdx.x;
    const float* hb = hs + (size_t)b * (cL * cDD) + px;
    u32 w[20];
    #pragma unroll
    for (int c2 = 0; c2 < 20; ++c2) {
        const int c0 = 2*c2, c1 = 2*c2 + 1;
        const u32 lo = f2bf(hb[(size_t)c0 * cDD]);
        const u32 hi = (c1 < cL) ? (u32)f2bf(hb[(size_t)c1 * cDD]) : 0u;
        w[c2] = lo | (hi << 16);
    }
    u16* ob = hst + (size_t)b * (65536 * PROW) + (size_t)px * PROW;
    #pragma unroll
    for (int g = 0; g < 5; ++g) {
        uint4 v;
        v.x = w[g*4 + 0]; v.y = w[g*4 + 1]; v.z = w[g*4 + 2]; v.w = w[g*4 + 3];
        *(uint4*)(ob + g*8) = v;
    }
}

// ---------------------------------------------------------------------------
// K1: MFMA gram. A-frag == B-frag, read straight from hst (strided u16).
// ---------------------------------------------------------------------------
__global__ __launch_bounds__(256) void k_gram(const u16* __restrict__ hst,
                                              float* __restrict__ sp) {
    const int b  = blockIdx.y;
    const int kc = blockIdx.x;
    const int tid = threadIdx.x;
    const int wv = tid >> 6, ln15 = tid & 15, kg4 = (tid & 63) >> 4;
    const u16* hb = hst + (size_t)b * (65536 * PROW);
    const int px0 = kc * 1024 + wv * 256;

    f32x4 acc[3][3] = {};
    #pragma unroll
    for (int s = 0; s < 8; ++s) {
        const int px = px0 + s * 32 + kg4 * 8;
        short8 f[3];
        #pragma unroll
        for (int o = 0; o < 3; ++o) {
            const int ch = o * 16 + ln15;
            short8 v = {};
            if (ch < PROW) {
                const u16* p = hb + (size_t)px * PROW + ch;
                #pragma unroll
                for (int j = 0; j < 8; ++j) v[j] = (short)p[j * PROW];
            }
            f[o] = v;
        }
        #pragma unroll
        for (int oi = 0; oi < 3; ++oi)
            #pragma unroll
            for (int oj = 0; oj < 3; ++oj)
                acc[oi][oj] = __builtin_amdgcn_mfma_f32_16x16x32_bf16(
                    f[oi], f[oj], acc[oi][oj], 0, 0, 0);
    }

    __shared__ float R[4][48 * 50];
    #pragma unroll
    for (int oi = 0; oi < 3; ++oi)
        #pragma unroll
        for (int oj = 0; oj < 3; ++oj)
            #pragma unroll
            for (int r = 0; r < 4; ++r)
                R[wv][(oi*16 + kg4*4 + r)*50 + oj*16 + ln15] = acc[oi][oj][r];
    __syncthreads();

    float* outp = sp + ((size_t)b * KCHUNKS + kc) * PAIRS;
    for (int idx = tid; idx < PAIRS; idx += 256) {
        const int i = idx / 39, j = idx - i * 39;
        const int a = i * 50 + j;
        outp[idx] = R[0][a] + R[1][a] + R[2][a] + R[3][a];
    }
}

// ---------------------------------------------------------------------------
// K2: reduce gram partials, scale 1/256, row softmax.
// ---------------------------------------------------------------------------
__global__ __launch_bounds__(256) void k_softmax(const float* __restrict__ sp,
                                                 float* __restrict__ attnWs,
                                                 float* __restrict__ outAttn) {
    const int b = blockIdx.x;
    const int tid = threadIdx.x;
    __shared__ float sc[PAIRS];
    for (int idx = tid; idx < PAIRS; idx += 256) {
        float s = 0.f;
        for (int c = 0; c < KCHUNKS; ++c)
            s += sp[((size_t)b * KCHUNKS + c) * PAIRS + idx];
        sc[idx] = s * (1.0f / 256.0f);
    }
    __syncthreads();
    if (tid < cL) {
        const int i = tid;
        float m = -1e30f;
        #pragma unroll
        for (int j = 0; j < cL; ++j) m = fmaxf(m, sc[i*cL + j]);
        float e[cL];
        float sum = 0.f;
        #pragma unroll
        for (int j = 0; j < cL; ++j) { e[j] = expf(sc[i*cL + j] - m); sum += e[j]; }
        const float inv = 1.0f / sum;
        #pragma unroll
        for (int j = 0; j < cL; ++j) {
            const float a = e[j] * inv;
            attnWs [(size_t)b*PAIRS + i*cL + j] = a;
            outAttn[(size_t)b*PAIRS + i*cL + j] = a;
        }
    }
}

// ---------------------------------------------------------------------------
// K3: fold attention into conv weights -> dense-K bf16 MFMA A-layout.
// ---------------------------------------------------------------------------
__global__ __launch_bounds__(1024) void k_wtrans(const float* __restrict__ cw,
                                                 const float* __restrict__ attn,
                                                 u16* __restrict__ w2m,
                                                 u16* __restrict__ w2t) {
    const int b = blockIdx.x;
    const int t = threadIdx.x;
    __shared__ float at[PAIRS];
    for (int idx = t; idx < PAIRS; idx += 1024)
        at[idx] = attn[(size_t)b*PAIRS + idx];
    u32* zm = (u32*)(w2m + (size_t)b * 25*48*32);
    u32* zt = (u32*)(w2t + (size_t)b * 7*48*32);
    for (int i = t; i < 25*48*16; i += 1024) zm[i] = 0;
    for (int i = t; i < 7*48*16;  i += 1024) zt[i] = 0;
    __syncthreads();
    if (t < cL * 25) {
        const int oc = t / 25, tap = t % 25;
        float c[cL];
        #pragma unroll
        for (int i = 0; i < cL; ++i)
            c[i] = cw[(size_t)oc * (cL*25) + i*25 + tap];
        u16* dm = w2m + ((size_t)(b*25 + tap)*48 + oc)*32;
        u16* dt = w2t + ((size_t)(b*7 + (tap>>2))*48 + oc)*32 + (tap&3)*8;
        for (int j = 0; j < cL; ++j) {
            float a = 0.f;
            #pragma unroll
            for (int i = 0; i < cL; ++i) a = fmaf(c[i], at[i*cL + j], a);
            if (j < 32) dm[j] = f2bf(a);
            else        dt[j - 32] = f2bf(a);
        }
    }
}

// ---------------------------------------------------------------------------
// K4: conv as dense-K MFMA. Weights now broadcast through a double-buffered
// LDS tile (T14 async-STAGE: load chunk t+2 to regs early, ds_write chunk t+1
// late, one barrier per chunk). A-frags = 3 ds_read_b128/chunk/wave; weight
// L2 traffic per block drops 4x (per-wave -> per-block). W rows padded to
// 36 u16 (72B) -> 2-way bank aliasing (free). LDS 39.7KB -> 4 blocks/CU.
// ---------------------------------------------------------------------------
__global__ __launch_bounds__(256, 4) void k_conv(const u16* __restrict__ hst,
                                                 const u16* __restrict__ w2m,
                                                 const u16* __restrict__ w2t,
                                                 const float* __restrict__ cb,
                                                 u8* __restrict__ convout,
                                                 float* __restrict__ tileSumsq) {
    const int b   = blockIdx.z;
    const int gh0 = blockIdx.y * 16, gw0 = blockIdx.x * 16;
    const int tid = threadIdx.x;
    const int wv  = tid >> 6;
    const int ln15 = tid & 15;
    const int kg4  = (tid & 63) >> 4;

    __shared__ u16 P[400 * PROW];      // 32000 B; reused as fp8 staging
    __shared__ u16 W[2][48 * WSTR];    // 2 x 3456 B weight broadcast tiles
    __shared__ float red[4][48];

    const u16* wbm = w2m + (size_t)b * 25*48*32;
    const u16* wbt = w2t + (size_t)b * 7*48*32;
    const bool wact = tid < 192;                 // 192 x 16B = one 48x32 chunk
    const int  wrow = tid >> 2, wq = tid & 3;    // LDS dest row/quarter

    // issue chunk-0 weight load before pixel staging (latency hides under it)
    uint4 wA = {};
    if (wact) wA = *(const uint4*)(wbm + tid*8);

    // ---- stage 20x20 patch, [pix][40ic], reg-staged ----
    const u16* hb = hst + (size_t)b * (65536 * PROW);
    for (int c = tid; c < 2000; c += 256) {
        const int p = c / 5, g = c - p*5;
        const int pr = p / 20, pc = p - pr*20;
        const int gh = min(gh0 + pr, 255);
        const size_t pix = (size_t)gh * 256 + gw0 + pc;   // may spill; masked later
        const short8 v = *(const short8*)(hb + pix*PROW + g*8);
        *(short8*)&P[p*PROW + g*8] = v;
    }
    // write chunk 0 into W[0], then issue chunk-1 load
    if (wact) {
        *(uint4*)&W[0][wrow*WSTR + wq*8] = wA;
        wA = *(const uint4*)(wbm + 1*48*32 + tid*8);
    }
    __syncthreads();

    f32x4 acc[3][4] = {};

    #pragma unroll
    for (int t = 0; t < 32; ++t) {
        const int cur = t & 1;
        // write chunk t+1 (in wA) into the other buffer; issue chunk t+2 load
        if (t + 1 < 32 && wact)
            *(uint4*)&W[cur ^ 1][wrow*WSTR + wq*8] = wA;
        if (t + 2 < 32 && wact) {
            const int c2 = t + 2;
            const u16* ws = (c2 < 25) ? (wbm + (size_t)c2 * 48*32)
                                      : (wbt + (size_t)(c2 - 25) * 48*32);
            wA = *(const uint4*)(ws + tid*8);
        }
        // A-frags from LDS broadcast tile
        short8 af0 = *(const short8*)&W[cur][( 0 + ln15)*WSTR + kg4*8];
        short8 af1 = *(const short8*)&W[cur][(16 + ln15)*WSTR + kg4*8];
        short8 af2 = *(const short8*)&W[cur][(32 + ln15)*WSTR + kg4*8];
        if (t < 25) {
            const int kh = t / 5, kw = t - (t/5)*5;
            #pragma unroll
            for (int pt = 0; pt < 4; ++pt) {
                const int p = (wv*4 + pt + kh)*20 + ln15 + kw;
                const short8 bfr = *(const short8*)&P[p*PROW + kg4*8];
                acc[0][pt] = __builtin_amdgcn_mfma_f32_16x16x32_bf16(af0, bfr, acc[0][pt], 0, 0, 0);
                acc[1][pt] = __builtin_amdgcn_mfma_f32_16x16x32_bf16(af1, bfr, acc[1][pt], 0, 0, 0);
                acc[2][pt] = __builtin_amdgcn_mfma_f32_16x16x32_bf16(af2, bfr, acc[2][pt], 0, 0, 0);
            }
        } else {
            int tap = (t - 25)*4 + kg4;
            if (tap > 24) tap = 24;              // pad taps: zero A rows
            const int kh = tap / 5, kw = tap - kh*5;
            #pragma unroll
            for (int pt = 0; pt < 4; ++pt) {
                const int p = (wv*4 + pt + kh)*20 + ln15 + kw;
                const short8 bfr = *(const short8*)&P[p*PROW + 32];
                acc[0][pt] = __builtin_amdgcn_mfma_f32_16x16x32_bf16(af0, bfr, acc[0][pt], 0, 0, 0);
                acc[1][pt] = __builtin_amdgcn_mfma_f32_16x16x32_bf16(af1, bfr, acc[1][pt], 0, 0, 0);
                acc[2][pt] = __builtin_amdgcn_mfma_f32_16x16x32_bf16(af2, bfr, acc[2][pt], 0, 0, 0);
            }
        }
        __syncthreads();
    }

    u8* E = (u8*)P;                   // E[oc][256] fp8 staging (9984 B)

    float ss[3][4];
    #pragma unroll
    for (int o = 0; o < 3; ++o)
        #pragma unroll
        for (int r = 0; r < 4; ++r) ss[o][r] = 0.f;

    const int tile = blockIdx.y * 16 + blockIdx.x;
    const int ow = gw0 + ln15;
    #pragma unroll
    for (int o = 0; o < 3; ++o) {
        #pragma unroll
        for (int r = 0; r < 4; ++r) {
            const int oc = o*16 + kg4*4 + r;
            const float bias = (oc < cL) ? cb[oc] : 0.f;
            #pragma unroll
            for (int pt = 0; pt < 4; ++pt) {
                const int oh = gh0 + wv*4 + pt;
                const int loc = (wv*4 + pt)*16 + ln15;
                u8 val = 0;
                if (oc < cL && oh < cM && ow < cM) {
                    const float e = __expf(acc[o][pt][r] + bias);
                    if (ow <= oh) val = f2fp8(e);
                    ss[o][r] += e * e;
                }
                if (oc < cL) E[oc*256 + loc] = val;
            }
        }
    }
    __syncthreads();

    // full-line vectorized stores: 39 oc x 16 segs of 16B
    for (int c = tid; c < cL*16; c += 256) {
        const int oc = c >> 4, seg = c & 15;
        const uint4 v = *(const uint4*)&E[oc*256 + seg*16];
        *(uint4*)&convout[(size_t)(b*cL + oc)*GKP + tile*256 + seg*16] = v;
    }

    #pragma unroll
    for (int o = 0; o < 3; ++o) {
        #pragma unroll
        for (int r = 0; r < 4; ++r) {
            float v = ss[o][r];
            v += __shfl_xor(v, 1);
            v += __shfl_xor(v, 2);
            v += __shfl_xor(v, 4);
            v += __shfl_xor(v, 8);
            if (ln15 == 0) red[wv][o*16 + kg4*4 + r] = v;
        }
    }
    __syncthreads();
    if (tid < cL) {
        tileSumsq[((size_t)b*256 + tile)*cL + tid] =
            red[0][tid] + red[1][tid] + red[2][tid] + red[3][tid];
    }
}

// ---------------------------------------------------------------------------
// K4b: norms[row] = sqrt(sum over 256 tiles).
// ---------------------------------------------------------------------------
__global__ __launch_bounds__(256) void k_norm(const float* __restrict__ ts,
                                              float* __restrict__ norms) {
    const int row = blockIdx.x;
    const int b = row / cL, l = row % cL;
    const int tid = threadIdx.x;
    float v = ts[((size_t)b*256 + tid)*cL + l];
    for (int off = 32; off; off >>= 1) v += __shfl_down(v, off, 64);
    __shared__ float r[4];
    if ((tid & 63) == 0) r[tid >> 6] = v;
    __syncthreads();
    if (tid == 0) norms[row] = sqrtf(r[0] + r[1] + r[2] + r[3]);
}

// ---------------------------------------------------------------------------
// K5: fp8 MFMA out-GEMM. grid (1, 3, 128), 512 thr; block tile 128x256,
// wave tile 64x64; double-buffered LDS, rows padded to 80 B.
// ---------------------------------------------------------------------------
__global__ __launch_bounds__(512) void k_gemm(const u8* __restrict__ A,
                                              const u8* __restrict__ Bw,
                                              float* __restrict__ op) {
    const int mt = blockIdx.y, z = blockIdx.z;
    const int tid = threadIdx.x;
    const int wid = tid >> 6, lane = tid & 63;
    const int ln15 = lane & 15, kg4 = lane >> 4;
    const int wm = wid >> 2, wn = wid & 3;

    __shared__ u8 As[2][128*80];
    __shared__ u8 Bs[2][256*80];

    const int mbase = mt * 128;
    const int ra = tid >> 2, sl = tid & 3;
    const int arow = mbase + ra;
    const int aro = (arow < 312) ? arow : 0;
    const u8* Ap  = A  + (size_t)aro * GKP        + z*CSTEP + sl*16;
    const u8* Bp0 = Bw + (size_t)ra * GKP         + z*CSTEP + sl*16;
    const u8* Bp1 = Bw + (size_t)(128 + ra) * GKP + z*CSTEP + sl*16;

    uint4 pa  = *(const uint4*)Ap;
    uint4 pb0 = *(const uint4*)Bp0;
    uint4 pb1 = *(const uint4*)Bp1;

    f32x4 acc[4][4] = {};

    for (int s = 0; s < CSTEP/64; ++s) {
        const int cur = s & 1;
        __syncthreads();
        *(uint4*)&As[cur][ra*80 + sl*16]        = pa;
        *(uint4*)&Bs[cur][ra*80 + sl*16]        = pb0;
        *(uint4*)&Bs[cur][(128 + ra)*80 + sl*16] = pb1;
        __syncthreads();
        if (s + 1 < CSTEP/64) {
            const int off = (s + 1) * 64;
            pa  = *(const uint4*)(Ap + off);
            pb0 = *(const uint4*)(Bp0 + off);
            pb1 = *(const uint4*)(Bp1 + off);
        }
        #pragma unroll
        for (int kc = 0; kc < 2; ++kc) {
            long af[4], bf[4];
            #pragma unroll
            for (int fm = 0; fm < 4; ++fm)
                af[fm] = *(const long*)&As[cur][(wm*64 + fm*16 + ln15)*80 + kc*32 + kg4*8];
            #pragma unroll
            for (int fn = 0; fn < 4; ++fn)
                bf[fn] = *(const long*)&Bs[cur][(wn*64 + fn*16 + ln15)*80 + kc*32 + kg4*8];
            #pragma unroll
            for (int fm = 0; fm < 4; ++fm)
                #pragma unroll
                for (int fn = 0; fn < 4; ++fn)
                    acc[fm][fn] = __builtin_amdgcn_mfma_f32_16x16x32_fp8_fp8(
                        af[fm], bf[fn], acc[fm][fn], 0, 0, 0);
        }
    }

    #pragma unroll
    for (int fm = 0; fm < 4; ++fm) {
        #pragma unroll
        for (int r = 0; r < 4; ++r) {
            const int row = mbase + wm*64 + fm*16 + kg4*4 + r;
            if (row < 312) {
                #pragma unroll
                for (int fn = 0; fn < 4; ++fn) {
                    const int col = wn*64 + fn*16 + ln15;
                    op[((size_t)z*312 + row)*256 + col] = acc[fm][fn][r];
                }
            }
        }
    }
}

// ---------------------------------------------------------------------------
// K5b: reduce K-split partials, divide by (norm*256), write out.
// ---------------------------------------------------------------------------
__global__ __launch_bounds__(256) void k_finish(const float* __restrict__ op,
                                                const float* __restrict__ norms,
                                                float* __restrict__ out) {
    const int idx = blockIdx.x * 256 + threadIdx.x;
    float s = 0.f;
    for (int z = 0; z < GSPLIT; ++z) s += op[(size_t)z * (312*256) + idx];
    out[idx] = s / (norms[idx >> 8] * 256.0f);
}

// ---------------------------------------------------------------------------
extern "C" void kernel_launch(void* const* d_in, const int* in_sizes, int n_in,
                              void* d_out, int out_size, void* d_ws, size_t ws_size,
                              hipStream_t stream) {
    const float* hs = (const float*)d_in[0];
    const float* cw = (const float*)d_in[1];
    const float* cb = (const float*)d_in[2];
    const float* ow = (const float*)d_in[3];
    float* out = (float*)d_out;
    float* ws  = (float*)d_ws;

    if (ws_size < WS_FLOATS * sizeof(float)) return;

    float* sp   = ws + OFF_SP;
    float* ts   = ws + OFF_TS;
    float* nrm  = ws + OFF_NORM;
    float* attn = ws + OFF_ATTN;
    u16*   w2m  = (u16*)(ws + OFF_W2M);
    u16*   w2t  = (u16*)(ws + OFF_W2T);
    u16*   hst  = (u16*)(ws + OFF_HST);
    float* op   = ws + OFF_HST;            // overlaps hst (dead by k_gemm)
    u8*    cv   = (u8*)(ws + OFF_CONV);
    u8*    owb  = (u8*)(ws + OFF_OWB);

    k_hst    <<<dim3(256, cB), 256, 0, stream>>>(hs, hst);
    k_bwcast <<<256, 256, 0, stream>>>(ow, owb);
    k_gram   <<<dim3(KCHUNKS, cB), 256, 0, stream>>>(hst, sp);
    k_softmax<<<cB, 256, 0, stream>>>(sp, attn, out + (size_t)cB*cL*cD);
    k_wtrans <<<cB, 1024, 0, stream>>>(cw, attn, w2m, w2t);
    k_conv   <<<dim3(16, 16, cB), 256, 0, stream>>>(hst, w2m, w2t, cb, cv, ts);
    k_norm   <<<cB*cL, 256, 0, stream>>>(ts, nrm);
    k_gemm   <<<dim3(1, 3, GSPLIT), 512, 0, stream>>>(cv, owb, op);
    k_finish <<<312, 256, 0, stream>>>(op, nrm, out);
}